// Round 5
// baseline (993.423 us; speedup 1.0000x reference)
//
#include <hip/hip_runtime.h>
#include <hip/hip_bf16.h>

typedef __hip_bfloat16 bf16;

__device__ __forceinline__ float dssp(float x){
  return fmaxf(x, 0.f) + log1pf(expf(-fabsf(x))) - 0.693147180559945f;
}
__device__ __forceinline__ int clampi(int x, int lo, int hi){ return x<lo?lo:(x>hi?hi:x); }
__device__ __forceinline__ unsigned short f2b(float f){
  unsigned x = __float_as_uint(f);
  return (unsigned short)((x + 0x7fffu + ((x>>16)&1u)) >> 16);
}
__device__ __forceinline__ float b2f16(unsigned short u){ return __uint_as_float(((unsigned)u)<<16); }

constexpr int TBL_K    = 4096;
constexpr int TBL_ROWS = TBL_K + 1;
constexpr int TBL_TILES = (TBL_ROWS + 31) / 32;  // 129

// ------------------------------------------------- dtype detection ----------
__global__ void detect_mode(const unsigned* __restrict__ raw, int* flag){
  __shared__ int c;
  int t = threadIdx.x;
  if (t==0) c = 0;
  __syncthreads();
  unsigned u  = raw[t];
  unsigned lo = u & 0xFFFFu;
  int e = (int)((lo >> 7) & 0xFF);
  int ok = (lo==0u) || (e >= 0x70 && e <= 0x8F);
  atomicAdd(&c, ok);
  __syncthreads();
  if (t==0) *flag = (c >= 160) ? 1 : 0;   // 1 = bf16 storage, 0 = f32 storage
}

// ---------------------------------------------- canonical fp32 conversion ---
struct Seg { const void* src; float* dst; int n; };
struct SegTable { Seg s[27]; int count; long total; };

__global__ void convert_all(SegTable tbl, const int* __restrict__ flag){
  int mode = *flag;
  long tid    = (long)blockIdx.x*blockDim.x + threadIdx.x;
  long stride = (long)gridDim.x*blockDim.x;
  for (long i=tid; i<tbl.total; i+=stride){
    long off = i; int k = 0;
    while (k < tbl.count-1 && off >= tbl.s[k].n){ off -= tbl.s[k].n; k++; }
    float f;
    if (mode) f = __bfloat162float(((const bf16*)tbl.s[k].src)[off]);
    else      f = ((const float*)tbl.s[k].src)[off];
    tbl.s[k].dst[off] = (f==f) ? f : 0.f;
  }
}

// ------------------------------------------------------------------ setup ---
__global__ void init_all(int* cnt_r, int* cnt_h, float* uacc,
                         int2* spk_r, int2* spk_h, int N, int E, int EH){
  int t = blockIdx.x*blockDim.x + threadIdx.x;
  if (t < N){ cnt_r[t]=0; cnt_h[t]=0; }
  if (t < 64) uacc[t]=0.f;
  if (t < E)  spk_r[t]=make_int2(0,0);
  if (t < EH) spk_h[t]=make_int2(0,0);
}

__global__ void count_edges(const int* __restrict__ ei, const int* __restrict__ eih,
                            int E, int EH, int N, int* cnt_r, int* cnt_h){
  int t = blockIdx.x*blockDim.x + threadIdx.x;
  if (t < E)  atomicAdd(&cnt_r[clampi(ei[E + t], 0, N-1)], 1);
  if (t < EH) atomicAdd(&cnt_h[clampi(eih[EH + t], 0, N-1)], 1);
}

__global__ __launch_bounds__(256) void scan_pair(const int* cnt_r, int* off_r, int* cur_r,
                                                 const int* cnt_h, int* off_h, int* cur_h, int N){
  __shared__ int s[256];
  int t = threadIdx.x;
  int CH = (N + 255) / 256;
  for (int which=0; which<2; which++){
    const int* cnt = which? cnt_h : cnt_r;
    int* off = which? off_h : off_r;
    int* cur = which? cur_h : cur_r;
    int base = t*CH;
    int sum = 0;
    for (int q=0;q<CH;q++){ int idx=base+q; sum += (idx<N)? cnt[idx] : 0; }
    __syncthreads();
    s[t]=sum; __syncthreads();
    for (int ofs=1; ofs<256; ofs<<=1){
      int v = s[t]; int vp = (t>=ofs)? s[t-ofs] : 0;
      __syncthreads(); s[t]=v+vp; __syncthreads();
    }
    int run = (t>0)? s[t-1] : 0;
    for (int q=0;q<CH;q++){
      int idx=base+q;
      if (idx<N){ off[idx]=run; cur[idx]=run; run += cnt[idx]; }
    }
    if (t==255) off[N] = s[255];
  }
}

__global__ void scatter_edges(const int* __restrict__ ei, const float* __restrict__ distc,
                              const int* __restrict__ eih, int E, int EH, int N,
                              int* cur_r, int* cur_h, int2* spk_r, int2* spk_h){
  int t = blockIdx.x*blockDim.x + threadIdx.x;
  if (t < E){
    int i = clampi(ei[E+t], 0, N-1);
    int p = clampi(atomicAdd(&cur_r[i], 1), 0, E-1);
    spk_r[p] = make_int2(clampi(ei[t],0,N-1), __float_as_int(distc[t]));
  }
  if (t < EH){
    int ih = clampi(eih[EH+t], 0, N-1);
    int p = clampi(atomicAdd(&cur_h[ih], 1), 0, EH-1);
    spk_h[p] = make_int2(clampi(eih[t],0,N-1), t);
  }
}

// --------------------------------------------- W(dist) lookup table (bf16) ---
__global__ __launch_bounds__(256) void build_wtab(const float* __restrict__ mlp_w1,
    const float* __restrict__ mlp_b1, const float* __restrict__ mlp_w2,
    const float* __restrict__ mlp_b2, unsigned short* __restrict__ Wtab){
  int l    = blockIdx.x / TBL_TILES;
  int tile = blockIdx.x % TBL_TILES;
  int row0 = tile * 32;
  const float* w1 = mlp_w1 + l*128*25;
  const float* b1 = mlp_b1 + l*128;
  const float* w2 = mlp_w2 + l*128*128;
  const float* b2 = mlp_b2 + l*128;
  __shared__ float Gs[32][26];
  __shared__ float Ts[32][129];
  __shared__ float Ws[32][129];
  int t = threadIdx.x;
  for (int idx=t; idx<32*25; idx+=256){
    int r = idx/25, k = idx%25;
    float d = (row0+r) * (5.0f/4096.0f);
    float x = d - (float)k*(5.0f/24.0f);
    Gs[r][k] = expf(-11.52f*x*x);
  }
  __syncthreads();
  int rg = t&7, cg = t>>3;
  #pragma unroll
  for (int ri=0;ri<4;ri++){
    int r = rg*4+ri;
    #pragma unroll
    for (int ci=0;ci<4;ci++){
      int c = cg*4+ci;
      float s = b1[c];
      for (int k=0;k<25;k++) s += Gs[r][k]*w1[c*25+k];
      Ts[r][c] = dssp(s);
    }
  }
  float acc[4][4] = {};
  for (int k0=0;k0<128;k0+=32){
    __syncthreads();
    for (int idx=t; idx<1024; idx+=256){
      int c=idx>>3, kk4=(idx&7)*4;
      float4 f = *(const float4*)(w2+(size_t)c*128+k0+kk4);
      Ws[kk4][c]=f.x; Ws[kk4+1][c]=f.y; Ws[kk4+2][c]=f.z; Ws[kk4+3][c]=f.w;
    }
    __syncthreads();
    for (int kk=0;kk<32;kk++){
      float xv[4];
      #pragma unroll
      for (int ri=0;ri<4;ri++) xv[ri]=Ts[rg*4+ri][k0+kk];
      #pragma unroll
      for (int ci=0;ci<4;ci++){
        float wv = Ws[kk][cg*4+ci];
        #pragma unroll
        for (int ri=0;ri<4;ri++) acc[ri][ci] += xv[ri]*wv;
      }
    }
  }
  #pragma unroll
  for (int ri=0;ri<4;ri++){
    int r = row0 + rg*4 + ri;
    if (r >= TBL_ROWS) continue;
    float d  = r * (5.0f/4096.0f);
    float Cf = 0.5f*(cosf(d*(3.14159265358979f/5.0f))+1.0f);
    #pragma unroll
    for (int ci=0;ci<4;ci++){
      int c = cg*4+ci;
      Wtab[((size_t)l*TBL_ROWS + r)*128 + c] = f2b((acc[ri][ci] + b2[c]) * Cf);
    }
  }
}

// ---------------------- 16-row x 128-thread tile matmul helpers -------------
// X in LDS Xs[16][132] (row-major). W global row-major [cols][128].
// Thread: rg=t&3 -> rows rg*4+ri ; cg=t>>2 (0..31).
// mm128: cols cg*4+ci, acc[4][4]. mm64: cols cg*2+ci, acc[4][2].
__device__ __forceinline__ void mm128(const float (*Xs)[132], float (*Ws)[132],
    const float* __restrict__ W, int t, float a[4][4]){
  int rg=t&3, cg=t>>2;
  #pragma unroll
  for (int ri=0;ri<4;ri++){ a[ri][0]=0.f; a[ri][1]=0.f; a[ri][2]=0.f; a[ri][3]=0.f; }
  for (int k0=0;k0<128;k0+=32){
    __syncthreads();
    for (int idx=t; idx<1024; idx+=128){
      int c=idx>>3, k4=(idx&7)*4;
      float4 f = *(const float4*)(W + (size_t)c*128 + k0 + k4);
      Ws[k4][c]=f.x; Ws[k4+1][c]=f.y; Ws[k4+2][c]=f.z; Ws[k4+3][c]=f.w;
    }
    __syncthreads();
    #pragma unroll 4
    for (int kk=0;kk<32;kk++){
      float xv[4];
      #pragma unroll
      for (int ri=0;ri<4;ri++) xv[ri]=Xs[rg*4+ri][k0+kk];
      float4 wv = *(const float4*)&Ws[kk][cg*4];
      #pragma unroll
      for (int ri=0;ri<4;ri++){
        a[ri][0] += xv[ri]*wv.x; a[ri][1] += xv[ri]*wv.y;
        a[ri][2] += xv[ri]*wv.z; a[ri][3] += xv[ri]*wv.w;
      }
    }
  }
  __syncthreads();   // callers may overwrite Xs/Ws after return
}

__device__ __forceinline__ void mm64(const float (*Xs)[132], float (*Ws)[132],
    const float* __restrict__ W, int t, float a[4][2]){
  int rg=t&3, cg=t>>2;
  #pragma unroll
  for (int ri=0;ri<4;ri++){ a[ri][0]=0.f; a[ri][1]=0.f; }
  for (int k0=0;k0<128;k0+=32){
    __syncthreads();
    for (int idx=t; idx<512; idx+=128){
      int c=idx>>3, k4=(idx&7)*4;
      float4 f = *(const float4*)(W + (size_t)c*128 + k0 + k4);
      Ws[k4][c]=f.x; Ws[k4+1][c]=f.y; Ws[k4+2][c]=f.z; Ws[k4+3][c]=f.w;
    }
    __syncthreads();
    #pragma unroll 4
    for (int kk=0;kk<32;kk++){
      float xv[4];
      #pragma unroll
      for (int ri=0;ri<4;ri++) xv[ri]=Xs[rg*4+ri][k0+kk];
      float2 wv = *(const float2*)&Ws[kk][cg*2];
      #pragma unroll
      for (int ri=0;ri<4;ri++){ a[ri][0]+=xv[ri]*wv.x; a[ri][1]+=xv[ri]*wv.y; }
    }
  }
  __syncthreads();
}

// ------------------------- F0: embed + lin + linh ---------------------------
__global__ __launch_bounds__(128) void f_first(const int* __restrict__ z,
    const float* __restrict__ emb, float* __restrict__ v,
    const float* __restrict__ linA, const float* __restrict__ linB,
    unsigned short* __restrict__ vlin, unsigned short* __restrict__ vlinh, int N){
  __shared__ float Xs[16][132];
  __shared__ float Ws[32][132];
  int t=threadIdx.x; int row0=blockIdx.x*16; int rg=t&3, cg=t>>2;
  for (int idx=t; idx<512; idx+=128){
    int r=idx>>5, k4=(idx&31)*4; int gr=row0+r;
    int zz = (gr<N)? clampi(z[gr],0,99) : 0;
    float4 f = *(const float4*)(emb + (size_t)zz*128 + k4);
    Xs[r][k4]=f.x; Xs[r][k4+1]=f.y; Xs[r][k4+2]=f.z; Xs[r][k4+3]=f.w;
    if (gr<N) *(float4*)(v + (size_t)gr*128 + k4) = f;
  }
  float a[4][4];
  mm128(Xs,Ws,linA,t,a);
  #pragma unroll
  for (int ri=0;ri<4;ri++){
    int gr=row0+rg*4+ri; if (gr>=N) continue;
    #pragma unroll
    for (int ci=0;ci<4;ci++) vlin[(size_t)gr*128+cg*4+ci]=f2b(a[ri][ci]);
  }
  mm128(Xs,Ws,linB,t,a);
  #pragma unroll
  for (int ri=0;ri<4;ri++){
    int gr=row0+rg*4+ri; if (gr>=N) continue;
    #pragma unroll
    for (int ci=0;ci<4;ci++) vlinh[(size_t)gr*128+cg*4+ci]=f2b(a[ri][ci]);
  }
}

// -------------- F_mid: update_v(l) + lin(l+1) + linh(l+1) -------------------
__global__ __launch_bounds__(128) void f_mid(
    const float* __restrict__ accR, const float* __restrict__ accH,
    float* __restrict__ v,
    const float* __restrict__ v1w, const float* __restrict__ v1b,
    const float* __restrict__ v2w, const float* __restrict__ v2b,
    const float* __restrict__ vh1w, const float* __restrict__ vh1b,
    const float* __restrict__ vh2w, const float* __restrict__ vh2b,
    const float* __restrict__ cw, const float* __restrict__ cb,
    const float* __restrict__ linA, const float* __restrict__ linB,
    unsigned short* __restrict__ vlin, unsigned short* __restrict__ vlinh, int N){
  __shared__ float Xs[16][132];
  __shared__ float Ws[32][132];
  __shared__ float Os[16][132];
  int t=threadIdx.x; int row0=blockIdx.x*16; int rg=t&3, cg=t>>2;
  float a[4][4]; float a2[4][2];

  for (int path=0; path<2; path++){
    const float* X  = path? accH : accR;
    for (int idx=t; idx<512; idx+=128){
      int r=idx>>5, k4=(idx&31)*4; int gr=row0+r;
      float4 f = (gr<N)? *(const float4*)(X+(size_t)gr*128+k4) : make_float4(0,0,0,0);
      Xs[r][k4]=f.x; Xs[r][k4+1]=f.y; Xs[r][k4+2]=f.z; Xs[r][k4+3]=f.w;
    }
    mm128(Xs, Ws, path? vh1w:v1w, t, a);      // first internal sync covers staging
    const float* B1 = path? vh1b : v1b;
    #pragma unroll
    for (int ri=0;ri<4;ri++)
      #pragma unroll
      for (int ci=0;ci<4;ci++)
        Xs[rg*4+ri][cg*4+ci] = dssp(a[ri][ci] + B1[cg*4+ci]);
    mm64(Xs, Ws, path? vh2w:v2w, t, a2);
    const float* B2 = path? vh2b : v2b;
    #pragma unroll
    for (int ri=0;ri<4;ri++)
      #pragma unroll
      for (int ci=0;ci<2;ci++)
        Os[rg*4+ri][path*64+cg*2+ci] = a2[ri][ci] + B2[cg*2+ci];
  }
  mm128(Os, Ws, cw, t, a);
  float vn[4][4];
  #pragma unroll
  for (int ri=0;ri<4;ri++){
    int gr=row0+rg*4+ri;
    float4 vres = (gr<N)? *(const float4*)(v+(size_t)gr*128+cg*4) : make_float4(0,0,0,0);
    vn[ri][0] = vres.x + dssp(a[ri][0]+cb[cg*4+0]);
    vn[ri][1] = vres.y + dssp(a[ri][1]+cb[cg*4+1]);
    vn[ri][2] = vres.z + dssp(a[ri][2]+cb[cg*4+2]);
    vn[ri][3] = vres.w + dssp(a[ri][3]+cb[cg*4+3]);
    if (gr<N) *(float4*)(v+(size_t)gr*128+cg*4) = make_float4(vn[ri][0],vn[ri][1],vn[ri][2],vn[ri][3]);
    #pragma unroll
    for (int ci=0;ci<4;ci++) Xs[rg*4+ri][cg*4+ci] = vn[ri][ci];
  }
  mm128(Xs, Ws, linA, t, a);
  #pragma unroll
  for (int ri=0;ri<4;ri++){
    int gr=row0+rg*4+ri; if (gr>=N) continue;
    #pragma unroll
    for (int ci=0;ci<4;ci++) vlin[(size_t)gr*128+cg*4+ci]=f2b(a[ri][ci]);
  }
  mm128(Xs, Ws, linB, t, a);
  #pragma unroll
  for (int ri=0;ri<4;ri++){
    int gr=row0+rg*4+ri; if (gr>=N) continue;
    #pragma unroll
    for (int ci=0;ci<4;ci++) vlinh[(size_t)gr*128+cg*4+ci]=f2b(a[ri][ci]);
  }
}

// -------------- F_last: update_v(3) + readout (update_u) --------------------
__global__ __launch_bounds__(128) void f_last(
    const float* __restrict__ accR, const float* __restrict__ accH,
    const float* __restrict__ v,
    const float* __restrict__ v1w, const float* __restrict__ v1b,
    const float* __restrict__ v2w, const float* __restrict__ v2b,
    const float* __restrict__ vh1w, const float* __restrict__ vh1b,
    const float* __restrict__ vh2w, const float* __restrict__ vh2b,
    const float* __restrict__ cw, const float* __restrict__ cb,
    const float* __restrict__ u1w, const float* __restrict__ u1b,
    const float* __restrict__ u2w, const float* __restrict__ u2b,
    const int* __restrict__ batch, float* __restrict__ uacc, int N){
  __shared__ float Xs[16][132];
  __shared__ float Ws[32][132];
  __shared__ float Os[16][132];
  __shared__ float ss[16];
  __shared__ int   bb[16];
  int t=threadIdx.x; int row0=blockIdx.x*16; int rg=t&3, cg=t>>2;
  float a[4][4]; float a2[4][2];

  for (int path=0; path<2; path++){
    const float* X  = path? accH : accR;
    for (int idx=t; idx<512; idx+=128){
      int r=idx>>5, k4=(idx&31)*4; int gr=row0+r;
      float4 f = (gr<N)? *(const float4*)(X+(size_t)gr*128+k4) : make_float4(0,0,0,0);
      Xs[r][k4]=f.x; Xs[r][k4+1]=f.y; Xs[r][k4+2]=f.z; Xs[r][k4+3]=f.w;
    }
    mm128(Xs, Ws, path? vh1w:v1w, t, a);
    const float* B1 = path? vh1b : v1b;
    #pragma unroll
    for (int ri=0;ri<4;ri++)
      #pragma unroll
      for (int ci=0;ci<4;ci++)
        Xs[rg*4+ri][cg*4+ci] = dssp(a[ri][ci] + B1[cg*4+ci]);
    mm64(Xs, Ws, path? vh2w:v2w, t, a2);
    const float* B2 = path? vh2b : v2b;
    #pragma unroll
    for (int ri=0;ri<4;ri++)
      #pragma unroll
      for (int ci=0;ci<2;ci++)
        Os[rg*4+ri][path*64+cg*2+ci] = a2[ri][ci] + B2[cg*2+ci];
  }
  mm128(Os, Ws, cw, t, a);
  #pragma unroll
  for (int ri=0;ri<4;ri++){
    int gr=row0+rg*4+ri;
    float4 vres = (gr<N)? *(const float4*)(v+(size_t)gr*128+cg*4) : make_float4(0,0,0,0);
    Xs[rg*4+ri][cg*4+0] = vres.x + dssp(a[ri][0]+cb[cg*4+0]);
    Xs[rg*4+ri][cg*4+1] = vres.y + dssp(a[ri][1]+cb[cg*4+1]);
    Xs[rg*4+ri][cg*4+2] = vres.z + dssp(a[ri][2]+cb[cg*4+2]);
    Xs[rg*4+ri][cg*4+3] = vres.w + dssp(a[ri][3]+cb[cg*4+3]);
  }
  mm64(Xs, Ws, u1w, t, a2);
  #pragma unroll
  for (int ri=0;ri<4;ri++)
    #pragma unroll
    for (int ci=0;ci<2;ci++)
      Os[rg*4+ri][cg*2+ci] = dssp(a2[ri][ci] + u1b[cg*2+ci]);
  __syncthreads();
  if (t<16){
    int gr=row0+t;
    float s=0.f; int bt=-1;
    if (gr<N){
      s = u2b[0];
      for (int c=0;c<64;c++) s += Os[t][c]*u2w[c];
      bt = clampi(batch[gr],0,63);
    }
    ss[t]=s; bb[t]=bt;
  }
  __syncthreads();
  if (t==0){
    float run=0.f; int cur=-1;
    for (int q=0;q<16;q++){
      int bq=bb[q];
      if (bq<0) continue;
      if (bq!=cur){ if (cur>=0) atomicAdd(&uacc[cur],run); cur=bq; run=0.f; }
      run += ss[q];
    }
    if (cur>=0) atomicAdd(&uacc[cur],run);
  }
}

// -------------------- hull filter, all layers, sorted order -----------------
__global__ __launch_bounds__(128) void hull_all(const int2* __restrict__ spk_h,
    const float* __restrict__ fea,
    const float* __restrict__ mlph_w1, const float* __restrict__ mlph_b1,
    const float* __restrict__ mlph_w2, const float* __restrict__ mlph_b2,
    unsigned short* __restrict__ WhS_base, size_t lstride,
    int EH, int tilesPerLayer, int l0){
  int l    = l0 + blockIdx.x / tilesPerLayer;
  int tile = blockIdx.x % tilesPerLayer;
  int row0 = tile*16;
  const float* w1 = mlph_w1 + l*128*7;
  const float* b1 = mlph_b1 + l*128;
  const float* w2 = mlph_w2 + l*16384;
  const float* b2 = mlph_b2 + l*128;
  unsigned short* WhS = WhS_base + (size_t)(l-l0)*lstride;
  __shared__ float Fs[16][8];
  __shared__ float Xs[16][132];
  __shared__ float Ws[32][132];
  int t=threadIdx.x; int rg=t&3, cg=t>>2;
  if (t < 112){
    int r = t/7, k = t%7;
    int p = row0 + r;
    int eid = (p<EH) ? clampi(spk_h[p].y, 0, EH-1) : 0;
    Fs[r][k] = (p<EH) ? fea[(size_t)eid*7 + k] : 0.f;
  }
  __syncthreads();
  #pragma unroll
  for (int ri=0;ri<4;ri++){
    int r = rg*4+ri;
    #pragma unroll
    for (int ci=0;ci<4;ci++){
      int c = cg*4+ci;
      float s = b1[c];
      #pragma unroll
      for (int k=0;k<7;k++) s += Fs[r][k]*w1[c*7+k];
      Xs[r][c] = dssp(s);
    }
  }
  float a[4][4];
  mm128(Xs, Ws, w2, t, a);
  #pragma unroll
  for (int ri=0;ri<4;ri++){
    int p = row0+rg*4+ri;
    if (p>=EH) continue;
    #pragma unroll
    for (int ci=0;ci<4;ci++)
      WhS[(size_t)p*128+cg*4+ci] = f2b(a[ri][ci] + b2[cg*4+ci]);
  }
}

// ------------------------------ CSR segment reductions ----------------------
__global__ __launch_bounds__(128) void acc_both(
    const int* __restrict__ off_r, const int2* __restrict__ spk_r,
    const unsigned short* __restrict__ vlin, const unsigned short* __restrict__ Wt,
    float* __restrict__ accR,
    const int* __restrict__ off_h, const int2* __restrict__ spk_h,
    const unsigned short* __restrict__ vlinh, const unsigned short* __restrict__ WhS,
    float* __restrict__ accH,
    int Etot, int EHtot, int N){
  int f = threadIdx.x;
  if ((int)blockIdx.x < N){
    int n = blockIdx.x;
    int b = clampi(off_r[n], 0, Etot);
    int e = clampi(off_r[n+1], b, Etot);
    float a = 0.f;
    int p = b;
    for (; p+2<=e; p+=2){
      int2 kA = spk_r[p], kB = spk_r[p+1];
      float dA = __int_as_float(kA.y), dB = __int_as_float(kB.y);
      float xA = fminf(fmaxf(dA*(4096.0f/5.0f),0.f),4096.f);
      float xB = fminf(fmaxf(dB*(4096.0f/5.0f),0.f),4096.f);
      int iA=(int)xA; if(iA>TBL_K-1)iA=TBL_K-1;
      int iB=(int)xB; if(iB>TBL_K-1)iB=TBL_K-1;
      float frA=xA-(float)iA, frB=xB-(float)iB;
      float w0A=b2f16(Wt[(size_t)iA*128+f]),     w1A=b2f16(Wt[(size_t)iA*128+128+f]);
      float w0B=b2f16(Wt[(size_t)iB*128+f]),     w1B=b2f16(Wt[(size_t)iB*128+128+f]);
      float vA = b2f16(vlin[(size_t)clampi(kA.x,0,N-1)*128+f]);
      float vB = b2f16(vlin[(size_t)clampi(kB.x,0,N-1)*128+f]);
      a += vA*(w0A+frA*(w1A-w0A)) + vB*(w0B+frB*(w1B-w0B));
    }
    if (p<e){
      int2 kA = spk_r[p];
      float dA = __int_as_float(kA.y);
      float xA = fminf(fmaxf(dA*(4096.0f/5.0f),0.f),4096.f);
      int iA=(int)xA; if(iA>TBL_K-1)iA=TBL_K-1;
      float frA=xA-(float)iA;
      float w0A=b2f16(Wt[(size_t)iA*128+f]), w1A=b2f16(Wt[(size_t)iA*128+128+f]);
      float vA = b2f16(vlin[(size_t)clampi(kA.x,0,N-1)*128+f]);
      a += vA*(w0A+frA*(w1A-w0A));
    }
    accR[(size_t)n*128+f] = a;
  } else {
    int n = blockIdx.x - N;
    int b = clampi(off_h[n], 0, EHtot);
    int e = clampi(off_h[n+1], b, EHtot);
    float a = 0.f;
    int p = b;
    for (; p+2<=e; p+=2){
      int2 kA = spk_h[p], kB = spk_h[p+1];
      float vA = b2f16(vlinh[(size_t)clampi(kA.x,0,N-1)*128+f]);
      float vB = b2f16(vlinh[(size_t)clampi(kB.x,0,N-1)*128+f]);
      a += vA*b2f16(WhS[(size_t)p*128+f]) + vB*b2f16(WhS[(size_t)(p+1)*128+f]);
    }
    if (p<e){
      int2 kA = spk_h[p];
      float vA = b2f16(vlinh[(size_t)clampi(kA.x,0,N-1)*128+f]);
      a += vA*b2f16(WhS[(size_t)p*128+f]);
    }
    accH[(size_t)n*128+f] = a;
  }
}

__global__ void write_out(const float* __restrict__ uacc, void* out, const int* __restrict__ flag){
  int t = threadIdx.x;
  if (t < 64){
    if (*flag) ((bf16*)out)[t] = __float2bfloat16(uacc[t]);
    else       ((float*)out)[t] = uacc[t];
  }
}

// ----------------------------------------------------------------- launch ---
extern "C" void kernel_launch(void* const* d_in, const int* in_sizes, int n_in,
                              void* d_out, int out_size, void* d_ws, size_t ws_size,
                              hipStream_t stream){
  const int* z     = (const int*)d_in[0];
  const int* ei    = (const int*)d_in[1];
  const int* eih   = (const int*)d_in[2];
  const int* batch = (const int*)d_in[3];

  const int N  = in_sizes[0];
  const int E  = in_sizes[1]/2;
  const int EH = in_sizes[2]/2;

  char* wp = (char*)d_ws;
  auto alloc = [&](size_t bytes)->char*{
    char* p = wp; wp += (bytes + 255) & ~(size_t)255; return p;
  };
  int* flag    = (int*)alloc(256);
  int* cnt_r   = (int*)alloc((size_t)N*4);
  int* off_r   = (int*)alloc((size_t)(N+1)*4);
  int* cur_r   = (int*)alloc((size_t)N*4);
  int* cnt_h   = (int*)alloc((size_t)N*4);
  int* off_h   = (int*)alloc((size_t)(N+1)*4);
  int* cur_h   = (int*)alloc((size_t)N*4);
  int2* spk_r  = (int2*)alloc((size_t)E*8);
  int2* spk_h  = (int2*)alloc((size_t)EH*8);
  float* uacc  = (float*)alloc(64*4);

  SegTable tbl; tbl.count = 27; tbl.total = 0;
  float* cvt[27];
  for (int i=0;i<27;i++){
    int n = in_sizes[4+i];
    cvt[i] = (float*)alloc((size_t)n*4);
    tbl.s[i].src = d_in[4+i];
    tbl.s[i].dst = cvt[i];
    tbl.s[i].n   = n;
    tbl.total   += n;
  }
  const float* distc   = cvt[0];
  const float* feac    = cvt[1];
  const float* embc    = cvt[2];
  const float* lin_w   = cvt[3];
  const float* mlp_w1  = cvt[4];
  const float* mlp_b1  = cvt[5];
  const float* mlp_w2  = cvt[6];
  const float* mlp_b2  = cvt[7];
  const float* linh_w  = cvt[8];
  const float* mlph_w1 = cvt[9];
  const float* mlph_b1 = cvt[10];
  const float* mlph_w2 = cvt[11];
  const float* mlph_b2 = cvt[12];
  const float* v1_w  = cvt[13];
  const float* v1_b  = cvt[14];
  const float* v2_w  = cvt[15];
  const float* v2_b  = cvt[16];
  const float* vh1_w = cvt[17];
  const float* vh1_b = cvt[18];
  const float* vh2_w = cvt[19];
  const float* vh2_b = cvt[20];
  const float* cat_w = cvt[21];
  const float* cat_b = cvt[22];
  const float* u1_w  = cvt[23];
  const float* u1_b  = cvt[24];
  const float* u2_w  = cvt[25];
  const float* u2_b  = cvt[26];

  unsigned short* Wtab = (unsigned short*)alloc((size_t)4*TBL_ROWS*128*2);
  float* v     = (float*)alloc((size_t)N*128*4);
  unsigned short* vlin  = (unsigned short*)alloc((size_t)N*128*2);
  unsigned short* vlinh = (unsigned short*)alloc((size_t)N*128*2);
  float* accR  = (float*)alloc((size_t)N*128*4);
  float* accH  = (float*)alloc((size_t)N*128*4);

  // WhS: all 4 layers if workspace allows, else one layer recomputed per layer
  size_t used = (size_t)(wp - (char*)d_ws);
  size_t whs4 = (size_t)4*EH*128*2 + 256;
  bool pre = (ws_size >= used + whs4);
  unsigned short* WhS = (unsigned short*)alloc(pre ? (size_t)4*EH*128*2 : (size_t)EH*128*2);

  detect_mode<<<1,256,0,stream>>>((const unsigned*)d_in[6], flag);
  {
    int cb = (int)((tbl.total + 255)/256);
    if (cb > 4096) cb = 4096;
    convert_all<<<cb,256,0,stream>>>(tbl, flag);
  }
  int nb;
  nb = (E+255)/256;     init_all<<<nb,256,0,stream>>>(cnt_r,cnt_h,uacc,spk_r,spk_h,N,E,EH);
  nb = (E+255)/256;     count_edges<<<nb,256,0,stream>>>(ei,eih,E,EH,N,cnt_r,cnt_h);
  scan_pair<<<1,256,0,stream>>>(cnt_r,off_r,cur_r,cnt_h,off_h,cur_h,N);
  nb = (E+255)/256;     scatter_edges<<<nb,256,0,stream>>>(ei,distc,eih,E,EH,N,cur_r,cur_h,spk_r,spk_h);
  build_wtab<<<4*TBL_TILES,256,0,stream>>>(mlp_w1,mlp_b1,mlp_w2,mlp_b2,Wtab);

  const int nt = (N+15)/16;
  const int ht = (EH+15)/16;
  if (pre)
    hull_all<<<4*ht,128,0,stream>>>(spk_h, feac, mlph_w1, mlph_b1, mlph_w2, mlph_b2,
                                    WhS, (size_t)EH*128, EH, ht, 0);

  f_first<<<nt,128,0,stream>>>(z, embc, v, lin_w, linh_w, vlin, vlinh, N);
  for (int l=0;l<4;l++){
    if (!pre)
      hull_all<<<ht,128,0,stream>>>(spk_h, feac, mlph_w1, mlph_b1, mlph_w2, mlph_b2,
                                    WhS, 0, EH, ht, l);
    const unsigned short* WhSl = pre ? (WhS + (size_t)l*EH*128) : WhS;
    acc_both<<<2*N,128,0,stream>>>(off_r, spk_r, vlin, Wtab + (size_t)l*TBL_ROWS*128, accR,
                                   off_h, spk_h, vlinh, WhSl, accH, E, EH, N);
    if (l<3){
      f_mid<<<nt,128,0,stream>>>(accR, accH, v,
          v1_w + l*16384, v1_b + l*128, v2_w + l*8192, v2_b + l*64,
          vh1_w + l*16384, vh1_b + l*128, vh2_w + l*8192, vh2_b + l*64,
          cat_w + l*16384, cat_b + l*128,
          lin_w + (l+1)*16384, linh_w + (l+1)*16384, vlin, vlinh, N);
    } else {
      f_last<<<nt,128,0,stream>>>(accR, accH, v,
          v1_w + l*16384, v1_b + l*128, v2_w + l*8192, v2_b + l*64,
          vh1_w + l*16384, vh1_b + l*128, vh2_w + l*8192, vh2_b + l*64,
          cat_w + l*16384, cat_b + l*128,
          u1_w, u1_b, u2_w, u2_b, batch, uacc, N);
    }
  }
  write_out<<<1,64,0,stream>>>(uacc, d_out, flag);
}

// Round 6
// 708.702 us; speedup vs baseline: 1.4017x; 1.4017x over previous
//
#include <hip/hip_runtime.h>
#include <hip/hip_bf16.h>

typedef __hip_bfloat16 bf16;
typedef __attribute__((ext_vector_type(8))) short short8;   // 8 bf16 (4 VGPRs)
typedef __attribute__((ext_vector_type(4))) float f32x4;

__device__ __forceinline__ float dssp(float x){
  return fmaxf(x, 0.f) + log1pf(expf(-fabsf(x))) - 0.693147180559945f;
}
__device__ __forceinline__ int clampi(int x, int lo, int hi){ return x<lo?lo:(x>hi?hi:x); }
__device__ __forceinline__ unsigned short f2b(float f){
  unsigned x = __float_as_uint(f);
  return (unsigned short)((x + 0x7fffu + ((x>>16)&1u)) >> 16);
}
__device__ __forceinline__ float b2f16(unsigned short u){ return __uint_as_float(((unsigned)u)<<16); }

constexpr int TBL_K    = 4096;
constexpr int TBL_ROWS = TBL_K + 1;
constexpr int TBL_TILES = (TBL_ROWS + 31) / 32;  // 129

// ------------------------------------------------- dtype detection ----------
__global__ void detect_mode(const unsigned* __restrict__ raw, int* flag){
  __shared__ int c;
  int t = threadIdx.x;
  if (t==0) c = 0;
  __syncthreads();
  unsigned u  = raw[t];
  unsigned lo = u & 0xFFFFu;
  int e = (int)((lo >> 7) & 0xFF);
  int ok = (lo==0u) || (e >= 0x70 && e <= 0x8F);
  atomicAdd(&c, ok);
  __syncthreads();
  if (t==0) *flag = (c >= 160) ? 1 : 0;   // 1 = bf16 storage, 0 = f32 storage
}

// ---------------------------------------------- canonical fp32 conversion ---
struct Seg { const void* src; float* dst; int n; };
struct SegTable { Seg s[27]; int count; long total; };

__global__ void convert_all(SegTable tbl, const int* __restrict__ flag){
  int mode = *flag;
  long tid    = (long)blockIdx.x*blockDim.x + threadIdx.x;
  long stride = (long)gridDim.x*blockDim.x;
  for (long i=tid; i<tbl.total; i+=stride){
    long off = i; int k = 0;
    while (k < tbl.count-1 && off >= tbl.s[k].n){ off -= tbl.s[k].n; k++; }
    float f;
    if (mode) f = __bfloat162float(((const bf16*)tbl.s[k].src)[off]);
    else      f = ((const float*)tbl.s[k].src)[off];
    tbl.s[k].dst[off] = (f==f) ? f : 0.f;
  }
}

// ---------------------------------------- bf16 weight copies for MFMA -------
struct WSeg { const float* src; unsigned short* dst; int n; };
struct WTable { WSeg s[9]; int count; int total; };

__global__ void convert_wb(WTable wt){
  int tid = blockIdx.x*blockDim.x + threadIdx.x;
  if (tid >= wt.total) return;
  int off = tid, k = 0;
  while (k < wt.count-1 && off >= wt.s[k].n){ off -= wt.s[k].n; k++; }
  wt.s[k].dst[off] = f2b(wt.s[k].src[off]);
}

// ------------------------------------------------------------------ setup ---
__global__ void init_all(int* cnt_r, int* cnt_h, float* uacc,
                         int2* spk_r, int2* spk_h, int N, int E, int EH){
  int t = blockIdx.x*blockDim.x + threadIdx.x;
  if (t < N){ cnt_r[t]=0; cnt_h[t]=0; }
  if (t < 64) uacc[t]=0.f;
  if (t < E)  spk_r[t]=make_int2(0,0);
  if (t < EH) spk_h[t]=make_int2(0,0);
}

__global__ void count_edges(const int* __restrict__ ei, const int* __restrict__ eih,
                            int E, int EH, int N, int* cnt_r, int* cnt_h){
  int t = blockIdx.x*blockDim.x + threadIdx.x;
  if (t < E)  atomicAdd(&cnt_r[clampi(ei[E + t], 0, N-1)], 1);
  if (t < EH) atomicAdd(&cnt_h[clampi(eih[EH + t], 0, N-1)], 1);
}

__global__ __launch_bounds__(256) void scan_pair(const int* cnt_r, int* off_r, int* cur_r,
                                                 const int* cnt_h, int* off_h, int* cur_h, int N){
  __shared__ int s[256];
  int t = threadIdx.x;
  int CH = (N + 255) / 256;
  for (int which=0; which<2; which++){
    const int* cnt = which? cnt_h : cnt_r;
    int* off = which? off_h : off_r;
    int* cur = which? cur_h : cur_r;
    int base = t*CH;
    int sum = 0;
    for (int q=0;q<CH;q++){ int idx=base+q; sum += (idx<N)? cnt[idx] : 0; }
    __syncthreads();
    s[t]=sum; __syncthreads();
    for (int ofs=1; ofs<256; ofs<<=1){
      int v = s[t]; int vp = (t>=ofs)? s[t-ofs] : 0;
      __syncthreads(); s[t]=v+vp; __syncthreads();
    }
    int run = (t>0)? s[t-1] : 0;
    for (int q=0;q<CH;q++){
      int idx=base+q;
      if (idx<N){ off[idx]=run; cur[idx]=run; run += cnt[idx]; }
    }
    if (t==255) off[N] = s[255];
  }
}

__global__ void scatter_edges(const int* __restrict__ ei, const float* __restrict__ distc,
                              const int* __restrict__ eih, int E, int EH, int N,
                              int* cur_r, int* cur_h, int2* spk_r, int2* spk_h){
  int t = blockIdx.x*blockDim.x + threadIdx.x;
  if (t < E){
    int i = clampi(ei[E+t], 0, N-1);
    int p = clampi(atomicAdd(&cur_r[i], 1), 0, E-1);
    spk_r[p] = make_int2(clampi(ei[t],0,N-1), __float_as_int(distc[t]));
  }
  if (t < EH){
    int ih = clampi(eih[EH+t], 0, N-1);
    int p = clampi(atomicAdd(&cur_h[ih], 1), 0, EH-1);
    spk_h[p] = make_int2(clampi(eih[t],0,N-1), t);
  }
}

// --------------------------------------------- W(dist) lookup table (bf16) ---
__global__ __launch_bounds__(256) void build_wtab(const float* __restrict__ mlp_w1,
    const float* __restrict__ mlp_b1, const float* __restrict__ mlp_w2,
    const float* __restrict__ mlp_b2, unsigned short* __restrict__ Wtab){
  int l    = blockIdx.x / TBL_TILES;
  int tile = blockIdx.x % TBL_TILES;
  int row0 = tile * 32;
  const float* w1 = mlp_w1 + l*128*25;
  const float* b1 = mlp_b1 + l*128;
  const float* w2 = mlp_w2 + l*128*128;
  const float* b2 = mlp_b2 + l*128;
  __shared__ float Gs[32][26];
  __shared__ float Ts[32][129];
  __shared__ float Ws[32][129];
  int t = threadIdx.x;
  for (int idx=t; idx<32*25; idx+=256){
    int r = idx/25, k = idx%25;
    float d = (row0+r) * (5.0f/4096.0f);
    float x = d - (float)k*(5.0f/24.0f);
    Gs[r][k] = expf(-11.52f*x*x);
  }
  __syncthreads();
  int rg = t&7, cg = t>>3;
  #pragma unroll
  for (int ri=0;ri<4;ri++){
    int r = rg*4+ri;
    #pragma unroll
    for (int ci=0;ci<4;ci++){
      int c = cg*4+ci;
      float s = b1[c];
      for (int k=0;k<25;k++) s += Gs[r][k]*w1[c*25+k];
      Ts[r][c] = dssp(s);
    }
  }
  float acc[4][4] = {};
  for (int k0=0;k0<128;k0+=32){
    __syncthreads();
    for (int idx=t; idx<1024; idx+=256){
      int c=idx>>3, kk4=(idx&7)*4;
      float4 f = *(const float4*)(w2+(size_t)c*128+k0+kk4);
      Ws[kk4][c]=f.x; Ws[kk4+1][c]=f.y; Ws[kk4+2][c]=f.z; Ws[kk4+3][c]=f.w;
    }
    __syncthreads();
    for (int kk=0;kk<32;kk++){
      float xv[4];
      #pragma unroll
      for (int ri=0;ri<4;ri++) xv[ri]=Ts[rg*4+ri][k0+kk];
      #pragma unroll
      for (int ci=0;ci<4;ci++){
        float wv = Ws[kk][cg*4+ci];
        #pragma unroll
        for (int ri=0;ri<4;ri++) acc[ri][ci] += xv[ri]*wv;
      }
    }
  }
  #pragma unroll
  for (int ri=0;ri<4;ri++){
    int r = row0 + rg*4 + ri;
    if (r >= TBL_ROWS) continue;
    float d  = r * (5.0f/4096.0f);
    float Cf = 0.5f*(cosf(d*(3.14159265358979f/5.0f))+1.0f);
    #pragma unroll
    for (int ci=0;ci<4;ci++){
      int c = cg*4+ci;
      Wtab[((size_t)l*TBL_ROWS + r)*128 + c] = f2b((acc[ri][ci] + b2[c]) * Cf);
    }
  }
}

// pack rows r,r+1 into one uint (lo=w(r), hi=w(r+1)) per [l][r][f], r<4096
__global__ void pack_wtab(const unsigned short* __restrict__ Wtab, unsigned* __restrict__ Wpk){
  long t = (long)blockIdx.x*blockDim.x + threadIdx.x;
  const long TOT = 4L*TBL_K*128;
  if (t < TOT){
    int l = (int)(t / ((long)TBL_K*128));
    long rem = t % ((long)TBL_K*128);
    int r = (int)(rem >> 7), f = (int)(rem & 127);
    const unsigned short* base = Wtab + (size_t)l*TBL_ROWS*128;
    Wpk[t] = (((unsigned)base[(size_t)(r+1)*128+f])<<16) | (unsigned)base[(size_t)r*128+f];
  }
}

// ------------------------------ MFMA tile helpers ---------------------------
// Block = 128 threads = 2 waves. A-tile = 16 rows (fp32 in LDS, stride 132).
// A-frag: A[m=lane&15][k=quad*8+j]; B-frag: W[c=lane&15][k=quad*8+j] (bf16 global);
// C/D: row=quad*4+reg, col=lane&15  [m89/m120 verified mappings].
__device__ __forceinline__ short8 afrag(const float (*Xs)[132], int lane, int k0){
  int m = lane&15, q = (lane>>4)&3;
  const float* p = &Xs[m][k0 + q*8];
  float4 f0 = *(const float4*)(p);
  float4 f1 = *(const float4*)(p+4);
  short8 r;
  r[0]=(short)f2b(f0.x); r[1]=(short)f2b(f0.y); r[2]=(short)f2b(f0.z); r[3]=(short)f2b(f0.w);
  r[4]=(short)f2b(f1.x); r[5]=(short)f2b(f1.y); r[6]=(short)f2b(f1.z); r[7]=(short)f2b(f1.w);
  return r;
}
__device__ __forceinline__ short8 bfrag(const unsigned short* __restrict__ W,
                                        int cbase, int lane, int k0){
  int n = lane&15, q = (lane>>4)&3;
  return *(const short8*)(W + (size_t)(cbase+n)*128 + k0 + q*8);
}
// ntiles=4 -> 128-col GEMM (wave w covers cols w*64..+63); ntiles=2 -> 64-col.
template<int NT>
__device__ __forceinline__ void mfma_gemm(const float (*Xs)[132],
    const unsigned short* __restrict__ W, int t, f32x4 d[NT]){
  int lane = t&63, w = t>>6;
  #pragma unroll
  for (int ct=0;ct<NT;ct++) d[ct]=(f32x4){0.f,0.f,0.f,0.f};
  #pragma unroll
  for (int kc=0;kc<4;kc++){
    short8 a = afrag(Xs, lane, kc*32);
    #pragma unroll
    for (int ct=0;ct<NT;ct++){
      short8 b = bfrag(W, w*(NT*16)+ct*16, lane, kc*32);
      d[ct] = __builtin_amdgcn_mfma_f32_16x16x32_bf16(a, b, d[ct], 0, 0, 0);
    }
  }
}
template<int NT>
__device__ __forceinline__ void dstore_lds(float (*Ys)[132], const f32x4 d[NT], int t,
    int colofs, const float* __restrict__ bias, int do_ssp){
  int lane=t&63, w=t>>6, q=(lane>>4)&3, n=lane&15;
  #pragma unroll
  for (int ct=0;ct<NT;ct++){
    int c = w*(NT*16)+ct*16+n;
    float bv = bias ? bias[c] : 0.f;
    #pragma unroll
    for (int i=0;i<4;i++){
      float y = d[ct][i] + bv;
      if (do_ssp) y = dssp(y);
      Ys[q*4+i][colofs + c] = y;
    }
  }
}
// scatter D (bf16) to row-major [*,128] global, row-bounds-checked
__device__ __forceinline__ void scatter_bf16(unsigned short* __restrict__ out,
    const f32x4 d[4], int t, int row0, int N){
  int lane=t&63, w=t>>6, q=(lane>>4)&3, n=lane&15;
  #pragma unroll
  for (int ct=0;ct<4;ct++){
    int c = w*64+ct*16+n;
    #pragma unroll
    for (int i=0;i<4;i++){
      int gr = row0 + q*4 + i;
      if (gr<N) out[(size_t)gr*128 + c] = f2b(d[ct][i]);
    }
  }
}

// ------------------------- F0: embed + lin + linh ---------------------------
__global__ __launch_bounds__(128) void f_first(const int* __restrict__ z,
    const float* __restrict__ emb, float* __restrict__ v,
    const unsigned short* __restrict__ linA, const unsigned short* __restrict__ linB,
    unsigned short* __restrict__ vlin, unsigned short* __restrict__ vlinh, int N){
  __shared__ float Xs[16][132];
  int t=threadIdx.x; int row0=blockIdx.x*16;
  f32x4 d[4];
  for (int idx=t; idx<512; idx+=128){
    int r=idx>>5, k4=(idx&31)*4; int gr=row0+r;
    int zz=(gr<N)? clampi(z[gr],0,99):0;
    float4 f = *(const float4*)(emb + (size_t)zz*128 + k4);
    Xs[r][k4]=f.x; Xs[r][k4+1]=f.y; Xs[r][k4+2]=f.z; Xs[r][k4+3]=f.w;
    if (gr<N) *(float4*)(v + (size_t)gr*128 + k4) = f;
  }
  __syncthreads();
  mfma_gemm<4>(Xs, linA, t, d);
  scatter_bf16(vlin, d, t, row0, N);
  mfma_gemm<4>(Xs, linB, t, d);
  scatter_bf16(vlinh, d, t, row0, N);
}

// -------------- F_mid: update_v(l) + lin(l+1) + linh(l+1) -------------------
__global__ __launch_bounds__(128) void f_mid(
    const float* __restrict__ accR, const float* __restrict__ accH,
    float* __restrict__ v,
    const unsigned short* __restrict__ v1w, const float* __restrict__ v1b,
    const unsigned short* __restrict__ v2w, const float* __restrict__ v2b,
    const unsigned short* __restrict__ vh1w, const float* __restrict__ vh1b,
    const unsigned short* __restrict__ vh2w, const float* __restrict__ vh2b,
    const unsigned short* __restrict__ cw, const float* __restrict__ cb,
    const unsigned short* __restrict__ linA, const unsigned short* __restrict__ linB,
    unsigned short* __restrict__ vlin, unsigned short* __restrict__ vlinh, int N){
  __shared__ float Xs[16][132];
  __shared__ float Ys[16][132];
  __shared__ float Os[16][132];
  int t=threadIdx.x; int row0=blockIdx.x*16;
  f32x4 d[4]; f32x4 d2[2];

  for (int path=0; path<2; path++){
    const float* X = path? accH : accR;
    for (int idx=t; idx<512; idx+=128){
      int r=idx>>5, k4=(idx&31)*4; int gr=row0+r;
      float4 f=(gr<N)? *(const float4*)(X+(size_t)gr*128+k4):make_float4(0,0,0,0);
      Xs[r][k4]=f.x; Xs[r][k4+1]=f.y; Xs[r][k4+2]=f.z; Xs[r][k4+3]=f.w;
    }
    __syncthreads();
    mfma_gemm<4>(Xs, path?vh1w:v1w, t, d);
    dstore_lds<4>(Ys, d, t, 0, path?vh1b:v1b, 1);
    __syncthreads();
    mfma_gemm<2>(Ys, path?vh2w:v2w, t, d2);
    dstore_lds<2>(Os, d2, t, path*64, path?vh2b:v2b, 0);
    __syncthreads();
  }
  mfma_gemm<4>(Os, cw, t, d);
  dstore_lds<4>(Ys, d, t, 0, cb, 1);       // Ys = dssp(cat + cb)
  __syncthreads();
  for (int idx=t; idx<512; idx+=128){      // v += Ys ; Xs = new v
    int r=idx>>5, k4=(idx&31)*4; int gr=row0+r;
    float4 f=(gr<N)? *(const float4*)(v+(size_t)gr*128+k4):make_float4(0,0,0,0);
    f.x+=Ys[r][k4]; f.y+=Ys[r][k4+1]; f.z+=Ys[r][k4+2]; f.w+=Ys[r][k4+3];
    if (gr<N) *(float4*)(v+(size_t)gr*128+k4)=f;
    Xs[r][k4]=f.x; Xs[r][k4+1]=f.y; Xs[r][k4+2]=f.z; Xs[r][k4+3]=f.w;
  }
  __syncthreads();
  mfma_gemm<4>(Xs, linA, t, d);
  scatter_bf16(vlin, d, t, row0, N);
  mfma_gemm<4>(Xs, linB, t, d);
  scatter_bf16(vlinh, d, t, row0, N);
}

// -------------- F_last: update_v(3) + readout (update_u) --------------------
__global__ __launch_bounds__(128) void f_last(
    const float* __restrict__ accR, const float* __restrict__ accH,
    const float* __restrict__ v,
    const unsigned short* __restrict__ v1w, const float* __restrict__ v1b,
    const unsigned short* __restrict__ v2w, const float* __restrict__ v2b,
    const unsigned short* __restrict__ vh1w, const float* __restrict__ vh1b,
    const unsigned short* __restrict__ vh2w, const float* __restrict__ vh2b,
    const unsigned short* __restrict__ cw, const float* __restrict__ cb,
    const unsigned short* __restrict__ u1w, const float* __restrict__ u1b,
    const float* __restrict__ u2w, const float* __restrict__ u2b,
    const int* __restrict__ batch, float* __restrict__ uacc, int N){
  __shared__ float Xs[16][132];
  __shared__ float Ys[16][132];
  __shared__ float Os[16][132];
  __shared__ float ss[16];
  __shared__ int   bb[16];
  int t=threadIdx.x; int row0=blockIdx.x*16;
  f32x4 d[4]; f32x4 d2[2];

  for (int path=0; path<2; path++){
    const float* X = path? accH : accR;
    for (int idx=t; idx<512; idx+=128){
      int r=idx>>5, k4=(idx&31)*4; int gr=row0+r;
      float4 f=(gr<N)? *(const float4*)(X+(size_t)gr*128+k4):make_float4(0,0,0,0);
      Xs[r][k4]=f.x; Xs[r][k4+1]=f.y; Xs[r][k4+2]=f.z; Xs[r][k4+3]=f.w;
    }
    __syncthreads();
    mfma_gemm<4>(Xs, path?vh1w:v1w, t, d);
    dstore_lds<4>(Ys, d, t, 0, path?vh1b:v1b, 1);
    __syncthreads();
    mfma_gemm<2>(Ys, path?vh2w:v2w, t, d2);
    dstore_lds<2>(Os, d2, t, path*64, path?vh2b:v2b, 0);
    __syncthreads();
  }
  mfma_gemm<4>(Os, cw, t, d);
  dstore_lds<4>(Ys, d, t, 0, cb, 1);
  __syncthreads();
  for (int idx=t; idx<512; idx+=128){      // Xs = v + dssp(cat)
    int r=idx>>5, k4=(idx&31)*4; int gr=row0+r;
    float4 f=(gr<N)? *(const float4*)(v+(size_t)gr*128+k4):make_float4(0,0,0,0);
    Xs[r][k4]=f.x+Ys[r][k4]; Xs[r][k4+1]=f.y+Ys[r][k4+1];
    Xs[r][k4+2]=f.z+Ys[r][k4+2]; Xs[r][k4+3]=f.w+Ys[r][k4+3];
  }
  __syncthreads();
  mfma_gemm<2>(Xs, u1w, t, d2);            // 64 cols
  dstore_lds<2>(Os, d2, t, 0, u1b, 1);     // Os[:, 0..63] = dssp(u1)
  __syncthreads();
  if (t<16){
    int gr=row0+t;
    float s=0.f; int bt=-1;
    if (gr<N){
      s = u2b[0];
      for (int c=0;c<64;c++) s += Os[t][c]*u2w[c];
      bt = clampi(batch[gr],0,63);
    }
    ss[t]=s; bb[t]=bt;
  }
  __syncthreads();
  if (t==0){
    float run=0.f; int cur=-1;
    for (int q=0;q<16;q++){
      int bq=bb[q];
      if (bq<0) continue;
      if (bq!=cur){ if (cur>=0) atomicAdd(&uacc[cur],run); cur=bq; run=0.f; }
      run += ss[q];
    }
    if (cur>=0) atomicAdd(&uacc[cur],run);
  }
}

// -------------------- hull filter, all layers, sorted order -----------------
__global__ __launch_bounds__(128) void hull_all(const int2* __restrict__ spk_h,
    const float* __restrict__ fea,
    const float* __restrict__ mlph_w1, const float* __restrict__ mlph_b1,
    const unsigned short* __restrict__ mlph_w2b, const float* __restrict__ mlph_b2,
    unsigned short* __restrict__ WhS_base, size_t lstride,
    int EH, int tilesPerLayer, int l0){
  int l    = l0 + blockIdx.x / tilesPerLayer;
  int tile = blockIdx.x % tilesPerLayer;
  int row0 = tile*16;
  const float* w1 = mlph_w1 + l*128*7;
  const float* b1 = mlph_b1 + l*128;
  const unsigned short* w2 = mlph_w2b + (size_t)l*16384;
  const float* b2 = mlph_b2 + l*128;
  unsigned short* WhS = WhS_base + (size_t)(l-l0)*lstride;
  __shared__ float Fs[16][8];
  __shared__ float Xs[16][132];
  int t=threadIdx.x; int rg=t&3, cg=t>>2;
  if (t < 112){
    int r = t/7, k = t%7;
    int p = row0 + r;
    int eid = (p<EH) ? clampi(spk_h[p].y, 0, EH-1) : 0;
    Fs[r][k] = (p<EH) ? fea[(size_t)eid*7 + k] : 0.f;
  }
  __syncthreads();
  #pragma unroll
  for (int ri=0;ri<4;ri++){
    int r = rg*4+ri;
    #pragma unroll
    for (int ci=0;ci<4;ci++){
      int c = cg*4+ci;
      float s = b1[c];
      #pragma unroll
      for (int k=0;k<7;k++) s += Fs[r][k]*w1[c*7+k];
      Xs[r][c] = dssp(s);
    }
  }
  __syncthreads();
  f32x4 d[4];
  mfma_gemm<4>(Xs, w2, t, d);
  int lane=t&63, w=t>>6, q=(lane>>4)&3, n=lane&15;
  #pragma unroll
  for (int ct=0;ct<4;ct++){
    int c = w*64+ct*16+n;
    float bv = b2[c];
    #pragma unroll
    for (int i=0;i<4;i++){
      int p = row0 + q*4 + i;
      if (p<EH) WhS[(size_t)p*128 + c] = f2b(d[ct][i] + bv);
    }
  }
}

// ------------------------------ CSR segment reductions ----------------------
__global__ __launch_bounds__(128) void acc_both(
    const int* __restrict__ off_r, const int2* __restrict__ spk_r,
    const unsigned short* __restrict__ vlin, const unsigned* __restrict__ Wpk,
    float* __restrict__ accR,
    const int* __restrict__ off_h, const int2* __restrict__ spk_h,
    const unsigned short* __restrict__ vlinh, const unsigned short* __restrict__ WhS,
    float* __restrict__ accH,
    int Etot, int EHtot, int N){
  int f = threadIdx.x;
  if ((int)blockIdx.x < N){
    int n = blockIdx.x;
    int b = clampi(off_r[n], 0, Etot);
    int e = clampi(off_r[n+1], b, Etot);
    float a = 0.f;
    int p = b;
    for (; p+2<=e; p+=2){
      int2 kA = spk_r[p], kB = spk_r[p+1];
      float dA = __int_as_float(kA.y), dB = __int_as_float(kB.y);
      float xA = fminf(fmaxf(dA*(4096.0f/5.0f),0.f),4096.f);
      float xB = fminf(fmaxf(dB*(4096.0f/5.0f),0.f),4096.f);
      int iA=(int)xA; if(iA>TBL_K-1)iA=TBL_K-1;
      int iB=(int)xB; if(iB>TBL_K-1)iB=TBL_K-1;
      float frA=xA-(float)iA, frB=xB-(float)iB;
      unsigned uA = Wpk[(size_t)iA*128+f];
      unsigned uB = Wpk[(size_t)iB*128+f];
      float vA = b2f16(vlin[(size_t)clampi(kA.x,0,N-1)*128+f]);
      float vB = b2f16(vlin[(size_t)clampi(kB.x,0,N-1)*128+f]);
      float w0A=b2f16((unsigned short)(uA&0xFFFFu)), w1A=b2f16((unsigned short)(uA>>16));
      float w0B=b2f16((unsigned short)(uB&0xFFFFu)), w1B=b2f16((unsigned short)(uB>>16));
      a += vA*(w0A+frA*(w1A-w0A)) + vB*(w0B+frB*(w1B-w0B));
    }
    if (p<e){
      int2 kA = spk_r[p];
      float dA = __int_as_float(kA.y);
      float xA = fminf(fmaxf(dA*(4096.0f/5.0f),0.f),4096.f);
      int iA=(int)xA; if(iA>TBL_K-1)iA=TBL_K-1;
      float frA=xA-(float)iA;
      unsigned uA = Wpk[(size_t)iA*128+f];
      float vA = b2f16(vlin[(size_t)clampi(kA.x,0,N-1)*128+f]);
      float w0A=b2f16((unsigned short)(uA&0xFFFFu)), w1A=b2f16((unsigned short)(uA>>16));
      a += vA*(w0A+frA*(w1A-w0A));
    }
    accR[(size_t)n*128+f] = a;
  } else {
    int n = blockIdx.x - N;
    int b = clampi(off_h[n], 0, EHtot);
    int e = clampi(off_h[n+1], b, EHtot);
    float a = 0.f;
    int p = b;
    for (; p+2<=e; p+=2){
      int2 kA = spk_h[p], kB = spk_h[p+1];
      float vA = b2f16(vlinh[(size_t)clampi(kA.x,0,N-1)*128+f]);
      float vB = b2f16(vlinh[(size_t)clampi(kB.x,0,N-1)*128+f]);
      a += vA*b2f16(WhS[(size_t)p*128+f]) + vB*b2f16(WhS[(size_t)(p+1)*128+f]);
    }
    if (p<e){
      int2 kA = spk_h[p];
      float vA = b2f16(vlinh[(size_t)clampi(kA.x,0,N-1)*128+f]);
      a += vA*b2f16(WhS[(size_t)p*128+f]);
    }
    accH[(size_t)n*128+f] = a;
  }
}

__global__ void write_out(const float* __restrict__ uacc, void* out, const int* __restrict__ flag){
  int t = threadIdx.x;
  if (t < 64){
    if (*flag) ((bf16*)out)[t] = __float2bfloat16(uacc[t]);
    else       ((float*)out)[t] = uacc[t];
  }
}

// ----------------------------------------------------------------- launch ---
extern "C" void kernel_launch(void* const* d_in, const int* in_sizes, int n_in,
                              void* d_out, int out_size, void* d_ws, size_t ws_size,
                              hipStream_t stream){
  const int* z     = (const int*)d_in[0];
  const int* ei    = (const int*)d_in[1];
  const int* eih   = (const int*)d_in[2];
  const int* batch = (const int*)d_in[3];

  const int N  = in_sizes[0];
  const int E  = in_sizes[1]/2;
  const int EH = in_sizes[2]/2;

  char* wp = (char*)d_ws;
  auto alloc = [&](size_t bytes)->char*{
    char* p = wp; wp += (bytes + 255) & ~(size_t)255; return p;
  };
  int* flag    = (int*)alloc(256);
  int* cnt_r   = (int*)alloc((size_t)N*4);
  int* off_r   = (int*)alloc((size_t)(N+1)*4);
  int* cur_r   = (int*)alloc((size_t)N*4);
  int* cnt_h   = (int*)alloc((size_t)N*4);
  int* off_h   = (int*)alloc((size_t)(N+1)*4);
  int* cur_h   = (int*)alloc((size_t)N*4);
  int2* spk_r  = (int2*)alloc((size_t)E*8);
  int2* spk_h  = (int2*)alloc((size_t)EH*8);
  float* uacc  = (float*)alloc(64*4);

  SegTable tbl; tbl.count = 27; tbl.total = 0;
  float* cvt[27];
  for (int i=0;i<27;i++){
    int n = in_sizes[4+i];
    cvt[i] = (float*)alloc((size_t)n*4);
    tbl.s[i].src = d_in[4+i];
    tbl.s[i].dst = cvt[i];
    tbl.s[i].n   = n;
    tbl.total   += n;
  }
  const float* distc   = cvt[0];
  const float* feac    = cvt[1];
  const float* embc    = cvt[2];
  const float* mlp_w1  = cvt[4];
  const float* mlp_b1  = cvt[5];
  const float* mlp_w2  = cvt[6];
  const float* mlp_b2  = cvt[7];
  const float* mlph_w1 = cvt[9];
  const float* mlph_b1 = cvt[10];
  const float* mlph_b2 = cvt[12];
  const float* v1_b  = cvt[14];
  const float* v2_b  = cvt[16];
  const float* vh1_b = cvt[18];
  const float* vh2_b = cvt[20];
  const float* cat_b = cvt[22];
  const float* u1_b  = cvt[24];
  const float* u2_w  = cvt[25];
  const float* u2_b  = cvt[26];

  // bf16 weight copies for MFMA
  unsigned short* lin_wb   = (unsigned short*)alloc((size_t)4*16384*2);
  unsigned short* linh_wb  = (unsigned short*)alloc((size_t)4*16384*2);
  unsigned short* v1_wb    = (unsigned short*)alloc((size_t)4*16384*2);
  unsigned short* vh1_wb   = (unsigned short*)alloc((size_t)4*16384*2);
  unsigned short* cat_wb   = (unsigned short*)alloc((size_t)4*16384*2);
  unsigned short* mlph_w2b = (unsigned short*)alloc((size_t)4*16384*2);
  unsigned short* v2_wb    = (unsigned short*)alloc((size_t)4*8192*2);
  unsigned short* vh2_wb   = (unsigned short*)alloc((size_t)4*8192*2);
  unsigned short* u1_wb    = (unsigned short*)alloc((size_t)8192*2);
  WTable wt; wt.count = 9;
  wt.s[0] = { cvt[3],  lin_wb,   4*16384 };
  wt.s[1] = { cvt[8],  linh_wb,  4*16384 };
  wt.s[2] = { cvt[13], v1_wb,    4*16384 };
  wt.s[3] = { cvt[17], vh1_wb,   4*16384 };
  wt.s[4] = { cvt[21], cat_wb,   4*16384 };
  wt.s[5] = { cvt[11], mlph_w2b, 4*16384 };
  wt.s[6] = { cvt[15], v2_wb,    4*8192  };
  wt.s[7] = { cvt[19], vh2_wb,   4*8192  };
  wt.s[8] = { cvt[23], u1_wb,    8192    };
  wt.total = 6*4*16384 + 2*4*8192 + 8192;

  unsigned short* Wtab = (unsigned short*)alloc((size_t)4*TBL_ROWS*128*2);
  unsigned*       Wpk  = (unsigned*)alloc((size_t)4*TBL_K*128*4);
  float* v     = (float*)alloc((size_t)N*128*4);
  unsigned short* vlin  = (unsigned short*)alloc((size_t)N*128*2);
  unsigned short* vlinh = (unsigned short*)alloc((size_t)N*128*2);
  float* accR  = (float*)alloc((size_t)N*128*4);
  float* accH  = (float*)alloc((size_t)N*128*4);

  size_t used = (size_t)(wp - (char*)d_ws);
  size_t whs4 = (size_t)4*EH*128*2 + 256;
  bool pre = (ws_size >= used + whs4);
  unsigned short* WhS = (unsigned short*)alloc(pre ? (size_t)4*EH*128*2 : (size_t)EH*128*2);

  detect_mode<<<1,256,0,stream>>>((const unsigned*)d_in[6], flag);
  {
    int cb = (int)((tbl.total + 255)/256);
    if (cb > 4096) cb = 4096;
    convert_all<<<cb,256,0,stream>>>(tbl, flag);
  }
  convert_wb<<<(wt.total+255)/256,256,0,stream>>>(wt);

  int nb;
  nb = (E+255)/256;     init_all<<<nb,256,0,stream>>>(cnt_r,cnt_h,uacc,spk_r,spk_h,N,E,EH);
  nb = (E+255)/256;     count_edges<<<nb,256,0,stream>>>(ei,eih,E,EH,N,cnt_r,cnt_h);
  scan_pair<<<1,256,0,stream>>>(cnt_r,off_r,cur_r,cnt_h,off_h,cur_h,N);
  nb = (E+255)/256;     scatter_edges<<<nb,256,0,stream>>>(ei,distc,eih,E,EH,N,cur_r,cur_h,spk_r,spk_h);
  build_wtab<<<4*TBL_TILES,256,0,stream>>>(mlp_w1,mlp_b1,mlp_w2,mlp_b2,Wtab);
  pack_wtab<<<(int)((4L*TBL_K*128+255)/256),256,0,stream>>>(Wtab,Wpk);

  const int nt = (N+15)/16;
  const int ht = (EH+15)/16;
  if (pre)
    hull_all<<<4*ht,128,0,stream>>>(spk_h, feac, mlph_w1, mlph_b1, mlph_w2b, mlph_b2,
                                    WhS, (size_t)EH*128, EH, ht, 0);

  f_first<<<nt,128,0,stream>>>(z, embc, v, lin_wb, linh_wb, vlin, vlinh, N);
  for (int l=0;l<4;l++){
    if (!pre)
      hull_all<<<ht,128,0,stream>>>(spk_h, feac, mlph_w1, mlph_b1, mlph_w2b, mlph_b2,
                                    WhS, 0, EH, ht, l);
    const unsigned short* WhSl = pre ? (WhS + (size_t)l*EH*128) : WhS;
    acc_both<<<2*N,128,0,stream>>>(off_r, spk_r, vlin, Wpk + (size_t)l*TBL_K*128, accR,
                                   off_h, spk_h, vlinh, WhSl, accH, E, EH, N);
    if (l<3){
      f_mid<<<nt,128,0,stream>>>(accR, accH, v,
          v1_wb + (size_t)l*16384, v1_b + l*128, v2_wb + (size_t)l*8192, v2_b + l*64,
          vh1_wb + (size_t)l*16384, vh1_b + l*128, vh2_wb + (size_t)l*8192, vh2_b + l*64,
          cat_wb + (size_t)l*16384, cat_b + l*128,
          lin_wb + (size_t)(l+1)*16384, linh_wb + (size_t)(l+1)*16384, vlin, vlinh, N);
    } else {
      f_last<<<nt,128,0,stream>>>(accR, accH, v,
          v1_wb + (size_t)l*16384, v1_b + l*128, v2_wb + (size_t)l*8192, v2_b + l*64,
          vh1_wb + (size_t)l*16384, vh1_b + l*128, vh2_wb + (size_t)l*8192, vh2_b + l*64,
          cat_wb + (size_t)l*16384, cat_b + l*128,
          u1_wb, u1_b, u2_w, u2_b, batch, uacc, N);
    }
  }
  write_out<<<1,64,0,stream>>>(uacc, d_out, flag);
}

// Round 7
// 602.707 us; speedup vs baseline: 1.6483x; 1.1759x over previous
//
#include <hip/hip_runtime.h>
#include <hip/hip_bf16.h>

typedef __hip_bfloat16 bf16;
typedef unsigned short ushort;
typedef __attribute__((ext_vector_type(8))) short short8;   // 8 bf16 (4 VGPRs)
typedef __attribute__((ext_vector_type(4))) float f32x4;

__device__ __forceinline__ float dssp(float x){
  // softplus(x)-ln2 via fast HW exp/log; error << bf16 rounding
  return fmaxf(x, 0.f) + 0.693147180559945f*(__logf(1.f + __expf(-fabsf(x)))*1.44269504088896f) - 0.693147180559945f;
}
__device__ __forceinline__ int clampi(int x, int lo, int hi){ return x<lo?lo:(x>hi?hi:x); }
__device__ __forceinline__ ushort f2b(float f){
  unsigned x = __float_as_uint(f);
  return (ushort)((x + 0x7fffu + ((x>>16)&1u)) >> 16);
}
__device__ __forceinline__ float b2f16(ushort u){ return __uint_as_float(((unsigned)u)<<16); }

constexpr int TBL_K    = 4096;
constexpr int TBL_ROWS = TBL_K + 1;
constexpr int TBL_TILES = (TBL_ROWS + 31) / 32;  // 129

// ------------------------------------------------- dtype detection ----------
__global__ void detect_mode(const unsigned* __restrict__ raw, int* flag){
  __shared__ int c;
  int t = threadIdx.x;
  if (t==0) c = 0;
  __syncthreads();
  unsigned u  = raw[t];
  unsigned lo = u & 0xFFFFu;
  int e = (int)((lo >> 7) & 0xFF);
  int ok = (lo==0u) || (e >= 0x70 && e <= 0x8F);
  atomicAdd(&c, ok);
  __syncthreads();
  if (t==0) *flag = (c >= 160) ? 1 : 0;   // 1 = bf16 storage, 0 = f32 storage
}

// ---------------------------------------------- canonical fp32 conversion ---
struct Seg { const void* src; float* dst; int n; };
struct SegTable { Seg s[27]; int count; long total; };

__global__ void convert_all(SegTable tbl, const int* __restrict__ flag){
  int mode = *flag;
  long tid    = (long)blockIdx.x*blockDim.x + threadIdx.x;
  long stride = (long)gridDim.x*blockDim.x;
  for (long i=tid; i<tbl.total; i+=stride){
    long off = i; int k = 0;
    while (k < tbl.count-1 && off >= tbl.s[k].n){ off -= tbl.s[k].n; k++; }
    float f;
    if (mode) f = __bfloat162float(((const bf16*)tbl.s[k].src)[off]);
    else      f = ((const float*)tbl.s[k].src)[off];
    tbl.s[k].dst[off] = (f==f) ? f : 0.f;
  }
}

// ---------------------------------------- bf16 weight copies for MFMA -------
struct WSeg { const float* src; ushort* dst; int n; };
struct WTable { WSeg s[9]; int count; int total; };

__global__ void convert_wb(WTable wt){
  int tid = blockIdx.x*blockDim.x + threadIdx.x;
  if (tid >= wt.total) return;
  int off = tid, k = 0;
  while (k < wt.count-1 && off >= wt.s[k].n){ off -= wt.s[k].n; k++; }
  wt.s[k].dst[off] = f2b(wt.s[k].src[off]);
}

// ------------------------------------------------------------------ setup ---
__global__ void init_all(int* cnt_r, int* cnt_h, float* uacc,
                         int2* spk_r, int2* spk_h, int N, int E, int EH){
  int t = blockIdx.x*blockDim.x + threadIdx.x;
  if (t < N){ cnt_r[t]=0; cnt_h[t]=0; }
  if (t < 64) uacc[t]=0.f;
  if (t < E)  spk_r[t]=make_int2(0,0);
  if (t < EH) spk_h[t]=make_int2(0,0);
}

__global__ void count_edges(const int* __restrict__ ei, const int* __restrict__ eih,
                            int E, int EH, int N, int* cnt_r, int* cnt_h){
  int t = blockIdx.x*blockDim.x + threadIdx.x;
  if (t < E)  atomicAdd(&cnt_r[clampi(ei[E + t], 0, N-1)], 1);
  if (t < EH) atomicAdd(&cnt_h[clampi(eih[EH + t], 0, N-1)], 1);
}

__global__ __launch_bounds__(256) void scan_pair(const int* cnt_r, int* off_r, int* cur_r,
                                                 const int* cnt_h, int* off_h, int* cur_h, int N){
  __shared__ int s[256];
  int t = threadIdx.x;
  int CH = (N + 255) / 256;
  for (int which=0; which<2; which++){
    const int* cnt = which? cnt_h : cnt_r;
    int* off = which? off_h : off_r;
    int* cur = which? cur_h : cur_r;
    int base = t*CH;
    int sum = 0;
    for (int q=0;q<CH;q++){ int idx=base+q; sum += (idx<N)? cnt[idx] : 0; }
    __syncthreads();
    s[t]=sum; __syncthreads();
    for (int ofs=1; ofs<256; ofs<<=1){
      int v = s[t]; int vp = (t>=ofs)? s[t-ofs] : 0;
      __syncthreads(); s[t]=v+vp; __syncthreads();
    }
    int run = (t>0)? s[t-1] : 0;
    for (int q=0;q<CH;q++){
      int idx=base+q;
      if (idx<N){ off[idx]=run; cur[idx]=run; run += cnt[idx]; }
    }
    if (t==255) off[N] = s[255];
  }
}

// digest dist into (i0<<16)|fr_u16 at scatter time
__global__ void scatter_edges(const int* __restrict__ ei, const float* __restrict__ distc,
                              const int* __restrict__ eih, int E, int EH, int N,
                              int* cur_r, int* cur_h, int2* spk_r, int2* spk_h){
  int t = blockIdx.x*blockDim.x + threadIdx.x;
  if (t < E){
    int i = clampi(ei[E+t], 0, N-1);
    int p = clampi(atomicAdd(&cur_r[i], 1), 0, E-1);
    float x = fminf(fmaxf(distc[t]*(4096.0f/5.0f), 0.f), 4095.999f);
    int i0 = (int)x; if (i0 > TBL_K-1) i0 = TBL_K-1;
    unsigned fr16 = (unsigned)((x - (float)i0)*65536.0f); if (fr16 > 65535u) fr16 = 65535u;
    spk_r[p] = make_int2(clampi(ei[t],0,N-1), (int)(((unsigned)i0<<16)|fr16));
  }
  if (t < EH){
    int ih = clampi(eih[EH+t], 0, N-1);
    int p = clampi(atomicAdd(&cur_h[ih], 1), 0, EH-1);
    spk_h[p] = make_int2(clampi(eih[t],0,N-1), t);
  }
}

// --------------------------------------------- W(dist) lookup table (bf16) ---
__global__ __launch_bounds__(256) void build_wtab(const float* __restrict__ mlp_w1,
    const float* __restrict__ mlp_b1, const float* __restrict__ mlp_w2,
    const float* __restrict__ mlp_b2, ushort* __restrict__ Wtab){
  int l    = blockIdx.x / TBL_TILES;
  int tile = blockIdx.x % TBL_TILES;
  int row0 = tile * 32;
  const float* w1 = mlp_w1 + l*128*25;
  const float* b1 = mlp_b1 + l*128;
  const float* w2 = mlp_w2 + l*128*128;
  const float* b2 = mlp_b2 + l*128;
  __shared__ float Gs[32][26];
  __shared__ float Ts[32][129];
  __shared__ float Ws[32][129];
  int t = threadIdx.x;
  for (int idx=t; idx<32*25; idx+=256){
    int r = idx/25, k = idx%25;
    float d = (row0+r) * (5.0f/4096.0f);
    float x = d - (float)k*(5.0f/24.0f);
    Gs[r][k] = __expf(-11.52f*x*x);
  }
  __syncthreads();
  int rg = t&7, cg = t>>3;
  #pragma unroll
  for (int ri=0;ri<4;ri++){
    int r = rg*4+ri;
    #pragma unroll
    for (int ci=0;ci<4;ci++){
      int c = cg*4+ci;
      float s = b1[c];
      for (int k=0;k<25;k++) s += Gs[r][k]*w1[c*25+k];
      Ts[r][c] = dssp(s);
    }
  }
  float acc[4][4] = {};
  for (int k0=0;k0<128;k0+=32){
    __syncthreads();
    for (int idx=t; idx<1024; idx+=256){
      int c=idx>>3, kk4=(idx&7)*4;
      float4 f = *(const float4*)(w2+(size_t)c*128+k0+kk4);
      Ws[kk4][c]=f.x; Ws[kk4+1][c]=f.y; Ws[kk4+2][c]=f.z; Ws[kk4+3][c]=f.w;
    }
    __syncthreads();
    for (int kk=0;kk<32;kk++){
      float xv[4];
      #pragma unroll
      for (int ri=0;ri<4;ri++) xv[ri]=Ts[rg*4+ri][k0+kk];
      #pragma unroll
      for (int ci=0;ci<4;ci++){
        float wv = Ws[kk][cg*4+ci];
        #pragma unroll
        for (int ri=0;ri<4;ri++) acc[ri][ci] += xv[ri]*wv;
      }
    }
  }
  #pragma unroll
  for (int ri=0;ri<4;ri++){
    int r = row0 + rg*4 + ri;
    if (r >= TBL_ROWS) continue;
    float d  = r * (5.0f/4096.0f);
    float Cf = 0.5f*(cosf(d*(3.14159265358979f/5.0f))+1.0f);
    #pragma unroll
    for (int ci=0;ci<4;ci++){
      int c = cg*4+ci;
      Wtab[((size_t)l*TBL_ROWS + r)*128 + c] = f2b((acc[ri][ci] + b2[c]) * Cf);
    }
  }
}

__global__ void pack_wtab(const ushort* __restrict__ Wtab, unsigned* __restrict__ Wpk){
  long t = (long)blockIdx.x*blockDim.x + threadIdx.x;
  const long TOT = 4L*TBL_K*128;
  if (t < TOT){
    int l = (int)(t / ((long)TBL_K*128));
    long rem = t % ((long)TBL_K*128);
    int r = (int)(rem >> 7), f = (int)(rem & 127);
    const ushort* base = Wtab + (size_t)l*TBL_ROWS*128;
    Wpk[t] = (((unsigned)base[(size_t)(r+1)*128+f])<<16) | (unsigned)base[(size_t)r*128+f];
  }
}

// ------------------------------ MFMA tile helpers (256 thd = 4 waves) -------
// A-tile: bf16 LDS [16][136] (conflict-free b128 frags).
// A-frag: A[m=lane&15][k=quad*8+j]; B-frag: W[c][k] row-major bf16 global.
// C/D: row=quad*4+reg, col=lane&15. Wave w covers cols w*(NT*16)..
__device__ __forceinline__ short8 afragb(const ushort (*Xb)[136], int lane, int k0){
  int m=lane&15, q=(lane>>4)&3;
  return *(const short8*)(&Xb[m][k0+q*8]);
}
__device__ __forceinline__ short8 bfrag(const ushort* __restrict__ W, int cbase, int lane, int k0){
  int n=lane&15, q=(lane>>4)&3;
  return *(const short8*)(W + (size_t)(cbase+n)*128 + k0 + q*8);
}
template<int NT>
__device__ __forceinline__ void mgemm(const ushort (*Xb)[136],
    const ushort* __restrict__ W, int t, f32x4 d[NT]){
  int lane=t&63, w=t>>6;
  #pragma unroll
  for (int ct=0;ct<NT;ct++) d[ct]=(f32x4){0.f,0.f,0.f,0.f};
  #pragma unroll
  for (int kc=0;kc<4;kc++){
    short8 a = afragb(Xb, lane, kc*32);
    #pragma unroll
    for (int ct=0;ct<NT;ct++){
      short8 b = bfrag(W, w*(NT*16)+ct*16, lane, kc*32);
      d[ct] = __builtin_amdgcn_mfma_f32_16x16x32_bf16(a, b, d[ct], 0, 0, 0);
    }
  }
}
// D -> bf16 A-tile (bias + optional ssp)
template<int NT>
__device__ __forceinline__ void d2tile(ushort (*Y)[136], const f32x4 d[NT], int t,
    int colofs, const float* __restrict__ bias, int do_ssp){
  int lane=t&63, w=t>>6, q=(lane>>4)&3, n=lane&15;
  #pragma unroll
  for (int ct=0;ct<NT;ct++){
    int c = w*(NT*16)+ct*16+n;
    float bv = bias? bias[c] : 0.f;
    #pragma unroll
    for (int i=0;i<4;i++){
      float y = d[ct][i] + bv;
      if (do_ssp) y = dssp(y);
      Y[q*4+i][colofs+c] = f2b(y);
    }
  }
}
// D -> fp32 LDS [16][132]
template<int NT>
__device__ __forceinline__ void d2os(float (*Os)[132], const f32x4 d[NT], int t,
    const float* __restrict__ bias, int do_ssp){
  int lane=t&63, w=t>>6, q=(lane>>4)&3, n=lane&15;
  #pragma unroll
  for (int ct=0;ct<NT;ct++){
    int c = w*(NT*16)+ct*16+n;
    float bv = bias? bias[c] : 0.f;
    #pragma unroll
    for (int i=0;i<4;i++){
      float y = d[ct][i] + bv;
      if (do_ssp) y = dssp(y);
      Os[q*4+i][c] = y;
    }
  }
}
// D (NT=2, 128 cols) -> global bf16 row-major [N,128]
__device__ __forceinline__ void d2glob(ushort* __restrict__ out, const f32x4 d[2],
    int t, int row0, int N){
  int lane=t&63, w=t>>6, q=(lane>>4)&3, n=lane&15;
  #pragma unroll
  for (int ct=0;ct<2;ct++){
    int c = w*32+ct*16+n;
    #pragma unroll
    for (int i=0;i<4;i++){
      int gr = row0 + q*4 + i;
      if (gr<N) out[(size_t)gr*128 + c] = f2b(d[ct][i]);
    }
  }
}

// ------------------------- F0: embed + lin + linh ---------------------------
__global__ __launch_bounds__(256) void f_first(const int* __restrict__ z,
    const float* __restrict__ emb, float* __restrict__ v,
    const ushort* __restrict__ linA, const ushort* __restrict__ linB,
    ushort* __restrict__ vlin, ushort* __restrict__ vlinh, int N){
  __shared__ ushort Xb[16][136];
  int t=threadIdx.x; int row0=blockIdx.x*16;
  f32x4 d[2];
  for (int idx=t; idx<512; idx+=256){
    int r=idx>>5, k4=(idx&31)*4; int gr=row0+r;
    int zz=(gr<N)? clampi(z[gr],0,99):0;
    float4 f = *(const float4*)(emb + (size_t)zz*128 + k4);
    unsigned r0 = (unsigned)f2b(f.x) | ((unsigned)f2b(f.y)<<16);
    unsigned r1 = (unsigned)f2b(f.z) | ((unsigned)f2b(f.w)<<16);
    *(uint2*)&Xb[r][k4] = make_uint2(r0,r1);
    if (gr<N) *(float4*)(v + (size_t)gr*128 + k4) = f;
  }
  __syncthreads();
  mgemm<2>(Xb, linA, t, d);
  d2glob(vlin, d, t, row0, N);
  mgemm<2>(Xb, linB, t, d);
  d2glob(vlinh, d, t, row0, N);
}

// -------------- F_mid: update_v(l) + lin(l+1) + linh(l+1) -------------------
__global__ __launch_bounds__(256) void f_mid(
    const float* __restrict__ accR, const float* __restrict__ accH,
    float* __restrict__ v,
    const ushort* __restrict__ v1w, const float* __restrict__ v1b,
    const ushort* __restrict__ v2w, const float* __restrict__ v2b,
    const ushort* __restrict__ vh1w, const float* __restrict__ vh1b,
    const ushort* __restrict__ vh2w, const float* __restrict__ vh2b,
    const ushort* __restrict__ cw, const float* __restrict__ cb,
    const ushort* __restrict__ linA, const ushort* __restrict__ linB,
    ushort* __restrict__ vlin, ushort* __restrict__ vlinh, int N){
  __shared__ ushort Xb[16][136];
  __shared__ ushort Xb2[16][136];
  __shared__ ushort Xb3[16][136];
  __shared__ float  Os[16][132];
  int t=threadIdx.x; int row0=blockIdx.x*16;
  f32x4 d[2]; f32x4 d1[1];

  for (int path=0; path<2; path++){
    const float* X = path? accH : accR;
    __syncthreads();
    for (int idx=t; idx<512; idx+=256){
      int r=idx>>5, k4=(idx&31)*4; int gr=row0+r;
      float4 f=(gr<N)? *(const float4*)(X+(size_t)gr*128+k4):make_float4(0,0,0,0);
      unsigned r0 = (unsigned)f2b(f.x) | ((unsigned)f2b(f.y)<<16);
      unsigned r1 = (unsigned)f2b(f.z) | ((unsigned)f2b(f.w)<<16);
      *(uint2*)&Xb[r][k4] = make_uint2(r0,r1);
    }
    __syncthreads();
    mgemm<2>(Xb, path?vh1w:v1w, t, d);
    d2tile<2>(Xb2, d, t, 0, path?vh1b:v1b, 1);
    __syncthreads();
    mgemm<1>(Xb2, path?vh2w:v2w, t, d1);
    d2tile<1>(Xb3, d1, t, path*64, path?vh2b:v2b, 0);
  }
  __syncthreads();
  mgemm<2>(Xb3, cw, t, d);
  d2os<2>(Os, d, t, cb, 1);
  __syncthreads();
  for (int idx=t; idx<512; idx+=256){      // v += Os ; Xb = bf16(new v)
    int r=idx>>5, k4=(idx&31)*4; int gr=row0+r;
    float4 f=(gr<N)? *(const float4*)(v+(size_t)gr*128+k4):make_float4(0,0,0,0);
    f.x+=Os[r][k4]; f.y+=Os[r][k4+1]; f.z+=Os[r][k4+2]; f.w+=Os[r][k4+3];
    if (gr<N) *(float4*)(v+(size_t)gr*128+k4)=f;
    unsigned r0 = (unsigned)f2b(f.x) | ((unsigned)f2b(f.y)<<16);
    unsigned r1 = (unsigned)f2b(f.z) | ((unsigned)f2b(f.w)<<16);
    *(uint2*)&Xb[r][k4] = make_uint2(r0,r1);
  }
  __syncthreads();
  mgemm<2>(Xb, linA, t, d);
  d2glob(vlin, d, t, row0, N);
  mgemm<2>(Xb, linB, t, d);
  d2glob(vlinh, d, t, row0, N);
}

// -------------- F_last: update_v(3) + readout (update_u) --------------------
__global__ __launch_bounds__(256) void f_last(
    const float* __restrict__ accR, const float* __restrict__ accH,
    const float* __restrict__ v,
    const ushort* __restrict__ v1w, const float* __restrict__ v1b,
    const ushort* __restrict__ v2w, const float* __restrict__ v2b,
    const ushort* __restrict__ vh1w, const float* __restrict__ vh1b,
    const ushort* __restrict__ vh2w, const float* __restrict__ vh2b,
    const ushort* __restrict__ cw, const float* __restrict__ cb,
    const ushort* __restrict__ u1w, const float* __restrict__ u1b,
    const float* __restrict__ u2w, const float* __restrict__ u2b,
    const int* __restrict__ batch, float* __restrict__ uacc, int N){
  __shared__ ushort Xb[16][136];
  __shared__ ushort Xb2[16][136];
  __shared__ ushort Xb3[16][136];
  __shared__ float  Os[16][132];
  __shared__ float ss[16];
  __shared__ int   bb[16];
  int t=threadIdx.x; int row0=blockIdx.x*16;
  f32x4 d[2]; f32x4 d1[1];

  for (int path=0; path<2; path++){
    const float* X = path? accH : accR;
    __syncthreads();
    for (int idx=t; idx<512; idx+=256){
      int r=idx>>5, k4=(idx&31)*4; int gr=row0+r;
      float4 f=(gr<N)? *(const float4*)(X+(size_t)gr*128+k4):make_float4(0,0,0,0);
      unsigned r0 = (unsigned)f2b(f.x) | ((unsigned)f2b(f.y)<<16);
      unsigned r1 = (unsigned)f2b(f.z) | ((unsigned)f2b(f.w)<<16);
      *(uint2*)&Xb[r][k4] = make_uint2(r0,r1);
    }
    __syncthreads();
    mgemm<2>(Xb, path?vh1w:v1w, t, d);
    d2tile<2>(Xb2, d, t, 0, path?vh1b:v1b, 1);
    __syncthreads();
    mgemm<1>(Xb2, path?vh2w:v2w, t, d1);
    d2tile<1>(Xb3, d1, t, path*64, path?vh2b:v2b, 0);
  }
  __syncthreads();
  mgemm<2>(Xb3, cw, t, d);
  d2os<2>(Os, d, t, cb, 1);
  __syncthreads();
  for (int idx=t; idx<512; idx+=256){      // Xb = bf16(v + dssp(cat))
    int r=idx>>5, k4=(idx&31)*4; int gr=row0+r;
    float4 f=(gr<N)? *(const float4*)(v+(size_t)gr*128+k4):make_float4(0,0,0,0);
    f.x+=Os[r][k4]; f.y+=Os[r][k4+1]; f.z+=Os[r][k4+2]; f.w+=Os[r][k4+3];
    unsigned r0 = (unsigned)f2b(f.x) | ((unsigned)f2b(f.y)<<16);
    unsigned r1 = (unsigned)f2b(f.z) | ((unsigned)f2b(f.w)<<16);
    *(uint2*)&Xb[r][k4] = make_uint2(r0,r1);
  }
  __syncthreads();
  mgemm<1>(Xb, u1w, t, d1);                // 64 cols
  d2os<1>(Os, d1, t, u1b, 1);
  __syncthreads();
  if (t<16){
    int gr=row0+t;
    float s=0.f; int bt=-1;
    if (gr<N){
      s = u2b[0];
      for (int c=0;c<64;c++) s += Os[t][c]*u2w[c];
      bt = clampi(batch[gr],0,63);
    }
    ss[t]=s; bb[t]=bt;
  }
  __syncthreads();
  if (t==0){
    float run=0.f; int cur=-1;
    for (int q=0;q<16;q++){
      int bq=bb[q];
      if (bq<0) continue;
      if (bq!=cur){ if (cur>=0) atomicAdd(&uacc[cur],run); cur=bq; run=0.f; }
      run += ss[q];
    }
    if (cur>=0) atomicAdd(&uacc[cur],run);
  }
}

// -------------------- hull filter, transposed output [c][EHpad] -------------
__global__ __launch_bounds__(256) void hull_all(const int2* __restrict__ spk_h,
    const float* __restrict__ fea,
    const float* __restrict__ mlph_w1, const float* __restrict__ mlph_b1,
    const ushort* __restrict__ mlph_w2b, const float* __restrict__ mlph_b2,
    ushort* __restrict__ WhT_base, size_t lstride, int EHpad,
    int EH, int tilesPerLayer, int l0){
  int l    = l0 + blockIdx.x / tilesPerLayer;
  int tile = blockIdx.x % tilesPerLayer;
  int row0 = tile*16;
  const float* w1 = mlph_w1 + l*128*7;
  const float* b1 = mlph_b1 + l*128;
  const ushort* w2 = mlph_w2b + (size_t)l*16384;
  const float* b2 = mlph_b2 + l*128;
  ushort* WhT = WhT_base + (size_t)(l-l0)*lstride;
  __shared__ float Fs[16][8];
  __shared__ ushort Xb[16][136];
  int t=threadIdx.x;
  if (t < 112){
    int r = t/7, k = t%7;
    int p = row0 + r;
    int eid = (p<EH) ? clampi(spk_h[p].y, 0, EH-1) : 0;
    Fs[r][k] = (p<EH) ? fea[(size_t)eid*7 + k] : 0.f;
  }
  __syncthreads();
  {
    int r = t>>4, c0 = (t&15)*8;
    short8 pk;
    #pragma unroll
    for (int j=0;j<8;j++){
      int c = c0+j;
      float s = b1[c];
      #pragma unroll
      for (int k=0;k<7;k++) s += Fs[r][k]*w1[c*7+k];
      pk[j] = (short)f2b(dssp(s));
    }
    *(short8*)&Xb[r][c0] = pk;
  }
  __syncthreads();
  f32x4 d[2];
  mgemm<2>(Xb, w2, t, d);
  int lane=t&63, w=t>>6, q=(lane>>4)&3, n=lane&15;
  int p0 = row0 + q*4;
  #pragma unroll
  for (int ct=0;ct<2;ct++){
    int c = w*32+ct*16+n;
    float bv = b2[c];
    unsigned r0 = (unsigned)f2b(d[ct][0]+bv) | ((unsigned)f2b(d[ct][1]+bv)<<16);
    unsigned r1 = (unsigned)f2b(d[ct][2]+bv) | ((unsigned)f2b(d[ct][3]+bv)<<16);
    *(uint2*)(WhT + (size_t)c*EHpad + p0) = make_uint2(r0,r1);  // rows p0..p0+3
  }
}

// ------------------------------ CSR segment reductions ----------------------
__global__ __launch_bounds__(128) void acc_both(
    const int* __restrict__ off_r, const int2* __restrict__ spk_r,
    const ushort* __restrict__ vlin, const unsigned* __restrict__ Wpk,
    float* __restrict__ accR,
    const int* __restrict__ off_h, const int2* __restrict__ spk_h,
    const ushort* __restrict__ vlinh, const ushort* __restrict__ WhT, int EHpad,
    float* __restrict__ accH,
    int Etot, int EHtot, int N){
  int f = threadIdx.x;
  if ((int)blockIdx.x < N){
    int n = blockIdx.x;
    int b = clampi(off_r[n], 0, Etot);
    int e = clampi(off_r[n+1], b, Etot);
    float a = 0.f;
    int p = b;
    for (; p+2<=e; p+=2){
      int2 kA = spk_r[p], kB = spk_r[p+1];
      unsigned yA = (unsigned)kA.y, yB = (unsigned)kB.y;
      int iA = (int)(yA>>16), iB = (int)(yB>>16);
      float frA = (float)(yA&0xFFFFu)*(1.f/65536.f);
      float frB = (float)(yB&0xFFFFu)*(1.f/65536.f);
      unsigned uA = Wpk[(size_t)iA*128+f];
      unsigned uB = Wpk[(size_t)iB*128+f];
      float vA = b2f16(vlin[(size_t)kA.x*128+f]);
      float vB = b2f16(vlin[(size_t)kB.x*128+f]);
      float w0A=__uint_as_float(uA<<16), w1A=__uint_as_float(uA&0xFFFF0000u);
      float w0B=__uint_as_float(uB<<16), w1B=__uint_as_float(uB&0xFFFF0000u);
      a += vA*fmaf(frA, w1A-w0A, w0A) + vB*fmaf(frB, w1B-w0B, w0B);
    }
    if (p<e){
      int2 kA = spk_r[p];
      unsigned yA = (unsigned)kA.y;
      int iA = (int)(yA>>16);
      float frA = (float)(yA&0xFFFFu)*(1.f/65536.f);
      unsigned uA = Wpk[(size_t)iA*128+f];
      float vA = b2f16(vlin[(size_t)kA.x*128+f]);
      float w0A=__uint_as_float(uA<<16), w1A=__uint_as_float(uA&0xFFFF0000u);
      a += vA*fmaf(frA, w1A-w0A, w0A);
    }
    accR[(size_t)n*128+f] = a;
  } else {
    int n = blockIdx.x - N;
    int b = clampi(off_h[n], 0, EHtot);
    int e = clampi(off_h[n+1], b, EHtot);
    const ushort* wrow = WhT + (size_t)f*EHpad;
    float a = 0.f;
    int p = b;
    for (; p+2<=e; p+=2){
      int2 kA = spk_h[p], kB = spk_h[p+1];
      float vA = b2f16(vlinh[(size_t)kA.x*128+f]);
      float vB = b2f16(vlinh[(size_t)kB.x*128+f]);
      a += vA*b2f16(wrow[p]) + vB*b2f16(wrow[p+1]);
    }
    if (p<e){
      int2 kA = spk_h[p];
      float vA = b2f16(vlinh[(size_t)kA.x*128+f]);
      a += vA*b2f16(wrow[p]);
    }
    accH[(size_t)n*128+f] = a;
  }
}

__global__ void write_out(const float* __restrict__ uacc, void* out, const int* __restrict__ flag){
  int t = threadIdx.x;
  if (t < 64){
    if (*flag) ((bf16*)out)[t] = __float2bfloat16(uacc[t]);
    else       ((float*)out)[t] = uacc[t];
  }
}

// ----------------------------------------------------------------- launch ---
extern "C" void kernel_launch(void* const* d_in, const int* in_sizes, int n_in,
                              void* d_out, int out_size, void* d_ws, size_t ws_size,
                              hipStream_t stream){
  const int* z     = (const int*)d_in[0];
  const int* ei    = (const int*)d_in[1];
  const int* eih   = (const int*)d_in[2];
  const int* batch = (const int*)d_in[3];

  const int N  = in_sizes[0];
  const int E  = in_sizes[1]/2;
  const int EH = in_sizes[2]/2;
  const int EHpad = (EH + 15) & ~15;

  char* wp = (char*)d_ws;
  auto alloc = [&](size_t bytes)->char*{
    char* p = wp; wp += (bytes + 255) & ~(size_t)255; return p;
  };
  int* flag    = (int*)alloc(256);
  int* cnt_r   = (int*)alloc((size_t)N*4);
  int* off_r   = (int*)alloc((size_t)(N+1)*4);
  int* cur_r   = (int*)alloc((size_t)N*4);
  int* cnt_h   = (int*)alloc((size_t)N*4);
  int* off_h   = (int*)alloc((size_t)(N+1)*4);
  int* cur_h   = (int*)alloc((size_t)N*4);
  int2* spk_r  = (int2*)alloc((size_t)E*8);
  int2* spk_h  = (int2*)alloc((size_t)EH*8);
  float* uacc  = (float*)alloc(64*4);

  SegTable tbl; tbl.count = 27; tbl.total = 0;
  float* cvt[27];
  for (int i=0;i<27;i++){
    int n = in_sizes[4+i];
    cvt[i] = (float*)alloc((size_t)n*4);
    tbl.s[i].src = d_in[4+i];
    tbl.s[i].dst = cvt[i];
    tbl.s[i].n   = n;
    tbl.total   += n;
  }
  const float* distc   = cvt[0];
  const float* feac    = cvt[1];
  const float* embc    = cvt[2];
  const float* mlp_w1  = cvt[4];
  const float* mlp_b1  = cvt[5];
  const float* mlp_w2  = cvt[6];
  const float* mlp_b2  = cvt[7];
  const float* mlph_w1 = cvt[9];
  const float* mlph_b1 = cvt[10];
  const float* mlph_b2 = cvt[12];
  const float* v1_b  = cvt[14];
  const float* v2_b  = cvt[16];
  const float* vh1_b = cvt[18];
  const float* vh2_b = cvt[20];
  const float* cat_b = cvt[22];
  const float* u1_b  = cvt[24];
  const float* u2_w  = cvt[25];
  const float* u2_b  = cvt[26];

  ushort* lin_wb   = (ushort*)alloc((size_t)4*16384*2);
  ushort* linh_wb  = (ushort*)alloc((size_t)4*16384*2);
  ushort* v1_wb    = (ushort*)alloc((size_t)4*16384*2);
  ushort* vh1_wb   = (ushort*)alloc((size_t)4*16384*2);
  ushort* cat_wb   = (ushort*)alloc((size_t)4*16384*2);
  ushort* mlph_w2b = (ushort*)alloc((size_t)4*16384*2);
  ushort* v2_wb    = (ushort*)alloc((size_t)4*8192*2);
  ushort* vh2_wb   = (ushort*)alloc((size_t)4*8192*2);
  ushort* u1_wb    = (ushort*)alloc((size_t)8192*2);
  WTable wt; wt.count = 9;
  wt.s[0] = { cvt[3],  lin_wb,   4*16384 };
  wt.s[1] = { cvt[8],  linh_wb,  4*16384 };
  wt.s[2] = { cvt[13], v1_wb,    4*16384 };
  wt.s[3] = { cvt[17], vh1_wb,   4*16384 };
  wt.s[4] = { cvt[21], cat_wb,   4*16384 };
  wt.s[5] = { cvt[11], mlph_w2b, 4*16384 };
  wt.s[6] = { cvt[15], v2_wb,    4*8192  };
  wt.s[7] = { cvt[19], vh2_wb,   4*8192  };
  wt.s[8] = { cvt[23], u1_wb,    8192    };
  wt.total = 6*4*16384 + 2*4*8192 + 8192;

  ushort*   Wtab = (ushort*)alloc((size_t)4*TBL_ROWS*128*2);
  unsigned* Wpk  = (unsigned*)alloc((size_t)4*TBL_K*128*4);
  float* v     = (float*)alloc((size_t)N*128*4);
  ushort* vlin  = (ushort*)alloc((size_t)N*128*2);
  ushort* vlinh = (ushort*)alloc((size_t)N*128*2);
  float* accR  = (float*)alloc((size_t)N*128*4);
  float* accH  = (float*)alloc((size_t)N*128*4);

  size_t used = (size_t)(wp - (char*)d_ws);
  size_t wht1 = (size_t)128*EHpad*2;
  bool pre = (ws_size >= used + 4*wht1 + 256);
  ushort* WhT = (ushort*)alloc(pre ? 4*wht1 : wht1);

  detect_mode<<<1,256,0,stream>>>((const unsigned*)d_in[6], flag);
  {
    int cb = (int)((tbl.total + 255)/256);
    if (cb > 4096) cb = 4096;
    convert_all<<<cb,256,0,stream>>>(tbl, flag);
  }
  convert_wb<<<(wt.total+255)/256,256,0,stream>>>(wt);

  int nb;
  nb = (E+255)/256;     init_all<<<nb,256,0,stream>>>(cnt_r,cnt_h,uacc,spk_r,spk_h,N,E,EH);
  nb = (E+255)/256;     count_edges<<<nb,256,0,stream>>>(ei,eih,E,EH,N,cnt_r,cnt_h);
  scan_pair<<<1,256,0,stream>>>(cnt_r,off_r,cur_r,cnt_h,off_h,cur_h,N);
  nb = (E+255)/256;     scatter_edges<<<nb,256,0,stream>>>(ei,distc,eih,E,EH,N,cur_r,cur_h,spk_r,spk_h);
  build_wtab<<<4*TBL_TILES,256,0,stream>>>(mlp_w1,mlp_b1,mlp_w2,mlp_b2,Wtab);
  pack_wtab<<<(int)((4L*TBL_K*128+255)/256),256,0,stream>>>(Wtab,Wpk);

  const int nt = (N+15)/16;
  const int ht = (EH+15)/16;
  if (pre)
    hull_all<<<4*ht,256,0,stream>>>(spk_h, feac, mlph_w1, mlph_b1, mlph_w2b, mlph_b2,
                                    WhT, (size_t)128*EHpad, EHpad, EH, ht, 0);

  f_first<<<nt,256,0,stream>>>(z, embc, v, lin_wb, linh_wb, vlin, vlinh, N);
  for (int l=0;l<4;l++){
    if (!pre)
      hull_all<<<ht,256,0,stream>>>(spk_h, feac, mlph_w1, mlph_b1, mlph_w2b, mlph_b2,
                                    WhT, 0, EHpad, EH, ht, l);
    const ushort* WhTl = pre ? (WhT + (size_t)l*128*EHpad) : WhT;
    acc_both<<<2*N,128,0,stream>>>(off_r, spk_r, vlin, Wpk + (size_t)l*TBL_K*128, accR,
                                   off_h, spk_h, vlinh, WhTl, EHpad, accH, E, EH, N);
    if (l<3){
      f_mid<<<nt,256,0,stream>>>(accR, accH, v,
          v1_wb + (size_t)l*16384, v1_b + l*128, v2_wb + (size_t)l*8192, v2_b + l*64,
          vh1_wb + (size_t)l*16384, vh1_b + l*128, vh2_wb + (size_t)l*8192, vh2_b + l*64,
          cat_wb + (size_t)l*16384, cat_b + l*128,
          lin_wb + (size_t)(l+1)*16384, linh_wb + (size_t)(l+1)*16384, vlin, vlinh, N);
    } else {
      f_last<<<nt,256,0,stream>>>(accR, accH, v,
          v1_wb + (size_t)l*16384, v1_b + l*128, v2_wb + (size_t)l*8192, v2_b + l*64,
          vh1_wb + (size_t)l*16384, vh1_b + l*128, vh2_wb + (size_t)l*8192, vh2_b + l*64,
          cat_wb + (size_t)l*16384, cat_b + l*128,
          u1_wb, u1_b, u2_w, u2_b, batch, uacc, N);
    }
  }
  write_out<<<1,64,0,stream>>>(uacc, d_out, flag);
}

// Round 8
// 579.549 us; speedup vs baseline: 1.7141x; 1.0400x over previous
//
#include <hip/hip_runtime.h>
#include <hip/hip_bf16.h>

typedef __hip_bfloat16 bf16;
typedef unsigned short ushort;
typedef __attribute__((ext_vector_type(8))) short short8;   // 8 bf16 (4 VGPRs)
typedef __attribute__((ext_vector_type(4))) float f32x4;

__device__ __forceinline__ float dssp(float x){
  // softplus(x)-ln2 via fast HW exp/log; error << bf16 rounding
  return fmaxf(x, 0.f) + __logf(1.f + __expf(-fabsf(x))) - 0.693147180559945f;
}
__device__ __forceinline__ int clampi(int x, int lo, int hi){ return x<lo?lo:(x>hi?hi:x); }
__device__ __forceinline__ ushort f2b(float f){
  unsigned x = __float_as_uint(f);
  return (ushort)((x + 0x7fffu + ((x>>16)&1u)) >> 16);
}
__device__ __forceinline__ float b2f16(ushort u){ return __uint_as_float(((unsigned)u)<<16); }

constexpr int TBL_K    = 4096;
constexpr int TBL_ROWS = TBL_K + 1;
constexpr int TBL_TILES = (TBL_ROWS + 31) / 32;  // 129

// ------------------------------------------------- dtype detection ----------
__global__ void detect_mode(const unsigned* __restrict__ raw, int* flag){
  __shared__ int c;
  int t = threadIdx.x;
  if (t==0) c = 0;
  __syncthreads();
  unsigned u  = raw[t];
  unsigned lo = u & 0xFFFFu;
  int e = (int)((lo >> 7) & 0xFF);
  int ok = (lo==0u) || (e >= 0x70 && e <= 0x8F);
  atomicAdd(&c, ok);
  __syncthreads();
  if (t==0) *flag = (c >= 160) ? 1 : 0;   // 1 = bf16 storage, 0 = f32 storage
}

// ---------------------------------------------- canonical fp32 conversion ---
struct Seg { const void* src; float* dst; int n; };
struct SegTable { Seg s[27]; int count; long total; };

__global__ void convert_all(SegTable tbl, const int* __restrict__ flag){
  int mode = *flag;
  long tid    = (long)blockIdx.x*blockDim.x + threadIdx.x;
  long stride = (long)gridDim.x*blockDim.x;
  for (long i=tid; i<tbl.total; i+=stride){
    long off = i; int k = 0;
    while (k < tbl.count-1 && off >= tbl.s[k].n){ off -= tbl.s[k].n; k++; }
    float f;
    if (mode) f = __bfloat162float(((const bf16*)tbl.s[k].src)[off]);
    else      f = ((const float*)tbl.s[k].src)[off];
    tbl.s[k].dst[off] = (f==f) ? f : 0.f;
  }
}

// ---------------------------------------- bf16 weight copies for MFMA -------
struct WSeg { const float* src; ushort* dst; int n; };
struct WTable { WSeg s[9]; int count; int total; };

__global__ void convert_wb(WTable wt){
  int tid = blockIdx.x*blockDim.x + threadIdx.x;
  if (tid >= wt.total) return;
  int off = tid, k = 0;
  while (k < wt.count-1 && off >= wt.s[k].n){ off -= wt.s[k].n; k++; }
  wt.s[k].dst[off] = f2b(wt.s[k].src[off]);
}

// ------------------------------------------------------------------ setup ---
__global__ void init_all(int* cnt_r, int* cnt_h, float* uacc,
                         int2* spk_r, int2* spk_h, int N, int E, int EH){
  int t = blockIdx.x*blockDim.x + threadIdx.x;
  if (t < N){ cnt_r[t]=0; cnt_h[t]=0; }
  if (t < 64) uacc[t]=0.f;
  if (t < E)  spk_r[t]=make_int2(0,0);
  if (t < EH) spk_h[t]=make_int2(0,0);
}

__global__ void count_edges(const int* __restrict__ ei, const int* __restrict__ eih,
                            int E, int EH, int N, int* cnt_r, int* cnt_h){
  int t = blockIdx.x*blockDim.x + threadIdx.x;
  if (t < E)  atomicAdd(&cnt_r[clampi(ei[E + t], 0, N-1)], 1);
  if (t < EH) atomicAdd(&cnt_h[clampi(eih[EH + t], 0, N-1)], 1);
}

__global__ __launch_bounds__(256) void scan_pair(const int* cnt_r, int* off_r, int* cur_r,
                                                 const int* cnt_h, int* off_h, int* cur_h, int N){
  __shared__ int s[256];
  int t = threadIdx.x;
  int CH = (N + 255) / 256;
  for (int which=0; which<2; which++){
    const int* cnt = which? cnt_h : cnt_r;
    int* off = which? off_h : off_r;
    int* cur = which? cur_h : cur_r;
    int base = t*CH;
    int sum = 0;
    for (int q=0;q<CH;q++){ int idx=base+q; sum += (idx<N)? cnt[idx] : 0; }
    __syncthreads();
    s[t]=sum; __syncthreads();
    for (int ofs=1; ofs<256; ofs<<=1){
      int v = s[t]; int vp = (t>=ofs)? s[t-ofs] : 0;
      __syncthreads(); s[t]=v+vp; __syncthreads();
    }
    int run = (t>0)? s[t-1] : 0;
    for (int q=0;q<CH;q++){
      int idx=base+q;
      if (idx<N){ off[idx]=run; cur[idx]=run; run += cnt[idx]; }
    }
    if (t==255) off[N] = s[255];
  }
}

// digest dist into (i0<<16)|fr_u16 at scatter time
__global__ void scatter_edges(const int* __restrict__ ei, const float* __restrict__ distc,
                              const int* __restrict__ eih, int E, int EH, int N,
                              int* cur_r, int* cur_h, int2* spk_r, int2* spk_h){
  int t = blockIdx.x*blockDim.x + threadIdx.x;
  if (t < E){
    int i = clampi(ei[E+t], 0, N-1);
    int p = clampi(atomicAdd(&cur_r[i], 1), 0, E-1);
    float x = fminf(fmaxf(distc[t]*(4096.0f/5.0f), 0.f), 4095.999f);
    int i0 = (int)x; if (i0 > TBL_K-1) i0 = TBL_K-1;
    unsigned fr16 = (unsigned)((x - (float)i0)*65536.0f); if (fr16 > 65535u) fr16 = 65535u;
    spk_r[p] = make_int2(clampi(ei[t],0,N-1), (int)(((unsigned)i0<<16)|fr16));
  }
  if (t < EH){
    int ih = clampi(eih[EH+t], 0, N-1);
    int p = clampi(atomicAdd(&cur_h[ih], 1), 0, EH-1);
    spk_h[p] = make_int2(clampi(eih[t],0,N-1), t);
  }
}

// --------------------------------------------- W(dist) lookup table (bf16) ---
__global__ __launch_bounds__(256) void build_wtab(const float* __restrict__ mlp_w1,
    const float* __restrict__ mlp_b1, const float* __restrict__ mlp_w2,
    const float* __restrict__ mlp_b2, ushort* __restrict__ Wtab){
  int l    = blockIdx.x / TBL_TILES;
  int tile = blockIdx.x % TBL_TILES;
  int row0 = tile * 32;
  const float* w1 = mlp_w1 + l*128*25;
  const float* b1 = mlp_b1 + l*128;
  const float* w2 = mlp_w2 + l*128*128;
  const float* b2 = mlp_b2 + l*128;
  __shared__ float Gs[32][26];
  __shared__ float Ts[32][129];
  __shared__ float Ws[32][129];
  int t = threadIdx.x;
  for (int idx=t; idx<32*25; idx+=256){
    int r = idx/25, k = idx%25;
    float d = (row0+r) * (5.0f/4096.0f);
    float x = d - (float)k*(5.0f/24.0f);
    Gs[r][k] = __expf(-11.52f*x*x);
  }
  __syncthreads();
  int rg = t&7, cg = t>>3;
  #pragma unroll
  for (int ri=0;ri<4;ri++){
    int r = rg*4+ri;
    #pragma unroll
    for (int ci=0;ci<4;ci++){
      int c = cg*4+ci;
      float s = b1[c];
      for (int k=0;k<25;k++) s += Gs[r][k]*w1[c*25+k];
      Ts[r][c] = dssp(s);
    }
  }
  float acc[4][4] = {};
  for (int k0=0;k0<128;k0+=32){
    __syncthreads();
    for (int idx=t; idx<1024; idx+=256){
      int c=idx>>3, kk4=(idx&7)*4;
      float4 f = *(const float4*)(w2+(size_t)c*128+k0+kk4);
      Ws[kk4][c]=f.x; Ws[kk4+1][c]=f.y; Ws[kk4+2][c]=f.z; Ws[kk4+3][c]=f.w;
    }
    __syncthreads();
    for (int kk=0;kk<32;kk++){
      float xv[4];
      #pragma unroll
      for (int ri=0;ri<4;ri++) xv[ri]=Ts[rg*4+ri][k0+kk];
      #pragma unroll
      for (int ci=0;ci<4;ci++){
        float wv = Ws[kk][cg*4+ci];
        #pragma unroll
        for (int ri=0;ri<4;ri++) acc[ri][ci] += xv[ri]*wv;
      }
    }
  }
  #pragma unroll
  for (int ri=0;ri<4;ri++){
    int r = row0 + rg*4 + ri;
    if (r >= TBL_ROWS) continue;
    float d  = r * (5.0f/4096.0f);
    float Cf = 0.5f*(cosf(d*(3.14159265358979f/5.0f))+1.0f);
    #pragma unroll
    for (int ci=0;ci<4;ci++){
      int c = cg*4+ci;
      Wtab[((size_t)l*TBL_ROWS + r)*128 + c] = f2b((acc[ri][ci] + b2[c]) * Cf);
    }
  }
}

__global__ void pack_wtab(const ushort* __restrict__ Wtab, unsigned* __restrict__ Wpk){
  long t = (long)blockIdx.x*blockDim.x + threadIdx.x;
  const long TOT = 4L*TBL_K*128;
  if (t < TOT){
    int l = (int)(t / ((long)TBL_K*128));
    long rem = t % ((long)TBL_K*128);
    int r = (int)(rem >> 7), f = (int)(rem & 127);
    const ushort* base = Wtab + (size_t)l*TBL_ROWS*128;
    Wpk[t] = (((unsigned)base[(size_t)(r+1)*128+f])<<16) | (unsigned)base[(size_t)r*128+f];
  }
}

// ------------------------------ MFMA tile helpers ---------------------------
// A-tile: bf16 LDS rows stride 136 (conflict-free b128 frags).
// A-frag: A[m=lane&15][k=quad*8+j]; B-frag: W[c][k] row-major bf16 global.
// C/D: row=quad*4+reg, col=lane&15. Wave w covers cols w*(NT*16)..
__device__ __forceinline__ short8 afragb(const ushort (*Xb)[136], int lane, int k0){
  int m=lane&15, q=(lane>>4)&3;
  return *(const short8*)(&Xb[m][k0+q*8]);
}
__device__ __forceinline__ short8 bfrag(const ushort* __restrict__ W, int cbase, int lane, int k0){
  int n=lane&15, q=(lane>>4)&3;
  return *(const short8*)(W + (size_t)(cbase+n)*128 + k0 + q*8);
}
template<int NT>
__device__ __forceinline__ void mgemm(const ushort (*Xb)[136],
    const ushort* __restrict__ W, int t, f32x4 d[NT]){
  int lane=t&63, w=t>>6;
  #pragma unroll
  for (int ct=0;ct<NT;ct++) d[ct]=(f32x4){0.f,0.f,0.f,0.f};
  #pragma unroll
  for (int kc=0;kc<4;kc++){
    short8 a = afragb(Xb, lane, kc*32);
    #pragma unroll
    for (int ct=0;ct<NT;ct++){
      short8 b = bfrag(W, w*(NT*16)+ct*16, lane, kc*32);
      d[ct] = __builtin_amdgcn_mfma_f32_16x16x32_bf16(a, b, d[ct], 0, 0, 0);
    }
  }
}
// D -> bf16 A-tile (bias + optional ssp)
template<int NT>
__device__ __forceinline__ void d2tile(ushort (*Y)[136], const f32x4 d[NT], int t,
    int colofs, const float* __restrict__ bias, int do_ssp){
  int lane=t&63, w=t>>6, q=(lane>>4)&3, n=lane&15;
  #pragma unroll
  for (int ct=0;ct<NT;ct++){
    int c = w*(NT*16)+ct*16+n;
    float bv = bias? bias[c] : 0.f;
    #pragma unroll
    for (int i=0;i<4;i++){
      float y = d[ct][i] + bv;
      if (do_ssp) y = dssp(y);
      Y[q*4+i][colofs+c] = f2b(y);
    }
  }
}
// D -> fp32 LDS [16][132]
template<int NT>
__device__ __forceinline__ void d2os(float (*Os)[132], const f32x4 d[NT], int t,
    const float* __restrict__ bias, int do_ssp){
  int lane=t&63, w=t>>6, q=(lane>>4)&3, n=lane&15;
  #pragma unroll
  for (int ct=0;ct<NT;ct++){
    int c = w*(NT*16)+ct*16+n;
    float bv = bias? bias[c] : 0.f;
    #pragma unroll
    for (int i=0;i<4;i++){
      float y = d[ct][i] + bv;
      if (do_ssp) y = dssp(y);
      Os[q*4+i][c] = y;
    }
  }
}
// D (NT=2, 128 cols) -> global bf16 row-major [N,128]
__device__ __forceinline__ void d2glob(ushort* __restrict__ out, const f32x4 d[2],
    int t, int row0, int N){
  int lane=t&63, w=t>>6, q=(lane>>4)&3, n=lane&15;
  #pragma unroll
  for (int ct=0;ct<2;ct++){
    int c = w*32+ct*16+n;
    #pragma unroll
    for (int i=0;i<4;i++){
      int gr = row0 + q*4 + i;
      if (gr<N) out[(size_t)gr*128 + c] = f2b(d[ct][i]);
    }
  }
}

// ------------------------- F0: embed + lin + linh ---------------------------
__global__ __launch_bounds__(256) void f_first(const int* __restrict__ z,
    const float* __restrict__ emb, float* __restrict__ v,
    const ushort* __restrict__ linA, const ushort* __restrict__ linB,
    ushort* __restrict__ vlin, ushort* __restrict__ vlinh, int N){
  __shared__ ushort Xb[16][136];
  int t=threadIdx.x; int row0=blockIdx.x*16;
  f32x4 d[2];
  for (int idx=t; idx<512; idx+=256){
    int r=idx>>5, k4=(idx&31)*4; int gr=row0+r;
    int zz=(gr<N)? clampi(z[gr],0,99):0;
    float4 f = *(const float4*)(emb + (size_t)zz*128 + k4);
    unsigned r0 = (unsigned)f2b(f.x) | ((unsigned)f2b(f.y)<<16);
    unsigned r1 = (unsigned)f2b(f.z) | ((unsigned)f2b(f.w)<<16);
    *(uint2*)&Xb[r][k4] = make_uint2(r0,r1);
    if (gr<N) *(float4*)(v + (size_t)gr*128 + k4) = f;
  }
  __syncthreads();
  mgemm<2>(Xb, linA, t, d);
  d2glob(vlin, d, t, row0, N);
  mgemm<2>(Xb, linB, t, d);
  d2glob(vlinh, d, t, row0, N);
}

// -------------- F_mid: update_v(l) + lin(l+1) + linh(l+1) -------------------
__global__ __launch_bounds__(256) void f_mid(
    const float* __restrict__ accR, const float* __restrict__ accH,
    float* __restrict__ v,
    const ushort* __restrict__ v1w, const float* __restrict__ v1b,
    const ushort* __restrict__ v2w, const float* __restrict__ v2b,
    const ushort* __restrict__ vh1w, const float* __restrict__ vh1b,
    const ushort* __restrict__ vh2w, const float* __restrict__ vh2b,
    const ushort* __restrict__ cw, const float* __restrict__ cb,
    const ushort* __restrict__ linA, const ushort* __restrict__ linB,
    ushort* __restrict__ vlin, ushort* __restrict__ vlinh, int N){
  __shared__ ushort Xb[16][136];
  __shared__ ushort Xb2[16][136];
  __shared__ ushort Xb3[16][136];
  __shared__ float  Os[16][132];
  int t=threadIdx.x; int row0=blockIdx.x*16;
  f32x4 d[2]; f32x4 d1[1];

  for (int path=0; path<2; path++){
    const float* X = path? accH : accR;
    __syncthreads();
    for (int idx=t; idx<512; idx+=256){
      int r=idx>>5, k4=(idx&31)*4; int gr=row0+r;
      float4 f=(gr<N)? *(const float4*)(X+(size_t)gr*128+k4):make_float4(0,0,0,0);
      unsigned r0 = (unsigned)f2b(f.x) | ((unsigned)f2b(f.y)<<16);
      unsigned r1 = (unsigned)f2b(f.z) | ((unsigned)f2b(f.w)<<16);
      *(uint2*)&Xb[r][k4] = make_uint2(r0,r1);
    }
    __syncthreads();
    mgemm<2>(Xb, path?vh1w:v1w, t, d);
    d2tile<2>(Xb2, d, t, 0, path?vh1b:v1b, 1);
    __syncthreads();
    mgemm<1>(Xb2, path?vh2w:v2w, t, d1);
    d2tile<1>(Xb3, d1, t, path*64, path?vh2b:v2b, 0);
  }
  __syncthreads();
  mgemm<2>(Xb3, cw, t, d);
  d2os<2>(Os, d, t, cb, 1);
  __syncthreads();
  for (int idx=t; idx<512; idx+=256){      // v += Os ; Xb = bf16(new v)
    int r=idx>>5, k4=(idx&31)*4; int gr=row0+r;
    float4 f=(gr<N)? *(const float4*)(v+(size_t)gr*128+k4):make_float4(0,0,0,0);
    f.x+=Os[r][k4]; f.y+=Os[r][k4+1]; f.z+=Os[r][k4+2]; f.w+=Os[r][k4+3];
    if (gr<N) *(float4*)(v+(size_t)gr*128+k4)=f;
    unsigned r0 = (unsigned)f2b(f.x) | ((unsigned)f2b(f.y)<<16);
    unsigned r1 = (unsigned)f2b(f.z) | ((unsigned)f2b(f.w)<<16);
    *(uint2*)&Xb[r][k4] = make_uint2(r0,r1);
  }
  __syncthreads();
  mgemm<2>(Xb, linA, t, d);
  d2glob(vlin, d, t, row0, N);
  mgemm<2>(Xb, linB, t, d);
  d2glob(vlinh, d, t, row0, N);
}

// -------------- F_last: update_v(3) + readout (update_u) --------------------
__global__ __launch_bounds__(256) void f_last(
    const float* __restrict__ accR, const float* __restrict__ accH,
    const float* __restrict__ v,
    const ushort* __restrict__ v1w, const float* __restrict__ v1b,
    const ushort* __restrict__ v2w, const float* __restrict__ v2b,
    const ushort* __restrict__ vh1w, const float* __restrict__ vh1b,
    const ushort* __restrict__ vh2w, const float* __restrict__ vh2b,
    const ushort* __restrict__ cw, const float* __restrict__ cb,
    const ushort* __restrict__ u1w, const float* __restrict__ u1b,
    const float* __restrict__ u2w, const float* __restrict__ u2b,
    const int* __restrict__ batch, float* __restrict__ uacc, int N){
  __shared__ ushort Xb[16][136];
  __shared__ ushort Xb2[16][136];
  __shared__ ushort Xb3[16][136];
  __shared__ float  Os[16][132];
  __shared__ float ss[16];
  __shared__ int   bb[16];
  int t=threadIdx.x; int row0=blockIdx.x*16;
  f32x4 d[2]; f32x4 d1[1];

  for (int path=0; path<2; path++){
    const float* X = path? accH : accR;
    __syncthreads();
    for (int idx=t; idx<512; idx+=256){
      int r=idx>>5, k4=(idx&31)*4; int gr=row0+r;
      float4 f=(gr<N)? *(const float4*)(X+(size_t)gr*128+k4):make_float4(0,0,0,0);
      unsigned r0 = (unsigned)f2b(f.x) | ((unsigned)f2b(f.y)<<16);
      unsigned r1 = (unsigned)f2b(f.z) | ((unsigned)f2b(f.w)<<16);
      *(uint2*)&Xb[r][k4] = make_uint2(r0,r1);
    }
    __syncthreads();
    mgemm<2>(Xb, path?vh1w:v1w, t, d);
    d2tile<2>(Xb2, d, t, 0, path?vh1b:v1b, 1);
    __syncthreads();
    mgemm<1>(Xb2, path?vh2w:v2w, t, d1);
    d2tile<1>(Xb3, d1, t, path*64, path?vh2b:v2b, 0);
  }
  __syncthreads();
  mgemm<2>(Xb3, cw, t, d);
  d2os<2>(Os, d, t, cb, 1);
  __syncthreads();
  for (int idx=t; idx<512; idx+=256){      // Xb = bf16(v + dssp(cat))
    int r=idx>>5, k4=(idx&31)*4; int gr=row0+r;
    float4 f=(gr<N)? *(const float4*)(v+(size_t)gr*128+k4):make_float4(0,0,0,0);
    f.x+=Os[r][k4]; f.y+=Os[r][k4+1]; f.z+=Os[r][k4+2]; f.w+=Os[r][k4+3];
    unsigned r0 = (unsigned)f2b(f.x) | ((unsigned)f2b(f.y)<<16);
    unsigned r1 = (unsigned)f2b(f.z) | ((unsigned)f2b(f.w)<<16);
    *(uint2*)&Xb[r][k4] = make_uint2(r0,r1);
  }
  __syncthreads();
  mgemm<1>(Xb, u1w, t, d1);                // 64 cols
  d2os<1>(Os, d1, t, u1b, 1);
  __syncthreads();
  if (t<16){
    int gr=row0+t;
    float s=0.f; int bt=-1;
    if (gr<N){
      s = u2b[0];
      for (int c=0;c<64;c++) s += Os[t][c]*u2w[c];
      bt = clampi(batch[gr],0,63);
    }
    ss[t]=s; bb[t]=bt;
  }
  __syncthreads();
  if (t==0){
    float run=0.f; int cur=-1;
    for (int q=0;q<16;q++){
      int bq=bb[q];
      if (bq<0) continue;
      if (bq!=cur){ if (cur>=0) atomicAdd(&uacc[cur],run); cur=bq; run=0.f; }
      run += ss[q];
    }
    if (cur>=0) atomicAdd(&uacc[cur],run);
  }
}

// ------------- hull filter: 64 rows/block, one 16-row subtile per wave ------
__global__ __launch_bounds__(256) void hull_all(const int2* __restrict__ spk_h,
    const float* __restrict__ fea,
    const float* __restrict__ mlph_w1, const float* __restrict__ mlph_b1,
    const ushort* __restrict__ mlph_w2b, const float* __restrict__ mlph_b2,
    ushort* __restrict__ WhT_base, size_t lstride, int EHpad,
    int EH, int tilesPerLayer, int l0){
  int l    = l0 + blockIdx.x / tilesPerLayer;
  int tile = blockIdx.x % tilesPerLayer;
  int row0 = tile*64;
  const float* w1 = mlph_w1 + l*128*7;
  const float* b1 = mlph_b1 + l*128;
  const ushort* w2 = mlph_w2b + (size_t)l*16384;
  const float* b2 = mlph_b2 + l*128;
  ushort* WhT = WhT_base + (size_t)(l-l0)*lstride;
  __shared__ float Fs[64][8];
  __shared__ ushort Xb[64][136];
  int t=threadIdx.x;
  for (int idx=t; idx<448; idx+=256){
    int r=idx/7, k=idx%7;
    int p=row0+r;
    int eid=(p<EH)? clampi(spk_h[p].y,0,EH-1):0;
    Fs[r][k]=(p<EH)? fea[(size_t)eid*7+k]:0.f;
  }
  __syncthreads();
  {
    // thread -> 4 cols (reg-cached weights) x 8 rows
    int c0=(t&31)*4, r0=(t>>5)*8;
    float w[4][7]; float bb[4];
    #pragma unroll
    for (int cc=0;cc<4;cc++){
      bb[cc]=b1[c0+cc];
      #pragma unroll
      for (int k=0;k<7;k++) w[cc][k]=w1[(c0+cc)*7+k];
    }
    #pragma unroll
    for (int rr=0;rr<8;rr++){
      int r=r0+rr;
      float fv[7];
      #pragma unroll
      for (int k=0;k<7;k++) fv[k]=Fs[r][k];
      ushort o[4];
      #pragma unroll
      for (int cc=0;cc<4;cc++){
        float s=bb[cc];
        #pragma unroll
        for (int k=0;k<7;k++) s=fmaf(fv[k],w[cc][k],s);
        o[cc]=f2b(dssp(s));
      }
      unsigned lo=(unsigned)o[0]|((unsigned)o[1]<<16);
      unsigned hi=(unsigned)o[2]|((unsigned)o[3]<<16);
      *(uint2*)&Xb[r][c0]=make_uint2(lo,hi);
    }
  }
  __syncthreads();
  int lane=t&63, w=t>>6;
  const ushort (*Xw)[136] = (const ushort (*)[136])&Xb[w*16][0];
  f32x4 d[8];
  #pragma unroll
  for (int ct=0;ct<8;ct++) d[ct]=(f32x4){0.f,0.f,0.f,0.f};
  #pragma unroll
  for (int kc=0;kc<4;kc++){
    short8 a = afragb(Xw, lane, kc*32);
    #pragma unroll
    for (int ct=0;ct<8;ct++){
      short8 b = bfrag(w2, ct*16, lane, kc*32);
      d[ct] = __builtin_amdgcn_mfma_f32_16x16x32_bf16(a, b, d[ct], 0, 0, 0);
    }
  }
  int q=(lane>>4)&3, n=lane&15;
  int p0 = row0 + w*16 + q*4;          // EHpad is 64-aligned: pad space is writable
  #pragma unroll
  for (int ct=0;ct<8;ct++){
    int c=ct*16+n;
    float bv=b2[c];
    unsigned r0s=(unsigned)f2b(d[ct][0]+bv)|((unsigned)f2b(d[ct][1]+bv)<<16);
    unsigned r1s=(unsigned)f2b(d[ct][2]+bv)|((unsigned)f2b(d[ct][3]+bv)<<16);
    *(uint2*)(WhT + (size_t)c*EHpad + p0) = make_uint2(r0s,r1s);
  }
}

// ------------------------------ CSR segment reductions ----------------------
__device__ __forceinline__ float rlerp(unsigned y, const unsigned* __restrict__ Wpk, int f){
  int i0 = (int)(y>>16);
  float fr = (float)(y&0xFFFFu)*(1.f/65536.f);
  unsigned u = Wpk[(size_t)i0*128+f];
  float w0=__uint_as_float(u<<16), w1=__uint_as_float(u&0xFFFF0000u);
  return fmaf(fr, w1-w0, w0);
}

__global__ __launch_bounds__(128) void acc_both(
    const int* __restrict__ off_r, const int2* __restrict__ spk_r,
    const ushort* __restrict__ vlin, const unsigned* __restrict__ Wpk,
    float* __restrict__ accR,
    const int* __restrict__ off_h, const int2* __restrict__ spk_h,
    const ushort* __restrict__ vlinh, const ushort* __restrict__ WhT, int EHpad,
    float* __restrict__ accH,
    int Etot, int EHtot, int N){
  int f = threadIdx.x;
  if ((int)blockIdx.x < N){
    int n = blockIdx.x;
    int b = clampi(off_r[n], 0, Etot);
    int e = clampi(off_r[n+1], b, Etot);
    float a = 0.f;
    int p = b;
    for (; p+4<=e; p+=4){
      int2 k0=spk_r[p], k1=spk_r[p+1], k2=spk_r[p+2], k3=spk_r[p+3];
      float v0 = b2f16(vlin[(size_t)k0.x*128+f]);
      float v1 = b2f16(vlin[(size_t)k1.x*128+f]);
      float v2 = b2f16(vlin[(size_t)k2.x*128+f]);
      float v3 = b2f16(vlin[(size_t)k3.x*128+f]);
      float w0 = rlerp((unsigned)k0.y, Wpk, f);
      float w1 = rlerp((unsigned)k1.y, Wpk, f);
      float w2 = rlerp((unsigned)k2.y, Wpk, f);
      float w3 = rlerp((unsigned)k3.y, Wpk, f);
      a += v0*w0 + v1*w1 + v2*w2 + v3*w3;
    }
    for (; p<e; p++){
      int2 k0=spk_r[p];
      a += b2f16(vlin[(size_t)k0.x*128+f]) * rlerp((unsigned)k0.y, Wpk, f);
    }
    accR[(size_t)n*128+f] = a;
  } else {
    int n = blockIdx.x - N;
    int b = clampi(off_h[n], 0, EHtot);
    int e = clampi(off_h[n+1], b, EHtot);
    const ushort* wrow = WhT + (size_t)f*EHpad;
    float a = 0.f;
    int p = b;
    for (; p+4<=e; p+=4){
      int2 k0=spk_h[p], k1=spk_h[p+1], k2=spk_h[p+2], k3=spk_h[p+3];
      float v0 = b2f16(vlinh[(size_t)k0.x*128+f]);
      float v1 = b2f16(vlinh[(size_t)k1.x*128+f]);
      float v2 = b2f16(vlinh[(size_t)k2.x*128+f]);
      float v3 = b2f16(vlinh[(size_t)k3.x*128+f]);
      a += v0*b2f16(wrow[p]) + v1*b2f16(wrow[p+1]) + v2*b2f16(wrow[p+2]) + v3*b2f16(wrow[p+3]);
    }
    for (; p<e; p++){
      int2 k0=spk_h[p];
      a += b2f16(vlinh[(size_t)k0.x*128+f]) * b2f16(wrow[p]);
    }
    accH[(size_t)n*128+f] = a;
  }
}

__global__ void write_out(const float* __restrict__ uacc, void* out, const int* __restrict__ flag){
  int t = threadIdx.x;
  if (t < 64){
    if (*flag) ((bf16*)out)[t] = __float2bfloat16(uacc[t]);
    else       ((float*)out)[t] = uacc[t];
  }
}

// ----------------------------------------------------------------- launch ---
extern "C" void kernel_launch(void* const* d_in, const int* in_sizes, int n_in,
                              void* d_out, int out_size, void* d_ws, size_t ws_size,
                              hipStream_t stream){
  const int* z     = (const int*)d_in[0];
  const int* ei    = (const int*)d_in[1];
  const int* eih   = (const int*)d_in[2];
  const int* batch = (const int*)d_in[3];

  const int N  = in_sizes[0];
  const int E  = in_sizes[1]/2;
  const int EH = in_sizes[2]/2;
  const int EHpad = (EH + 63) & ~63;   // 64-aligned so hull stores need no guard

  char* wp = (char*)d_ws;
  auto alloc = [&](size_t bytes)->char*{
    char* p = wp; wp += (bytes + 255) & ~(size_t)255; return p;
  };
  int* flag    = (int*)alloc(256);
  int* cnt_r   = (int*)alloc((size_t)N*4);
  int* off_r   = (int*)alloc((size_t)(N+1)*4);
  int* cur_r   = (int*)alloc((size_t)N*4);
  int* cnt_h   = (int*)alloc((size_t)N*4);
  int* off_h   = (int*)alloc((size_t)(N+1)*4);
  int* cur_h   = (int*)alloc((size_t)N*4);
  int2* spk_r  = (int2*)alloc((size_t)E*8);
  int2* spk_h  = (int2*)alloc((size_t)EH*8);
  float* uacc  = (float*)alloc(64*4);

  SegTable tbl; tbl.count = 27; tbl.total = 0;
  float* cvt[27];
  for (int i=0;i<27;i++){
    int n = in_sizes[4+i];
    cvt[i] = (float*)alloc((size_t)n*4);
    tbl.s[i].src = d_in[4+i];
    tbl.s[i].dst = cvt[i];
    tbl.s[i].n   = n;
    tbl.total   += n;
  }
  const float* distc   = cvt[0];
  const float* feac    = cvt[1];
  const float* embc    = cvt[2];
  const float* mlp_w1  = cvt[4];
  const float* mlp_b1  = cvt[5];
  const float* mlp_w2  = cvt[6];
  const float* mlp_b2  = cvt[7];
  const float* mlph_w1 = cvt[9];
  const float* mlph_b1 = cvt[10];
  const float* mlph_b2 = cvt[12];
  const float* v1_b  = cvt[14];
  const float* v2_b  = cvt[16];
  const float* vh1_b = cvt[18];
  const float* vh2_b = cvt[20];
  const float* cat_b = cvt[22];
  const float* u1_b  = cvt[24];
  const float* u2_w  = cvt[25];
  const float* u2_b  = cvt[26];

  ushort* lin_wb   = (ushort*)alloc((size_t)4*16384*2);
  ushort* linh_wb  = (ushort*)alloc((size_t)4*16384*2);
  ushort* v1_wb    = (ushort*)alloc((size_t)4*16384*2);
  ushort* vh1_wb   = (ushort*)alloc((size_t)4*16384*2);
  ushort* cat_wb   = (ushort*)alloc((size_t)4*16384*2);
  ushort* mlph_w2b = (ushort*)alloc((size_t)4*16384*2);
  ushort* v2_wb    = (ushort*)alloc((size_t)4*8192*2);
  ushort* vh2_wb   = (ushort*)alloc((size_t)4*8192*2);
  ushort* u1_wb    = (ushort*)alloc((size_t)8192*2);
  WTable wt; wt.count = 9;
  wt.s[0] = { cvt[3],  lin_wb,   4*16384 };
  wt.s[1] = { cvt[8],  linh_wb,  4*16384 };
  wt.s[2] = { cvt[13], v1_wb,    4*16384 };
  wt.s[3] = { cvt[17], vh1_wb,   4*16384 };
  wt.s[4] = { cvt[21], cat_wb,   4*16384 };
  wt.s[5] = { cvt[11], mlph_w2b, 4*16384 };
  wt.s[6] = { cvt[15], v2_wb,    4*8192  };
  wt.s[7] = { cvt[19], vh2_wb,   4*8192  };
  wt.s[8] = { cvt[23], u1_wb,    8192    };
  wt.total = 6*4*16384 + 2*4*8192 + 8192;

  ushort*   Wtab = (ushort*)alloc((size_t)4*TBL_ROWS*128*2);
  unsigned* Wpk  = (unsigned*)alloc((size_t)4*TBL_K*128*4);
  float* v     = (float*)alloc((size_t)N*128*4);
  ushort* vlin  = (ushort*)alloc((size_t)N*128*2);
  ushort* vlinh = (ushort*)alloc((size_t)N*128*2);
  float* accR  = (float*)alloc((size_t)N*128*4);
  float* accH  = (float*)alloc((size_t)N*128*4);

  size_t used = (size_t)(wp - (char*)d_ws);
  size_t wht1 = (size_t)128*EHpad*2;
  bool pre = (ws_size >= used + 4*wht1 + 256);
  ushort* WhT = (ushort*)alloc(pre ? 4*wht1 : wht1);

  detect_mode<<<1,256,0,stream>>>((const unsigned*)d_in[6], flag);
  {
    int cb = (int)((tbl.total + 255)/256);
    if (cb > 4096) cb = 4096;
    convert_all<<<cb,256,0,stream>>>(tbl, flag);
  }
  convert_wb<<<(wt.total+255)/256,256,0,stream>>>(wt);

  int nb;
  nb = (E+255)/256;     init_all<<<nb,256,0,stream>>>(cnt_r,cnt_h,uacc,spk_r,spk_h,N,E,EH);
  nb = (E+255)/256;     count_edges<<<nb,256,0,stream>>>(ei,eih,E,EH,N,cnt_r,cnt_h);
  scan_pair<<<1,256,0,stream>>>(cnt_r,off_r,cur_r,cnt_h,off_h,cur_h,N);
  nb = (E+255)/256;     scatter_edges<<<nb,256,0,stream>>>(ei,distc,eih,E,EH,N,cur_r,cur_h,spk_r,spk_h);
  build_wtab<<<4*TBL_TILES,256,0,stream>>>(mlp_w1,mlp_b1,mlp_w2,mlp_b2,Wtab);
  pack_wtab<<<(int)((4L*TBL_K*128+255)/256),256,0,stream>>>(Wtab,Wpk);

  const int nt = (N+15)/16;
  const int ht64 = (EH+63)/64;
  if (pre)
    hull_all<<<4*ht64,256,0,stream>>>(spk_h, feac, mlph_w1, mlph_b1, mlph_w2b, mlph_b2,
                                      WhT, (size_t)128*EHpad, EHpad, EH, ht64, 0);

  f_first<<<nt,256,0,stream>>>(z, embc, v, lin_wb, linh_wb, vlin, vlinh, N);
  for (int l=0;l<4;l++){
    if (!pre)
      hull_all<<<ht64,256,0,stream>>>(spk_h, feac, mlph_w1, mlph_b1, mlph_w2b, mlph_b2,
                                      WhT, 0, EHpad, EH, ht64, l);
    const ushort* WhTl = pre ? (WhT + (size_t)l*128*EHpad) : WhT;
    acc_both<<<2*N,128,0,stream>>>(off_r, spk_r, vlin, Wpk + (size_t)l*TBL_K*128, accR,
                                   off_h, spk_h, vlinh, WhTl, EHpad, accH, E, EH, N);
    if (l<3){
      f_mid<<<nt,256,0,stream>>>(accR, accH, v,
          v1_wb + (size_t)l*16384, v1_b + l*128, v2_wb + (size_t)l*8192, v2_b + l*64,
          vh1_wb + (size_t)l*16384, vh1_b + l*128, vh2_wb + (size_t)l*8192, vh2_b + l*64,
          cat_wb + (size_t)l*16384, cat_b + l*128,
          lin_wb + (size_t)(l+1)*16384, linh_wb + (size_t)(l+1)*16384, vlin, vlinh, N);
    } else {
      f_last<<<nt,256,0,stream>>>(accR, accH, v,
          v1_wb + (size_t)l*16384, v1_b + l*128, v2_wb + (size_t)l*8192, v2_b + l*64,
          vh1_wb + (size_t)l*16384, vh1_b + l*128, vh2_wb + (size_t)l*8192, vh2_b + l*64,
          cat_wb + (size_t)l*16384, cat_b + l*128,
          u1_wb, u1_b, u2_w, u2_b, batch, uacc, N);
    }
  }
  write_out<<<1,64,0,stream>>>(uacc, d_out, flag);
}

// Round 9
// 532.312 us; speedup vs baseline: 1.8662x; 1.0887x over previous
//
#include <hip/hip_runtime.h>
#include <hip/hip_bf16.h>

typedef __hip_bfloat16 bf16;
typedef unsigned short ushort;
typedef __attribute__((ext_vector_type(8))) short short8;   // 8 bf16 (4 VGPRs)
typedef __attribute__((ext_vector_type(4))) float f32x4;

__device__ __forceinline__ float dssp(float x){
  return fmaxf(x, 0.f) + __logf(1.f + __expf(-fabsf(x))) - 0.693147180559945f;
}
__device__ __forceinline__ int clampi(int x, int lo, int hi){ return x<lo?lo:(x>hi?hi:x); }
__device__ __forceinline__ ushort f2b(float f){
  unsigned x = __float_as_uint(f);
  return (ushort)((x + 0x7fffu + ((x>>16)&1u)) >> 16);
}
__device__ __forceinline__ float b2f16(ushort u){ return __uint_as_float(((unsigned)u)<<16); }

constexpr int TBL_K    = 4096;
constexpr int TBL_ROWS = TBL_K + 1;
constexpr int TBL_TILES = (TBL_ROWS + 31) / 32;  // 129

// ------------------------------------------------- dtype detection ----------
__global__ void detect_mode(const unsigned* __restrict__ raw, int* flag){
  __shared__ int c;
  int t = threadIdx.x;
  if (t==0) c = 0;
  __syncthreads();
  unsigned u  = raw[t];
  unsigned lo = u & 0xFFFFu;
  int e = (int)((lo >> 7) & 0xFF);
  int ok = (lo==0u) || (e >= 0x70 && e <= 0x8F);
  atomicAdd(&c, ok);
  __syncthreads();
  if (t==0) *flag = (c >= 160) ? 1 : 0;   // 1 = bf16 storage, 0 = f32 storage
}

// ---------------------------------------------- canonical fp32 conversion ---
struct Seg { const void* src; float* dst; int n; };
struct SegTable { Seg s[27]; int count; long total; };

__global__ void convert_all(SegTable tbl, const int* __restrict__ flag){
  int mode = *flag;
  long tid    = (long)blockIdx.x*blockDim.x + threadIdx.x;
  long stride = (long)gridDim.x*blockDim.x;
  for (long i=tid; i<tbl.total; i+=stride){
    long off = i; int k = 0;
    while (k < tbl.count-1 && off >= tbl.s[k].n){ off -= tbl.s[k].n; k++; }
    float f;
    if (mode) f = __bfloat162float(((const bf16*)tbl.s[k].src)[off]);
    else      f = ((const float*)tbl.s[k].src)[off];
    tbl.s[k].dst[off] = (f==f) ? f : 0.f;
  }
}

// ---------------------------------------- bf16 weight copies for MFMA -------
struct WSeg { const float* src; ushort* dst; int n; };
struct WTable { WSeg s[9]; int count; int total; };

__global__ void convert_wb(WTable wt){
  int tid = blockIdx.x*blockDim.x + threadIdx.x;
  if (tid >= wt.total) return;
  int off = tid, k = 0;
  while (k < wt.count-1 && off >= wt.s[k].n){ off -= wt.s[k].n; k++; }
  wt.s[k].dst[off] = f2b(wt.s[k].src[off]);
}

// ------------------------------------------------------------------ setup ---
__global__ void init_all(int* cnt_r, int* cnt_h, float* uacc,
                         int2* spk_r, int2* spk_h, int N, int E, int EH){
  int t = blockIdx.x*blockDim.x + threadIdx.x;
  if (t < N){ cnt_r[t]=0; cnt_h[t]=0; }
  if (t < 64) uacc[t]=0.f;
  if (t < E)  spk_r[t]=make_int2(0,0);
  if (t < EH) spk_h[t]=make_int2(0,0);
}

__global__ void count_edges(const int* __restrict__ ei, const int* __restrict__ eih,
                            int E, int EH, int N, int* cnt_r, int* cnt_h){
  int t = blockIdx.x*blockDim.x + threadIdx.x;
  if (t < E)  atomicAdd(&cnt_r[clampi(ei[E + t], 0, N-1)], 1);
  if (t < EH) atomicAdd(&cnt_h[clampi(eih[EH + t], 0, N-1)], 1);
}

__global__ __launch_bounds__(1024) void scan_pair(const int* cnt_r, int* off_r, int* cur_r,
                                                  const int* cnt_h, int* off_h, int* cur_h, int N){
  __shared__ int s[1024];
  int t = threadIdx.x;
  int CH = (N + 1023) / 1024;
  for (int which=0; which<2; which++){
    const int* cnt = which? cnt_h : cnt_r;
    int* off = which? off_h : off_r;
    int* cur = which? cur_h : cur_r;
    int base = t*CH;
    int sum = 0;
    for (int q=0;q<CH;q++){ int idx=base+q; sum += (idx<N)? cnt[idx] : 0; }
    __syncthreads();
    s[t]=sum; __syncthreads();
    for (int ofs=1; ofs<1024; ofs<<=1){
      int v = s[t]; int vp = (t>=ofs)? s[t-ofs] : 0;
      __syncthreads(); s[t]=v+vp; __syncthreads();
    }
    int run = (t>0)? s[t-1] : 0;
    for (int q=0;q<CH;q++){
      int idx=base+q;
      if (idx<N){ off[idx]=run; cur[idx]=run; run += cnt[idx]; }
    }
    if (t==1023) off[N] = s[1023];
  }
}

// digest dist into (i0<<16)|fr_u16 at scatter time
__global__ void scatter_edges(const int* __restrict__ ei, const float* __restrict__ distc,
                              const int* __restrict__ eih, int E, int EH, int N,
                              int* cur_r, int* cur_h, int2* spk_r, int2* spk_h){
  int t = blockIdx.x*blockDim.x + threadIdx.x;
  if (t < E){
    int i = clampi(ei[E+t], 0, N-1);
    int p = clampi(atomicAdd(&cur_r[i], 1), 0, E-1);
    float x = fminf(fmaxf(distc[t]*(4096.0f/5.0f), 0.f), 4095.999f);
    int i0 = (int)x; if (i0 > TBL_K-1) i0 = TBL_K-1;
    unsigned fr16 = (unsigned)((x - (float)i0)*65536.0f); if (fr16 > 65535u) fr16 = 65535u;
    spk_r[p] = make_int2(clampi(ei[t],0,N-1), (int)(((unsigned)i0<<16)|fr16));
  }
  if (t < EH){
    int ih = clampi(eih[EH+t], 0, N-1);
    int p = clampi(atomicAdd(&cur_h[ih], 1), 0, EH-1);
    spk_h[p] = make_int2(clampi(eih[t],0,N-1), t);
  }
}

// --------------------------------------------- W(dist) lookup table (bf16) ---
__global__ __launch_bounds__(256) void build_wtab(const float* __restrict__ mlp_w1,
    const float* __restrict__ mlp_b1, const float* __restrict__ mlp_w2,
    const float* __restrict__ mlp_b2, ushort* __restrict__ Wtab){
  int l    = blockIdx.x / TBL_TILES;
  int tile = blockIdx.x % TBL_TILES;
  int row0 = tile * 32;
  const float* w1 = mlp_w1 + l*128*25;
  const float* b1 = mlp_b1 + l*128;
  const float* w2 = mlp_w2 + l*128*128;
  const float* b2 = mlp_b2 + l*128;
  __shared__ float Gs[32][26];
  __shared__ float Ts[32][129];
  __shared__ float Ws[32][129];
  int t = threadIdx.x;
  for (int idx=t; idx<32*25; idx+=256){
    int r = idx/25, k = idx%25;
    float d = (row0+r) * (5.0f/4096.0f);
    float x = d - (float)k*(5.0f/24.0f);
    Gs[r][k] = __expf(-11.52f*x*x);
  }
  __syncthreads();
  int rg = t&7, cg = t>>3;
  #pragma unroll
  for (int ri=0;ri<4;ri++){
    int r = rg*4+ri;
    #pragma unroll
    for (int ci=0;ci<4;ci++){
      int c = cg*4+ci;
      float s = b1[c];
      for (int k=0;k<25;k++) s += Gs[r][k]*w1[c*25+k];
      Ts[r][c] = dssp(s);
    }
  }
  float acc[4][4] = {};
  for (int k0=0;k0<128;k0+=32){
    __syncthreads();
    for (int idx=t; idx<1024; idx+=256){
      int c=idx>>3, kk4=(idx&7)*4;
      float4 f = *(const float4*)(w2+(size_t)c*128+k0+kk4);
      Ws[kk4][c]=f.x; Ws[kk4+1][c]=f.y; Ws[kk4+2][c]=f.z; Ws[kk4+3][c]=f.w;
    }
    __syncthreads();
    for (int kk=0;kk<32;kk++){
      float xv[4];
      #pragma unroll
      for (int ri=0;ri<4;ri++) xv[ri]=Ts[rg*4+ri][k0+kk];
      #pragma unroll
      for (int ci=0;ci<4;ci++){
        float wv = Ws[kk][cg*4+ci];
        #pragma unroll
        for (int ri=0;ri<4;ri++) acc[ri][ci] += xv[ri]*wv;
      }
    }
  }
  #pragma unroll
  for (int ri=0;ri<4;ri++){
    int r = row0 + rg*4 + ri;
    if (r >= TBL_ROWS) continue;
    float d  = r * (5.0f/4096.0f);
    float Cf = 0.5f*(cosf(d*(3.14159265358979f/5.0f))+1.0f);
    #pragma unroll
    for (int ci=0;ci<4;ci++){
      int c = cg*4+ci;
      Wtab[((size_t)l*TBL_ROWS + r)*128 + c] = f2b((acc[ri][ci] + b2[c]) * Cf);
    }
  }
}

__global__ void pack_wtab(const ushort* __restrict__ Wtab, unsigned* __restrict__ Wpk){
  long t = (long)blockIdx.x*blockDim.x + threadIdx.x;
  const long TOT = 4L*TBL_K*128;
  if (t < TOT){
    int l = (int)(t / ((long)TBL_K*128));
    long rem = t % ((long)TBL_K*128);
    int r = (int)(rem >> 7), f = (int)(rem & 127);
    const ushort* base = Wtab + (size_t)l*TBL_ROWS*128;
    Wpk[t] = (((unsigned)base[(size_t)(r+1)*128+f])<<16) | (unsigned)base[(size_t)r*128+f];
  }
}

// ------------------------------ MFMA tile helpers ---------------------------
// A-tile: bf16 LDS rows stride 136 (conflict-free b128 frags).
// A-frag: A[m=lane&15][k=quad*8+j]; B-frag: W[c][k] row-major bf16 global.
// C/D: row=quad*4+reg, col=lane&15. Wave w covers cols w*(NT*16)..
__device__ __forceinline__ short8 afragb(const ushort (*Xb)[136], int lane, int k0){
  int m=lane&15, q=(lane>>4)&3;
  return *(const short8*)(&Xb[m][k0+q*8]);
}
__device__ __forceinline__ short8 bfrag(const ushort* __restrict__ W, int cbase, int lane, int k0){
  int n=lane&15, q=(lane>>4)&3;
  return *(const short8*)(W + (size_t)(cbase+n)*128 + k0 + q*8);
}
template<int NT>
__device__ __forceinline__ void mgemm(const ushort (*Xb)[136],
    const ushort* __restrict__ W, int t, f32x4 d[NT]){
  int lane=t&63, w=t>>6;
  #pragma unroll
  for (int ct=0;ct<NT;ct++) d[ct]=(f32x4){0.f,0.f,0.f,0.f};
  #pragma unroll
  for (int kc=0;kc<4;kc++){
    short8 a = afragb(Xb, lane, kc*32);
    #pragma unroll
    for (int ct=0;ct<NT;ct++){
      short8 b = bfrag(W, w*(NT*16)+ct*16, lane, kc*32);
      d[ct] = __builtin_amdgcn_mfma_f32_16x16x32_bf16(a, b, d[ct], 0, 0, 0);
    }
  }
}
// D -> bf16 A-tile (bias + optional ssp)
template<int NT>
__device__ __forceinline__ void d2tile(ushort (*Y)[136], const f32x4 d[NT], int t,
    int colofs, const float* __restrict__ bias, int do_ssp){
  int lane=t&63, w=t>>6, q=(lane>>4)&3, n=lane&15;
  #pragma unroll
  for (int ct=0;ct<NT;ct++){
    int c = w*(NT*16)+ct*16+n;
    float bv = bias? bias[c] : 0.f;
    #pragma unroll
    for (int i=0;i<4;i++){
      float y = d[ct][i] + bv;
      if (do_ssp) y = dssp(y);
      Y[q*4+i][colofs+c] = f2b(y);
    }
  }
}
// D -> fp32 LDS [16][132]
template<int NT>
__device__ __forceinline__ void d2os(float (*Os)[132], const f32x4 d[NT], int t,
    const float* __restrict__ bias, int do_ssp){
  int lane=t&63, w=t>>6, q=(lane>>4)&3, n=lane&15;
  #pragma unroll
  for (int ct=0;ct<NT;ct++){
    int c = w*(NT*16)+ct*16+n;
    float bv = bias? bias[c] : 0.f;
    #pragma unroll
    for (int i=0;i<4;i++){
      float y = d[ct][i] + bv;
      if (do_ssp) y = dssp(y);
      Os[q*4+i][c] = y;
    }
  }
}
// D (NT=2, 128 cols) -> global bf16 row-major [N,128], coalesced via LDS tile
__device__ __forceinline__ void d2glob_c(ushort* __restrict__ out, const f32x4 d[2],
    int t, int row0, int N, ushort (*Tmp)[136]){
  d2tile<2>(Tmp, d, t, 0, nullptr, 0);
  __syncthreads();
  int r=t>>4, o=(t&15)*8;
  int gr=row0+r;
  if (gr<N) *(uint4*)(out + (size_t)gr*128 + o) = *(const uint4*)&Tmp[r][o];
  __syncthreads();
}

// ------------------------- F0: embed + lin + linh ---------------------------
__global__ __launch_bounds__(256) void f_first(const int* __restrict__ z,
    const float* __restrict__ emb, float* __restrict__ v,
    const ushort* __restrict__ linA, const ushort* __restrict__ linB,
    ushort* __restrict__ vlin, ushort* __restrict__ vlinh, int N){
  __shared__ ushort Xb[16][136];
  __shared__ ushort Tb[16][136];
  int t=threadIdx.x; int row0=blockIdx.x*16;
  f32x4 d[2];
  for (int idx=t; idx<512; idx+=256){
    int r=idx>>5, k4=(idx&31)*4; int gr=row0+r;
    int zz=(gr<N)? clampi(z[gr],0,99):0;
    float4 f = *(const float4*)(emb + (size_t)zz*128 + k4);
    unsigned r0 = (unsigned)f2b(f.x) | ((unsigned)f2b(f.y)<<16);
    unsigned r1 = (unsigned)f2b(f.z) | ((unsigned)f2b(f.w)<<16);
    *(uint2*)&Xb[r][k4] = make_uint2(r0,r1);
    if (gr<N) *(float4*)(v + (size_t)gr*128 + k4) = f;
  }
  __syncthreads();
  mgemm<2>(Xb, linA, t, d);
  d2glob_c(vlin, d, t, row0, N, Tb);
  mgemm<2>(Xb, linB, t, d);
  d2glob_c(vlinh, d, t, row0, N, Tb);
}

// -------------- F_mid: update_v(l) + lin(l+1) + linh(l+1) -------------------
__global__ __launch_bounds__(256) void f_mid(
    const float* __restrict__ accR, const float* __restrict__ accH,
    float* __restrict__ v,
    const ushort* __restrict__ v1w, const float* __restrict__ v1b,
    const ushort* __restrict__ v2w, const float* __restrict__ v2b,
    const ushort* __restrict__ vh1w, const float* __restrict__ vh1b,
    const ushort* __restrict__ vh2w, const float* __restrict__ vh2b,
    const ushort* __restrict__ cw, const float* __restrict__ cb,
    const ushort* __restrict__ linA, const ushort* __restrict__ linB,
    ushort* __restrict__ vlin, ushort* __restrict__ vlinh, int N){
  __shared__ ushort Xb[16][136];
  __shared__ ushort Xb2[16][136];
  __shared__ ushort Xb3[16][136];
  __shared__ float  Os[16][132];
  int t=threadIdx.x; int row0=blockIdx.x*16;
  f32x4 d[2]; f32x4 d1[1];

  for (int path=0; path<2; path++){
    const float* X = path? accH : accR;
    __syncthreads();
    for (int idx=t; idx<512; idx+=256){
      int r=idx>>5, k4=(idx&31)*4; int gr=row0+r;
      float4 f=(gr<N)? *(const float4*)(X+(size_t)gr*128+k4):make_float4(0,0,0,0);
      unsigned r0 = (unsigned)f2b(f.x) | ((unsigned)f2b(f.y)<<16);
      unsigned r1 = (unsigned)f2b(f.z) | ((unsigned)f2b(f.w)<<16);
      *(uint2*)&Xb[r][k4] = make_uint2(r0,r1);
    }
    __syncthreads();
    mgemm<2>(Xb, path?vh1w:v1w, t, d);
    d2tile<2>(Xb2, d, t, 0, path?vh1b:v1b, 1);
    __syncthreads();
    mgemm<1>(Xb2, path?vh2w:v2w, t, d1);
    d2tile<1>(Xb3, d1, t, path*64, path?vh2b:v2b, 0);
  }
  __syncthreads();
  mgemm<2>(Xb3, cw, t, d);
  d2os<2>(Os, d, t, cb, 1);
  __syncthreads();
  for (int idx=t; idx<512; idx+=256){      // v += Os ; Xb = bf16(new v)
    int r=idx>>5, k4=(idx&31)*4; int gr=row0+r;
    float4 f=(gr<N)? *(const float4*)(v+(size_t)gr*128+k4):make_float4(0,0,0,0);
    f.x+=Os[r][k4]; f.y+=Os[r][k4+1]; f.z+=Os[r][k4+2]; f.w+=Os[r][k4+3];
    if (gr<N) *(float4*)(v+(size_t)gr*128+k4)=f;
    unsigned r0 = (unsigned)f2b(f.x) | ((unsigned)f2b(f.y)<<16);
    unsigned r1 = (unsigned)f2b(f.z) | ((unsigned)f2b(f.w)<<16);
    *(uint2*)&Xb[r][k4] = make_uint2(r0,r1);
  }
  __syncthreads();
  mgemm<2>(Xb, linA, t, d);
  d2glob_c(vlin, d, t, row0, N, Xb2);
  mgemm<2>(Xb, linB, t, d);
  d2glob_c(vlinh, d, t, row0, N, Xb2);
}

// -------------- F_last: update_v(3) + readout (update_u) --------------------
__global__ __launch_bounds__(256) void f_last(
    const float* __restrict__ accR, const float* __restrict__ accH,
    const float* __restrict__ v,
    const ushort* __restrict__ v1w, const float* __restrict__ v1b,
    const ushort* __restrict__ v2w, const float* __restrict__ v2b,
    const ushort* __restrict__ vh1w, const float* __restrict__ vh1b,
    const ushort* __restrict__ vh2w, const float* __restrict__ vh2b,
    const ushort* __restrict__ cw, const float* __restrict__ cb,
    const ushort* __restrict__ u1w, const float* __restrict__ u1b,
    const float* __restrict__ u2w, const float* __restrict__ u2b,
    const int* __restrict__ batch, float* __restrict__ uacc, int N){
  __shared__ ushort Xb[16][136];
  __shared__ ushort Xb2[16][136];
  __shared__ ushort Xb3[16][136];
  __shared__ float  Os[16][132];
  __shared__ float ss[16];
  __shared__ int   bb[16];
  int t=threadIdx.x; int row0=blockIdx.x*16;
  f32x4 d[2]; f32x4 d1[1];

  for (int path=0; path<2; path++){
    const float* X = path? accH : accR;
    __syncthreads();
    for (int idx=t; idx<512; idx+=256){
      int r=idx>>5, k4=(idx&31)*4; int gr=row0+r;
      float4 f=(gr<N)? *(const float4*)(X+(size_t)gr*128+k4):make_float4(0,0,0,0);
      unsigned r0 = (unsigned)f2b(f.x) | ((unsigned)f2b(f.y)<<16);
      unsigned r1 = (unsigned)f2b(f.z) | ((unsigned)f2b(f.w)<<16);
      *(uint2*)&Xb[r][k4] = make_uint2(r0,r1);
    }
    __syncthreads();
    mgemm<2>(Xb, path?vh1w:v1w, t, d);
    d2tile<2>(Xb2, d, t, 0, path?vh1b:v1b, 1);
    __syncthreads();
    mgemm<1>(Xb2, path?vh2w:v2w, t, d1);
    d2tile<1>(Xb3, d1, t, path*64, path?vh2b:v2b, 0);
  }
  __syncthreads();
  mgemm<2>(Xb3, cw, t, d);
  d2os<2>(Os, d, t, cb, 1);
  __syncthreads();
  for (int idx=t; idx<512; idx+=256){      // Xb = bf16(v + dssp(cat))
    int r=idx>>5, k4=(idx&31)*4; int gr=row0+r;
    float4 f=(gr<N)? *(const float4*)(v+(size_t)gr*128+k4):make_float4(0,0,0,0);
    f.x+=Os[r][k4]; f.y+=Os[r][k4+1]; f.z+=Os[r][k4+2]; f.w+=Os[r][k4+3];
    unsigned r0 = (unsigned)f2b(f.x) | ((unsigned)f2b(f.y)<<16);
    unsigned r1 = (unsigned)f2b(f.z) | ((unsigned)f2b(f.w)<<16);
    *(uint2*)&Xb[r][k4] = make_uint2(r0,r1);
  }
  __syncthreads();
  mgemm<1>(Xb, u1w, t, d1);                // 64 cols
  d2os<1>(Os, d1, t, u1b, 1);
  __syncthreads();
  if (t<16){
    int gr=row0+t;
    float s=0.f; int bt=-1;
    if (gr<N){
      s = u2b[0];
      for (int c=0;c<64;c++) s += Os[t][c]*u2w[c];
      bt = clampi(batch[gr],0,63);
    }
    ss[t]=s; bb[t]=bt;
  }
  __syncthreads();
  if (t==0){
    float run=0.f; int cur=-1;
    for (int q=0;q<16;q++){
      int bq=bb[q];
      if (bq<0) continue;
      if (bq!=cur){ if (cur>=0) atomicAdd(&uacc[cur],run); cur=bq; run=0.f; }
      run += ss[q];
    }
    if (cur>=0) atomicAdd(&uacc[cur],run);
  }
}

// ------------- hull filter: 64 rows/block, coalesced column stores ----------
__global__ __launch_bounds__(256) void hull_all(const int2* __restrict__ spk_h,
    const float* __restrict__ fea,
    const float* __restrict__ mlph_w1, const float* __restrict__ mlph_b1,
    const ushort* __restrict__ mlph_w2b, const float* __restrict__ mlph_b2,
    ushort* __restrict__ WhT_base, size_t lstride, int EHpad,
    int EH, int tilesPerLayer, int l0){
  int l    = l0 + blockIdx.x / tilesPerLayer;
  int tile = blockIdx.x % tilesPerLayer;
  int row0 = tile*64;
  const float* w1 = mlph_w1 + l*128*7;
  const float* b1 = mlph_b1 + l*128;
  const ushort* w2 = mlph_w2b + (size_t)l*16384;
  const float* b2 = mlph_b2 + l*128;
  ushort* WhT = WhT_base + (size_t)(l-l0)*lstride;
  __shared__ int   Eid[64];
  __shared__ float Fs[64][8];
  __shared__ ushort Xb[64][136];
  __shared__ ushort Ys[128][70];
  int t=threadIdx.x;
  if (t < 64){
    int p=row0+t;
    Eid[t]=(p<EH)? clampi(spk_h[p].y,0,EH-1):0;
  }
  __syncthreads();
  for (int idx=t; idx<448; idx+=256){
    int r=idx/7, k=idx%7;
    int p=row0+r;
    Fs[r][k]=(p<EH)? fea[(size_t)Eid[r]*7+k]:0.f;
  }
  __syncthreads();
  {
    // thread -> 4 cols (reg-cached weights) x 8 rows
    int c0=(t&31)*4, r0=(t>>5)*8;
    float w[4][7]; float bb[4];
    #pragma unroll
    for (int cc=0;cc<4;cc++){
      bb[cc]=b1[c0+cc];
      #pragma unroll
      for (int k=0;k<7;k++) w[cc][k]=w1[(c0+cc)*7+k];
    }
    #pragma unroll
    for (int rr=0;rr<8;rr++){
      int r=r0+rr;
      float fv[7];
      #pragma unroll
      for (int k=0;k<7;k++) fv[k]=Fs[r][k];
      ushort o[4];
      #pragma unroll
      for (int cc=0;cc<4;cc++){
        float s=bb[cc];
        #pragma unroll
        for (int k=0;k<7;k++) s=fmaf(fv[k],w[cc][k],s);
        o[cc]=f2b(dssp(s));
      }
      unsigned lo=(unsigned)o[0]|((unsigned)o[1]<<16);
      unsigned hi=(unsigned)o[2]|((unsigned)o[3]<<16);
      *(uint2*)&Xb[r][c0]=make_uint2(lo,hi);
    }
  }
  __syncthreads();
  int lane=t&63, w=t>>6;
  const ushort (*Xw)[136] = (const ushort (*)[136])&Xb[w*16][0];
  f32x4 d[8];
  #pragma unroll
  for (int ct=0;ct<8;ct++) d[ct]=(f32x4){0.f,0.f,0.f,0.f};
  #pragma unroll
  for (int kc=0;kc<4;kc++){
    short8 a = afragb(Xw, lane, kc*32);
    #pragma unroll
    for (int ct=0;ct<8;ct++){
      short8 b = bfrag(w2, ct*16, lane, kc*32);
      d[ct] = __builtin_amdgcn_mfma_f32_16x16x32_bf16(a, b, d[ct], 0, 0, 0);
    }
  }
  // stage D into Ys[c][r] (c-major), then coalesced column stores
  int q=(lane>>4)&3, n=lane&15;
  #pragma unroll
  for (int ct=0;ct<8;ct++){
    int c=ct*16+n;
    float bv=b2[c];
    unsigned r0s=(unsigned)f2b(d[ct][0]+bv)|((unsigned)f2b(d[ct][1]+bv)<<16);
    unsigned r1s=(unsigned)f2b(d[ct][2]+bv)|((unsigned)f2b(d[ct][3]+bv)<<16);
    *(uint2*)&Ys[c][w*16+q*4] = make_uint2(r0s,r1s);
  }
  __syncthreads();
  // 8 lanes per column write 128 B contiguous: 4 passes x uint4/thread
  #pragma unroll
  for (int j=0;j<4;j++){
    int col = j*32 + (t>>3);
    int r0  = (t&7)*8;
    *(uint4*)(WhT + (size_t)col*EHpad + row0 + r0) = *(const uint4*)&Ys[col][r0];
  }
}

// ------------------------------ CSR segment reductions ----------------------
__device__ __forceinline__ float rlerp(unsigned y, const unsigned* __restrict__ Wpk, int f){
  int i0 = (int)(y>>16);
  float fr = (float)(y&0xFFFFu)*(1.f/65536.f);
  unsigned u = Wpk[(size_t)i0*128+f];
  float w0=__uint_as_float(u<<16), w1=__uint_as_float(u&0xFFFF0000u);
  return fmaf(fr, w1-w0, w0);
}

__global__ __launch_bounds__(128) void acc_both(
    const int* __restrict__ off_r, const int2* __restrict__ spk_r,
    const ushort* __restrict__ vlin, const unsigned* __restrict__ Wpk,
    float* __restrict__ accR,
    const int* __restrict__ off_h, const int2* __restrict__ spk_h,
    const ushort* __restrict__ vlinh, const ushort* __restrict__ WhT, int EHpad,
    float* __restrict__ accH,
    int Etot, int EHtot, int N){
  int f = threadIdx.x;
  if ((int)blockIdx.x < N){
    int n = blockIdx.x;
    int b = clampi(off_r[n], 0, Etot);
    int e = clampi(off_r[n+1], b, Etot);
    float a = 0.f;
    int p = b;
    for (; p+8<=e; p+=8){
      int2 k[8];
      #pragma unroll
      for (int j=0;j<8;j++) k[j]=spk_r[p+j];
      float vv[8], ww[8];
      #pragma unroll
      for (int j=0;j<8;j++) vv[j]=b2f16(vlin[(size_t)k[j].x*128+f]);
      #pragma unroll
      for (int j=0;j<8;j++) ww[j]=rlerp((unsigned)k[j].y, Wpk, f);
      #pragma unroll
      for (int j=0;j<8;j++) a=fmaf(vv[j],ww[j],a);
    }
    for (; p+4<=e; p+=4){
      int2 k0=spk_r[p], k1=spk_r[p+1], k2=spk_r[p+2], k3=spk_r[p+3];
      float v0 = b2f16(vlin[(size_t)k0.x*128+f]);
      float v1 = b2f16(vlin[(size_t)k1.x*128+f]);
      float v2 = b2f16(vlin[(size_t)k2.x*128+f]);
      float v3 = b2f16(vlin[(size_t)k3.x*128+f]);
      float w0 = rlerp((unsigned)k0.y, Wpk, f);
      float w1 = rlerp((unsigned)k1.y, Wpk, f);
      float w2 = rlerp((unsigned)k2.y, Wpk, f);
      float w3 = rlerp((unsigned)k3.y, Wpk, f);
      a += v0*w0 + v1*w1 + v2*w2 + v3*w3;
    }
    for (; p<e; p++){
      int2 k0=spk_r[p];
      a += b2f16(vlin[(size_t)k0.x*128+f]) * rlerp((unsigned)k0.y, Wpk, f);
    }
    accR[(size_t)n*128+f] = a;
  } else {
    int n = blockIdx.x - N;
    int b = clampi(off_h[n], 0, EHtot);
    int e = clampi(off_h[n+1], b, EHtot);
    const ushort* wrow = WhT + (size_t)f*EHpad;
    float a = 0.f;
    int p = b;
    for (; p+4<=e; p+=4){
      int2 k0=spk_h[p], k1=spk_h[p+1], k2=spk_h[p+2], k3=spk_h[p+3];
      float v0 = b2f16(vlinh[(size_t)k0.x*128+f]);
      float v1 = b2f16(vlinh[(size_t)k1.x*128+f]);
      float v2 = b2f16(vlinh[(size_t)k2.x*128+f]);
      float v3 = b2f16(vlinh[(size_t)k3.x*128+f]);
      a += v0*b2f16(wrow[p]) + v1*b2f16(wrow[p+1]) + v2*b2f16(wrow[p+2]) + v3*b2f16(wrow[p+3]);
    }
    for (; p<e; p++){
      int2 k0=spk_h[p];
      a += b2f16(vlinh[(size_t)k0.x*128+f]) * b2f16(wrow[p]);
    }
    accH[(size_t)n*128+f] = a;
  }
}

__global__ void write_out(const float* __restrict__ uacc, void* out, const int* __restrict__ flag){
  int t = threadIdx.x;
  if (t < 64){
    if (*flag) ((bf16*)out)[t] = __float2bfloat16(uacc[t]);
    else       ((float*)out)[t] = uacc[t];
  }
}

// ----------------------------------------------------------------- launch ---
extern "C" void kernel_launch(void* const* d_in, const int* in_sizes, int n_in,
                              void* d_out, int out_size, void* d_ws, size_t ws_size,
                              hipStream_t stream){
  const int* z     = (const int*)d_in[0];
  const int* ei    = (const int*)d_in[1];
  const int* eih   = (const int*)d_in[2];
  const int* batch = (const int*)d_in[3];

  const int N  = in_sizes[0];
  const int E  = in_sizes[1]/2;
  const int EH = in_sizes[2]/2;
  const int EHpad = (EH + 63) & ~63;   // 64-aligned so hull stores need no guard

  char* wp = (char*)d_ws;
  auto alloc = [&](size_t bytes)->char*{
    char* p = wp; wp += (bytes + 255) & ~(size_t)255; return p;
  };
  int* flag    = (int*)alloc(256);
  int* cnt_r   = (int*)alloc((size_t)N*4);
  int* off_r   = (int*)alloc((size_t)(N+1)*4);
  int* cur_r   = (int*)alloc((size_t)N*4);
  int* cnt_h   = (int*)alloc((size_t)N*4);
  int* off_h   = (int*)alloc((size_t)(N+1)*4);
  int* cur_h   = (int*)alloc((size_t)N*4);
  int2* spk_r  = (int2*)alloc((size_t)E*8);
  int2* spk_h  = (int2*)alloc((size_t)EH*8);
  float* uacc  = (float*)alloc(64*4);

  SegTable tbl; tbl.count = 27; tbl.total = 0;
  float* cvt[27];
  for (int i=0;i<27;i++){
    int n = in_sizes[4+i];
    cvt[i] = (float*)alloc((size_t)n*4);
    tbl.s[i].src = d_in[4+i];
    tbl.s[i].dst = cvt[i];
    tbl.s[i].n   = n;
    tbl.total   += n;
  }
  const float* distc   = cvt[0];
  const float* feac    = cvt[1];
  const float* embc    = cvt[2];
  const float* mlp_w1  = cvt[4];
  const float* mlp_b1  = cvt[5];
  const float* mlp_w2  = cvt[6];
  const float* mlp_b2  = cvt[7];
  const float* mlph_w1 = cvt[9];
  const float* mlph_b1 = cvt[10];
  const float* mlph_b2 = cvt[12];
  const float* v1_b  = cvt[14];
  const float* v2_b  = cvt[16];
  const float* vh1_b = cvt[18];
  const float* vh2_b = cvt[20];
  const float* cat_b = cvt[22];
  const float* u1_b  = cvt[24];
  const float* u2_w  = cvt[25];
  const float* u2_b  = cvt[26];

  ushort* lin_wb   = (ushort*)alloc((size_t)4*16384*2);
  ushort* linh_wb  = (ushort*)alloc((size_t)4*16384*2);
  ushort* v1_wb    = (ushort*)alloc((size_t)4*16384*2);
  ushort* vh1_wb   = (ushort*)alloc((size_t)4*16384*2);
  ushort* cat_wb   = (ushort*)alloc((size_t)4*16384*2);
  ushort* mlph_w2b = (ushort*)alloc((size_t)4*16384*2);
  ushort* v2_wb    = (ushort*)alloc((size_t)4*8192*2);
  ushort* vh2_wb   = (ushort*)alloc((size_t)4*8192*2);
  ushort* u1_wb    = (ushort*)alloc((size_t)8192*2);
  WTable wt; wt.count = 9;
  wt.s[0] = { cvt[3],  lin_wb,   4*16384 };
  wt.s[1] = { cvt[8],  linh_wb,  4*16384 };
  wt.s[2] = { cvt[13], v1_wb,    4*16384 };
  wt.s[3] = { cvt[17], vh1_wb,   4*16384 };
  wt.s[4] = { cvt[21], cat_wb,   4*16384 };
  wt.s[5] = { cvt[11], mlph_w2b, 4*16384 };
  wt.s[6] = { cvt[15], v2_wb,    4*8192  };
  wt.s[7] = { cvt[19], vh2_wb,   4*8192  };
  wt.s[8] = { cvt[23], u1_wb,    8192    };
  wt.total = 6*4*16384 + 2*4*8192 + 8192;

  ushort*   Wtab = (ushort*)alloc((size_t)4*TBL_ROWS*128*2);
  unsigned* Wpk  = (unsigned*)alloc((size_t)4*TBL_K*128*4);
  float* v     = (float*)alloc((size_t)N*128*4);
  ushort* vlin  = (ushort*)alloc((size_t)N*128*2);
  ushort* vlinh = (ushort*)alloc((size_t)N*128*2);
  float* accR  = (float*)alloc((size_t)N*128*4);
  float* accH  = (float*)alloc((size_t)N*128*4);

  size_t used = (size_t)(wp - (char*)d_ws);
  size_t wht1 = (size_t)128*EHpad*2;
  bool pre = (ws_size >= used + 4*wht1 + 256);
  ushort* WhT = (ushort*)alloc(pre ? 4*wht1 : wht1);

  detect_mode<<<1,256,0,stream>>>((const unsigned*)d_in[6], flag);
  {
    int cb = (int)((tbl.total + 255)/256);
    if (cb > 4096) cb = 4096;
    convert_all<<<cb,256,0,stream>>>(tbl, flag);
  }
  convert_wb<<<(wt.total+255)/256,256,0,stream>>>(wt);

  int nb;
  nb = (E+255)/256;     init_all<<<nb,256,0,stream>>>(cnt_r,cnt_h,uacc,spk_r,spk_h,N,E,EH);
  nb = (E+255)/256;     count_edges<<<nb,256,0,stream>>>(ei,eih,E,EH,N,cnt_r,cnt_h);
  scan_pair<<<1,1024,0,stream>>>(cnt_r,off_r,cur_r,cnt_h,off_h,cur_h,N);
  nb = (E+255)/256;     scatter_edges<<<nb,256,0,stream>>>(ei,distc,eih,E,EH,N,cur_r,cur_h,spk_r,spk_h);
  build_wtab<<<4*TBL_TILES,256,0,stream>>>(mlp_w1,mlp_b1,mlp_w2,mlp_b2,Wtab);
  pack_wtab<<<(int)((4L*TBL_K*128+255)/256),256,0,stream>>>(Wtab,Wpk);

  const int nt = (N+15)/16;
  const int ht64 = (EH+63)/64;
  if (pre)
    hull_all<<<4*ht64,256,0,stream>>>(spk_h, feac, mlph_w1, mlph_b1, mlph_w2b, mlph_b2,
                                      WhT, (size_t)128*EHpad, EHpad, EH, ht64, 0);

  f_first<<<nt,256,0,stream>>>(z, embc, v, lin_wb, linh_wb, vlin, vlinh, N);
  for (int l=0;l<4;l++){
    if (!pre)
      hull_all<<<ht64,256,0,stream>>>(spk_h, feac, mlph_w1, mlph_b1, mlph_w2b, mlph_b2,
                                      WhT, 0, EHpad, EH, ht64, l);
    const ushort* WhTl = pre ? (WhT + (size_t)l*128*EHpad) : WhT;
    acc_both<<<2*N,128,0,stream>>>(off_r, spk_r, vlin, Wpk + (size_t)l*TBL_K*128, accR,
                                   off_h, spk_h, vlinh, WhTl, EHpad, accH, E, EH, N);
    if (l<3){
      f_mid<<<nt,256,0,stream>>>(accR, accH, v,
          v1_wb + (size_t)l*16384, v1_b + l*128, v2_wb + (size_t)l*8192, v2_b + l*64,
          vh1_wb + (size_t)l*16384, vh1_b + l*128, vh2_wb + (size_t)l*8192, vh2_b + l*64,
          cat_wb + (size_t)l*16384, cat_b + l*128,
          lin_wb + (size_t)(l+1)*16384, linh_wb + (size_t)(l+1)*16384, vlin, vlinh, N);
    } else {
      f_last<<<nt,256,0,stream>>>(accR, accH, v,
          v1_wb + (size_t)l*16384, v1_b + l*128, v2_wb + (size_t)l*8192, v2_b + l*64,
          vh1_wb + (size_t)l*16384, vh1_b + l*128, vh2_wb + (size_t)l*8192, vh2_b + l*64,
          cat_wb + (size_t)l*16384, cat_b + l*128,
          u1_wb, u1_b, u2_w, u2_b, batch, uacc, N);
    }
  }
  write_out<<<1,64,0,stream>>>(uacc, d_out, flag);
}

// Round 10
// 485.485 us; speedup vs baseline: 2.0462x; 1.0965x over previous
//
#include <hip/hip_runtime.h>
#include <hip/hip_bf16.h>

typedef __hip_bfloat16 bf16;
typedef unsigned short ushort;
typedef __attribute__((ext_vector_type(8))) short short8;   // 8 bf16 (4 VGPRs)
typedef __attribute__((ext_vector_type(4))) float f32x4;

__device__ __forceinline__ float dssp(float x){
  return fmaxf(x, 0.f) + __logf(1.f + __expf(-fabsf(x))) - 0.693147180559945f;
}
__device__ __forceinline__ int clampi(int x, int lo, int hi){ return x<lo?lo:(x>hi?hi:x); }
__device__ __forceinline__ ushort f2b(float f){
  unsigned x = __float_as_uint(f);
  return (ushort)((x + 0x7fffu + ((x>>16)&1u)) >> 16);
}
__device__ __forceinline__ float b2f16(ushort u){ return __uint_as_float(((unsigned)u)<<16); }

constexpr int TBL_K    = 4096;
constexpr int TBL_ROWS = TBL_K + 1;
constexpr int TBL_TILES = (TBL_ROWS + 31) / 32;  // 129

// ------------------------------------------------- dtype detection ----------
__global__ void detect_mode(const unsigned* __restrict__ raw, int* flag){
  __shared__ int c;
  int t = threadIdx.x;
  if (t==0) c = 0;
  __syncthreads();
  unsigned u  = raw[t];
  unsigned lo = u & 0xFFFFu;
  int e = (int)((lo >> 7) & 0xFF);
  int ok = (lo==0u) || (e >= 0x70 && e <= 0x8F);
  atomicAdd(&c, ok);
  __syncthreads();
  if (t==0) *flag = (c >= 160) ? 1 : 0;   // 1 = bf16 storage, 0 = f32 storage
}

// ---------------------------------------------- canonical fp32 conversion ---
struct Seg { const void* src; float* dst; int n; };
struct SegTable { Seg s[27]; int count; long total; };

__global__ void convert_all(SegTable tbl, const int* __restrict__ flag){
  int mode = *flag;
  long tid    = (long)blockIdx.x*blockDim.x + threadIdx.x;
  long stride = (long)gridDim.x*blockDim.x;
  for (long i=tid; i<tbl.total; i+=stride){
    long off = i; int k = 0;
    while (k < tbl.count-1 && off >= tbl.s[k].n){ off -= tbl.s[k].n; k++; }
    float f;
    if (mode) f = __bfloat162float(((const bf16*)tbl.s[k].src)[off]);
    else      f = ((const float*)tbl.s[k].src)[off];
    tbl.s[k].dst[off] = (f==f) ? f : 0.f;
  }
}

// ---------------------------------------- bf16 weight copies for MFMA -------
struct WSeg { const float* src; ushort* dst; int n; };
struct WTable { WSeg s[9]; int count; int total; };

__global__ void convert_wb(WTable wt){
  int tid = blockIdx.x*blockDim.x + threadIdx.x;
  if (tid >= wt.total) return;
  int off = tid, k = 0;
  while (k < wt.count-1 && off >= wt.s[k].n){ off -= wt.s[k].n; k++; }
  wt.s[k].dst[off] = f2b(wt.s[k].src[off]);
}

// ------------------------------------------------------------------ setup ---
__global__ void init_all(int* cnt_r, int* cnt_h, float* uacc,
                         int2* spk_r, int2* spk_h, int N, int E, int EH){
  int t = blockIdx.x*blockDim.x + threadIdx.x;
  if (t < N){ cnt_r[t]=0; cnt_h[t]=0; }
  if (t < 64) uacc[t]=0.f;
  if (t < E)  spk_r[t]=make_int2(0,0);
  if (t < EH) spk_h[t]=make_int2(0,0);
}

__global__ void count_edges(const int* __restrict__ ei, const int* __restrict__ eih,
                            int E, int EH, int N, int* cnt_r, int* cnt_h){
  int t = blockIdx.x*blockDim.x + threadIdx.x;
  if (t < E)  atomicAdd(&cnt_r[clampi(ei[E + t], 0, N-1)], 1);
  if (t < EH) atomicAdd(&cnt_h[clampi(eih[EH + t], 0, N-1)], 1);
}

__global__ __launch_bounds__(1024) void scan_pair(const int* cnt_r, int* off_r, int* cur_r,
                                                  const int* cnt_h, int* off_h, int* cur_h, int N){
  __shared__ int s[1024];
  int t = threadIdx.x;
  int CH = (N + 1023) / 1024;
  for (int which=0; which<2; which++){
    const int* cnt = which? cnt_h : cnt_r;
    int* off = which? off_h : off_r;
    int* cur = which? cur_h : cur_r;
    int base = t*CH;
    int sum = 0;
    for (int q=0;q<CH;q++){ int idx=base+q; sum += (idx<N)? cnt[idx] : 0; }
    __syncthreads();
    s[t]=sum; __syncthreads();
    for (int ofs=1; ofs<1024; ofs<<=1){
      int v = s[t]; int vp = (t>=ofs)? s[t-ofs] : 0;
      __syncthreads(); s[t]=v+vp; __syncthreads();
    }
    int run = (t>0)? s[t-1] : 0;
    for (int q=0;q<CH;q++){
      int idx=base+q;
      if (idx<N){ off[idx]=run; cur[idx]=run; run += cnt[idx]; }
    }
    if (t==1023) off[N] = s[1023];
  }
}

// digest dist into (i0<<16)|fr_u16 at scatter time
__global__ void scatter_edges(const int* __restrict__ ei, const float* __restrict__ distc,
                              const int* __restrict__ eih, int E, int EH, int N,
                              int* cur_r, int* cur_h, int2* spk_r, int2* spk_h){
  int t = blockIdx.x*blockDim.x + threadIdx.x;
  if (t < E){
    int i = clampi(ei[E+t], 0, N-1);
    int p = clampi(atomicAdd(&cur_r[i], 1), 0, E-1);
    float x = fminf(fmaxf(distc[t]*(4096.0f/5.0f), 0.f), 4095.999f);
    int i0 = (int)x; if (i0 > TBL_K-1) i0 = TBL_K-1;
    unsigned fr16 = (unsigned)((x - (float)i0)*65536.0f); if (fr16 > 65535u) fr16 = 65535u;
    spk_r[p] = make_int2(clampi(ei[t],0,N-1), (int)(((unsigned)i0<<16)|fr16));
  }
  if (t < EH){
    int ih = clampi(eih[EH+t], 0, N-1);
    int p = clampi(atomicAdd(&cur_h[ih], 1), 0, EH-1);
    spk_h[p] = make_int2(clampi(eih[t],0,N-1), t);
  }
}

// --------------------------------------------- W(dist) lookup table (bf16) ---
__global__ __launch_bounds__(256) void build_wtab(const float* __restrict__ mlp_w1,
    const float* __restrict__ mlp_b1, const float* __restrict__ mlp_w2,
    const float* __restrict__ mlp_b2, ushort* __restrict__ Wtab){
  int l    = blockIdx.x / TBL_TILES;
  int tile = blockIdx.x % TBL_TILES;
  int row0 = tile * 32;
  const float* w1 = mlp_w1 + l*128*25;
  const float* b1 = mlp_b1 + l*128;
  const float* w2 = mlp_w2 + l*128*128;
  const float* b2 = mlp_b2 + l*128;
  __shared__ float Gs[32][26];
  __shared__ float Ts[32][129];
  __shared__ float Ws[32][129];
  int t = threadIdx.x;
  for (int idx=t; idx<32*25; idx+=256){
    int r = idx/25, k = idx%25;
    float d = (row0+r) * (5.0f/4096.0f);
    float x = d - (float)k*(5.0f/24.0f);
    Gs[r][k] = __expf(-11.52f*x*x);
  }
  __syncthreads();
  int rg = t&7, cg = t>>3;
  #pragma unroll
  for (int ri=0;ri<4;ri++){
    int r = rg*4+ri;
    #pragma unroll
    for (int ci=0;ci<4;ci++){
      int c = cg*4+ci;
      float s = b1[c];
      for (int k=0;k<25;k++) s += Gs[r][k]*w1[c*25+k];
      Ts[r][c] = dssp(s);
    }
  }
  float acc[4][4] = {};
  for (int k0=0;k0<128;k0+=32){
    __syncthreads();
    for (int idx=t; idx<1024; idx+=256){
      int c=idx>>3, kk4=(idx&7)*4;
      float4 f = *(const float4*)(w2+(size_t)c*128+k0+kk4);
      Ws[kk4][c]=f.x; Ws[kk4+1][c]=f.y; Ws[kk4+2][c]=f.z; Ws[kk4+3][c]=f.w;
    }
    __syncthreads();
    for (int kk=0;kk<32;kk++){
      float xv[4];
      #pragma unroll
      for (int ri=0;ri<4;ri++) xv[ri]=Ts[rg*4+ri][k0+kk];
      #pragma unroll
      for (int ci=0;ci<4;ci++){
        float wv = Ws[kk][cg*4+ci];
        #pragma unroll
        for (int ri=0;ri<4;ri++) acc[ri][ci] += xv[ri]*wv;
      }
    }
  }
  #pragma unroll
  for (int ri=0;ri<4;ri++){
    int r = row0 + rg*4 + ri;
    if (r >= TBL_ROWS) continue;
    float d  = r * (5.0f/4096.0f);
    float Cf = 0.5f*(cosf(d*(3.14159265358979f/5.0f))+1.0f);
    #pragma unroll
    for (int ci=0;ci<4;ci++){
      int c = cg*4+ci;
      Wtab[((size_t)l*TBL_ROWS + r)*128 + c] = f2b((acc[ri][ci] + b2[c]) * Cf);
    }
  }
}

__global__ void pack_wtab(const ushort* __restrict__ Wtab, unsigned* __restrict__ Wpk){
  long t = (long)blockIdx.x*blockDim.x + threadIdx.x;
  const long TOT = 4L*TBL_K*128;
  if (t < TOT){
    int l = (int)(t / ((long)TBL_K*128));
    long rem = t % ((long)TBL_K*128);
    int r = (int)(rem >> 7), f = (int)(rem & 127);
    const ushort* base = Wtab + (size_t)l*TBL_ROWS*128;
    Wpk[t] = (((unsigned)base[(size_t)(r+1)*128+f])<<16) | (unsigned)base[(size_t)r*128+f];
  }
}

// ------------------------------ MFMA tile helpers ---------------------------
// A-tile: bf16 LDS rows stride 136 (conflict-free b128 frags).
// A-frag: A[m=lane&15][k=quad*8+j]; B-frag: W[c][k] row-major bf16 global.
// C/D: row=quad*4+reg, col=lane&15. Wave w covers cols w*(NT*16)..
__device__ __forceinline__ short8 afragb(const ushort (*Xb)[136], int lane, int k0){
  int m=lane&15, q=(lane>>4)&3;
  return *(const short8*)(&Xb[m][k0+q*8]);
}
__device__ __forceinline__ short8 bfrag(const ushort* __restrict__ W, int cbase, int lane, int k0){
  int n=lane&15, q=(lane>>4)&3;
  return *(const short8*)(W + (size_t)(cbase+n)*128 + k0 + q*8);
}
template<int NT>
__device__ __forceinline__ void mgemm(const ushort (*Xb)[136],
    const ushort* __restrict__ W, int t, f32x4 d[NT]){
  int lane=t&63, w=t>>6;
  #pragma unroll
  for (int ct=0;ct<NT;ct++) d[ct]=(f32x4){0.f,0.f,0.f,0.f};
  #pragma unroll
  for (int kc=0;kc<4;kc++){
    short8 a = afragb(Xb, lane, kc*32);
    #pragma unroll
    for (int ct=0;ct<NT;ct++){
      short8 b = bfrag(W, w*(NT*16)+ct*16, lane, kc*32);
      d[ct] = __builtin_amdgcn_mfma_f32_16x16x32_bf16(a, b, d[ct], 0, 0, 0);
    }
  }
}
// D -> bf16 A-tile (bias + optional ssp)
template<int NT>
__device__ __forceinline__ void d2tile(ushort (*Y)[136], const f32x4 d[NT], int t,
    int colofs, const float* __restrict__ bias, int do_ssp){
  int lane=t&63, w=t>>6, q=(lane>>4)&3, n=lane&15;
  #pragma unroll
  for (int ct=0;ct<NT;ct++){
    int c = w*(NT*16)+ct*16+n;
    float bv = bias? bias[c] : 0.f;
    #pragma unroll
    for (int i=0;i<4;i++){
      float y = d[ct][i] + bv;
      if (do_ssp) y = dssp(y);
      Y[q*4+i][colofs+c] = f2b(y);
    }
  }
}
// D -> fp32 LDS [16][132]
template<int NT>
__device__ __forceinline__ void d2os(float (*Os)[132], const f32x4 d[NT], int t,
    const float* __restrict__ bias, int do_ssp){
  int lane=t&63, w=t>>6, q=(lane>>4)&3, n=lane&15;
  #pragma unroll
  for (int ct=0;ct<NT;ct++){
    int c = w*(NT*16)+ct*16+n;
    float bv = bias? bias[c] : 0.f;
    #pragma unroll
    for (int i=0;i<4;i++){
      float y = d[ct][i] + bv;
      if (do_ssp) y = dssp(y);
      Os[q*4+i][c] = y;
    }
  }
}
// D (NT=2, 128 cols) -> global bf16 row-major [N,128], coalesced via LDS tile
__device__ __forceinline__ void d2glob_c(ushort* __restrict__ out, const f32x4 d[2],
    int t, int row0, int N, ushort (*Tmp)[136]){
  d2tile<2>(Tmp, d, t, 0, nullptr, 0);
  __syncthreads();
  int r=t>>4, o=(t&15)*8;
  int gr=row0+r;
  if (gr<N) *(uint4*)(out + (size_t)gr*128 + o) = *(const uint4*)&Tmp[r][o];
  __syncthreads();
}

// ------------------------- F0: embed + lin + linh ---------------------------
__global__ __launch_bounds__(256) void f_first(const int* __restrict__ z,
    const float* __restrict__ emb, float* __restrict__ v,
    const ushort* __restrict__ linA, const ushort* __restrict__ linB,
    ushort* __restrict__ vlin, ushort* __restrict__ vlinh, int N){
  __shared__ ushort Xb[16][136];
  __shared__ ushort Tb[16][136];
  int t=threadIdx.x; int row0=blockIdx.x*16;
  f32x4 d[2];
  for (int idx=t; idx<512; idx+=256){
    int r=idx>>5, k4=(idx&31)*4; int gr=row0+r;
    int zz=(gr<N)? clampi(z[gr],0,99):0;
    float4 f = *(const float4*)(emb + (size_t)zz*128 + k4);
    unsigned r0 = (unsigned)f2b(f.x) | ((unsigned)f2b(f.y)<<16);
    unsigned r1 = (unsigned)f2b(f.z) | ((unsigned)f2b(f.w)<<16);
    *(uint2*)&Xb[r][k4] = make_uint2(r0,r1);
    if (gr<N) *(float4*)(v + (size_t)gr*128 + k4) = f;
  }
  __syncthreads();
  mgemm<2>(Xb, linA, t, d);
  d2glob_c(vlin, d, t, row0, N, Tb);
  mgemm<2>(Xb, linB, t, d);
  d2glob_c(vlinh, d, t, row0, N, Tb);
}

// -------------- F_mid: update_v(l) + lin(l+1) + linh(l+1) -------------------
__global__ __launch_bounds__(256) void f_mid(
    const float* __restrict__ accR, const float* __restrict__ accH,
    float* __restrict__ v,
    const ushort* __restrict__ v1w, const float* __restrict__ v1b,
    const ushort* __restrict__ v2w, const float* __restrict__ v2b,
    const ushort* __restrict__ vh1w, const float* __restrict__ vh1b,
    const ushort* __restrict__ vh2w, const float* __restrict__ vh2b,
    const ushort* __restrict__ cw, const float* __restrict__ cb,
    const ushort* __restrict__ linA, const ushort* __restrict__ linB,
    ushort* __restrict__ vlin, ushort* __restrict__ vlinh, int N){
  __shared__ ushort Xb[16][136];
  __shared__ ushort Xb2[16][136];
  __shared__ ushort Xb3[16][136];
  __shared__ float  Os[16][132];
  int t=threadIdx.x; int row0=blockIdx.x*16;
  f32x4 d[2]; f32x4 d1[1];

  for (int path=0; path<2; path++){
    const float* X = path? accH : accR;
    __syncthreads();
    for (int idx=t; idx<512; idx+=256){
      int r=idx>>5, k4=(idx&31)*4; int gr=row0+r;
      float4 f=(gr<N)? *(const float4*)(X+(size_t)gr*128+k4):make_float4(0,0,0,0);
      unsigned r0 = (unsigned)f2b(f.x) | ((unsigned)f2b(f.y)<<16);
      unsigned r1 = (unsigned)f2b(f.z) | ((unsigned)f2b(f.w)<<16);
      *(uint2*)&Xb[r][k4] = make_uint2(r0,r1);
    }
    __syncthreads();
    mgemm<2>(Xb, path?vh1w:v1w, t, d);
    d2tile<2>(Xb2, d, t, 0, path?vh1b:v1b, 1);
    __syncthreads();
    mgemm<1>(Xb2, path?vh2w:v2w, t, d1);
    d2tile<1>(Xb3, d1, t, path*64, path?vh2b:v2b, 0);
  }
  __syncthreads();
  mgemm<2>(Xb3, cw, t, d);
  d2os<2>(Os, d, t, cb, 1);
  __syncthreads();
  for (int idx=t; idx<512; idx+=256){      // v += Os ; Xb = bf16(new v)
    int r=idx>>5, k4=(idx&31)*4; int gr=row0+r;
    float4 f=(gr<N)? *(const float4*)(v+(size_t)gr*128+k4):make_float4(0,0,0,0);
    f.x+=Os[r][k4]; f.y+=Os[r][k4+1]; f.z+=Os[r][k4+2]; f.w+=Os[r][k4+3];
    if (gr<N) *(float4*)(v+(size_t)gr*128+k4)=f;
    unsigned r0 = (unsigned)f2b(f.x) | ((unsigned)f2b(f.y)<<16);
    unsigned r1 = (unsigned)f2b(f.z) | ((unsigned)f2b(f.w)<<16);
    *(uint2*)&Xb[r][k4] = make_uint2(r0,r1);
  }
  __syncthreads();
  mgemm<2>(Xb, linA, t, d);
  d2glob_c(vlin, d, t, row0, N, Xb2);
  mgemm<2>(Xb, linB, t, d);
  d2glob_c(vlinh, d, t, row0, N, Xb2);
}

// -------------- F_last: update_v(3) + readout (update_u) --------------------
__global__ __launch_bounds__(256) void f_last(
    const float* __restrict__ accR, const float* __restrict__ accH,
    const float* __restrict__ v,
    const ushort* __restrict__ v1w, const float* __restrict__ v1b,
    const ushort* __restrict__ v2w, const float* __restrict__ v2b,
    const ushort* __restrict__ vh1w, const float* __restrict__ vh1b,
    const ushort* __restrict__ vh2w, const float* __restrict__ vh2b,
    const ushort* __restrict__ cw, const float* __restrict__ cb,
    const ushort* __restrict__ u1w, const float* __restrict__ u1b,
    const float* __restrict__ u2w, const float* __restrict__ u2b,
    const int* __restrict__ batch, float* __restrict__ uacc, int N){
  __shared__ ushort Xb[16][136];
  __shared__ ushort Xb2[16][136];
  __shared__ ushort Xb3[16][136];
  __shared__ float  Os[16][132];
  __shared__ float ss[16];
  __shared__ int   bb[16];
  int t=threadIdx.x; int row0=blockIdx.x*16;
  f32x4 d[2]; f32x4 d1[1];

  for (int path=0; path<2; path++){
    const float* X = path? accH : accR;
    __syncthreads();
    for (int idx=t; idx<512; idx+=256){
      int r=idx>>5, k4=(idx&31)*4; int gr=row0+r;
      float4 f=(gr<N)? *(const float4*)(X+(size_t)gr*128+k4):make_float4(0,0,0,0);
      unsigned r0 = (unsigned)f2b(f.x) | ((unsigned)f2b(f.y)<<16);
      unsigned r1 = (unsigned)f2b(f.z) | ((unsigned)f2b(f.w)<<16);
      *(uint2*)&Xb[r][k4] = make_uint2(r0,r1);
    }
    __syncthreads();
    mgemm<2>(Xb, path?vh1w:v1w, t, d);
    d2tile<2>(Xb2, d, t, 0, path?vh1b:v1b, 1);
    __syncthreads();
    mgemm<1>(Xb2, path?vh2w:v2w, t, d1);
    d2tile<1>(Xb3, d1, t, path*64, path?vh2b:v2b, 0);
  }
  __syncthreads();
  mgemm<2>(Xb3, cw, t, d);
  d2os<2>(Os, d, t, cb, 1);
  __syncthreads();
  for (int idx=t; idx<512; idx+=256){      // Xb = bf16(v + dssp(cat))
    int r=idx>>5, k4=(idx&31)*4; int gr=row0+r;
    float4 f=(gr<N)? *(const float4*)(v+(size_t)gr*128+k4):make_float4(0,0,0,0);
    f.x+=Os[r][k4]; f.y+=Os[r][k4+1]; f.z+=Os[r][k4+2]; f.w+=Os[r][k4+3];
    unsigned r0 = (unsigned)f2b(f.x) | ((unsigned)f2b(f.y)<<16);
    unsigned r1 = (unsigned)f2b(f.z) | ((unsigned)f2b(f.w)<<16);
    *(uint2*)&Xb[r][k4] = make_uint2(r0,r1);
  }
  __syncthreads();
  mgemm<1>(Xb, u1w, t, d1);                // 64 cols
  d2os<1>(Os, d1, t, u1b, 1);
  __syncthreads();
  if (t<16){
    int gr=row0+t;
    float s=0.f; int bt=-1;
    if (gr<N){
      s = u2b[0];
      for (int c=0;c<64;c++) s += Os[t][c]*u2w[c];
      bt = clampi(batch[gr],0,63);
    }
    ss[t]=s; bb[t]=bt;
  }
  __syncthreads();
  if (t==0){
    float run=0.f; int cur=-1;
    for (int q=0;q<16;q++){
      int bq=bb[q];
      if (bq<0) continue;
      if (bq!=cur){ if (cur>=0) atomicAdd(&uacc[cur],run); cur=bq; run=0.f; }
      run += ss[q];
    }
    if (cur>=0) atomicAdd(&uacc[cur],run);
  }
}

// ------ hull filter: 64 rows/block, row-major out, LDS-union, coalesced -----
__global__ __launch_bounds__(256) void hull_all(const int2* __restrict__ spk_h,
    const float* __restrict__ fea,
    const float* __restrict__ mlph_w1, const float* __restrict__ mlph_b1,
    const ushort* __restrict__ mlph_w2b, const float* __restrict__ mlph_b2,
    ushort* __restrict__ WhS_base, size_t lstride,
    int EH, int tilesPerLayer, int l0){
  int l    = l0 + blockIdx.x / tilesPerLayer;
  int tile = blockIdx.x % tilesPerLayer;
  int row0 = tile*64;
  const float* w1 = mlph_w1 + l*128*7;
  const float* b1 = mlph_b1 + l*128;
  const ushort* w2 = mlph_w2b + (size_t)l*16384;
  const float* b2 = mlph_b2 + l*128;
  ushort* WhS = WhS_base + (size_t)(l-l0)*lstride;
  __shared__ int   Eid[64];
  __shared__ float Fs[64][8];
  __shared__ ushort Buf[64][136];   // layer-1 out (Xb) THEN layer-2 out (Ys)
  int t=threadIdx.x;
  if (t < 64){
    int p=row0+t;
    Eid[t]=(p<EH)? clampi(spk_h[p].y,0,EH-1):0;
  }
  __syncthreads();
  for (int idx=t; idx<448; idx+=256){
    int r=idx/7, k=idx%7;
    int p=row0+r;
    Fs[r][k]=(p<EH)? fea[(size_t)Eid[r]*7+k]:0.f;
  }
  __syncthreads();
  {
    // layer 1: thread -> 4 cols (reg-cached weights) x 8 rows
    int c0=(t&31)*4, r0=(t>>5)*8;
    float w[4][7]; float bb[4];
    #pragma unroll
    for (int cc=0;cc<4;cc++){
      bb[cc]=b1[c0+cc];
      #pragma unroll
      for (int k=0;k<7;k++) w[cc][k]=w1[(c0+cc)*7+k];
    }
    #pragma unroll
    for (int rr=0;rr<8;rr++){
      int r=r0+rr;
      float fv[7];
      #pragma unroll
      for (int k=0;k<7;k++) fv[k]=Fs[r][k];
      ushort o[4];
      #pragma unroll
      for (int cc=0;cc<4;cc++){
        float s=bb[cc];
        #pragma unroll
        for (int k=0;k<7;k++) s=fmaf(fv[k],w[cc][k],s);
        o[cc]=f2b(dssp(s));
      }
      unsigned lo=(unsigned)o[0]|((unsigned)o[1]<<16);
      unsigned hi=(unsigned)o[2]|((unsigned)o[3]<<16);
      *(uint2*)&Buf[r][c0]=make_uint2(lo,hi);
    }
  }
  __syncthreads();
  int lane=t&63, w=t>>6;
  const ushort (*Xw)[136] = (const ushort (*)[136])&Buf[w*16][0];
  f32x4 d[8];
  #pragma unroll
  for (int ct=0;ct<8;ct++) d[ct]=(f32x4){0.f,0.f,0.f,0.f};
  #pragma unroll
  for (int kc=0;kc<4;kc++){
    short8 a = afragb(Xw, lane, kc*32);
    #pragma unroll
    for (int ct=0;ct<8;ct++){
      short8 b = bfrag(w2, ct*16, lane, kc*32);
      d[ct] = __builtin_amdgcn_mfma_f32_16x16x32_bf16(a, b, d[ct], 0, 0, 0);
    }
  }
  __syncthreads();   // all Buf reads done; reuse Buf as row-major output tile
  int q=(lane>>4)&3, n=lane&15;
  #pragma unroll
  for (int ct=0;ct<8;ct++){
    int c=ct*16+n;
    float bv=b2[c];
    #pragma unroll
    for (int i=0;i<4;i++)
      Buf[w*16+q*4+i][c] = f2b(d[ct][i]+bv);
  }
  __syncthreads();
  // coalesced row-major stores: 1024 chunks of 16 B; wave covers 4 full rows
  #pragma unroll
  for (int j=0;j<4;j++){
    int idx=j*256+t;
    int r=idx>>4, o=(idx&15)*8;
    *(uint4*)(WhS + (size_t)(row0+r)*128 + o) = *(const uint4*)&Buf[r][o];
  }
}

// ------------------------------ CSR segment reductions ----------------------
__device__ __forceinline__ float rlerp(unsigned y, const unsigned* __restrict__ Wpk, int f){
  int i0 = (int)(y>>16);
  float fr = (float)(y&0xFFFFu)*(1.f/65536.f);
  unsigned u = Wpk[(size_t)i0*128+f];
  float w0=__uint_as_float(u<<16), w1=__uint_as_float(u&0xFFFF0000u);
  return fmaf(fr, w1-w0, w0);
}

__global__ __launch_bounds__(128) void acc_both(
    const int* __restrict__ off_r, const int2* __restrict__ spk_r,
    const ushort* __restrict__ vlin, const unsigned* __restrict__ Wpk,
    float* __restrict__ accR,
    const int* __restrict__ off_h, const int2* __restrict__ spk_h,
    const ushort* __restrict__ vlinh, const ushort* __restrict__ WhS,
    float* __restrict__ accH,
    int Etot, int EHtot, int N){
  int f = threadIdx.x;
  if ((int)blockIdx.x < N){
    int n = blockIdx.x;
    int b = clampi(off_r[n], 0, Etot);
    int e = clampi(off_r[n+1], b, Etot);
    float a = 0.f;
    int p = b;
    for (; p+8<=e; p+=8){
      int2 k[8];
      #pragma unroll
      for (int j=0;j<8;j++) k[j]=spk_r[p+j];
      float vv[8], ww[8];
      #pragma unroll
      for (int j=0;j<8;j++) vv[j]=b2f16(vlin[(size_t)k[j].x*128+f]);
      #pragma unroll
      for (int j=0;j<8;j++) ww[j]=rlerp((unsigned)k[j].y, Wpk, f);
      #pragma unroll
      for (int j=0;j<8;j++) a=fmaf(vv[j],ww[j],a);
    }
    for (; p+4<=e; p+=4){
      int2 k0=spk_r[p], k1=spk_r[p+1], k2=spk_r[p+2], k3=spk_r[p+3];
      float v0 = b2f16(vlin[(size_t)k0.x*128+f]);
      float v1 = b2f16(vlin[(size_t)k1.x*128+f]);
      float v2 = b2f16(vlin[(size_t)k2.x*128+f]);
      float v3 = b2f16(vlin[(size_t)k3.x*128+f]);
      float w0 = rlerp((unsigned)k0.y, Wpk, f);
      float w1 = rlerp((unsigned)k1.y, Wpk, f);
      float w2 = rlerp((unsigned)k2.y, Wpk, f);
      float w3 = rlerp((unsigned)k3.y, Wpk, f);
      a += v0*w0 + v1*w1 + v2*w2 + v3*w3;
    }
    for (; p<e; p++){
      int2 k0=spk_r[p];
      a += b2f16(vlin[(size_t)k0.x*128+f]) * rlerp((unsigned)k0.y, Wpk, f);
    }
    accR[(size_t)n*128+f] = a;
  } else {
    int n = blockIdx.x - N;
    int b = clampi(off_h[n], 0, EHtot);
    int e = clampi(off_h[n+1], b, EHtot);
    float a = 0.f;
    int p = b;
    for (; p+4<=e; p+=4){
      int2 k0=spk_h[p], k1=spk_h[p+1], k2=spk_h[p+2], k3=spk_h[p+3];
      float v0 = b2f16(vlinh[(size_t)k0.x*128+f]);
      float v1 = b2f16(vlinh[(size_t)k1.x*128+f]);
      float v2 = b2f16(vlinh[(size_t)k2.x*128+f]);
      float v3 = b2f16(vlinh[(size_t)k3.x*128+f]);
      a += v0*b2f16(WhS[(size_t)p*128+f])     + v1*b2f16(WhS[(size_t)(p+1)*128+f])
         + v2*b2f16(WhS[(size_t)(p+2)*128+f]) + v3*b2f16(WhS[(size_t)(p+3)*128+f]);
    }
    for (; p<e; p++){
      int2 k0=spk_h[p];
      a += b2f16(vlinh[(size_t)k0.x*128+f]) * b2f16(WhS[(size_t)p*128+f]);
    }
    accH[(size_t)n*128+f] = a;
  }
}

__global__ void write_out(const float* __restrict__ uacc, void* out, const int* __restrict__ flag){
  int t = threadIdx.x;
  if (t < 64){
    if (*flag) ((bf16*)out)[t] = __float2bfloat16(uacc[t]);
    else       ((float*)out)[t] = uacc[t];
  }
}

// ----------------------------------------------------------------- launch ---
extern "C" void kernel_launch(void* const* d_in, const int* in_sizes, int n_in,
                              void* d_out, int out_size, void* d_ws, size_t ws_size,
                              hipStream_t stream){
  const int* z     = (const int*)d_in[0];
  const int* ei    = (const int*)d_in[1];
  const int* eih   = (const int*)d_in[2];
  const int* batch = (const int*)d_in[3];

  const int N  = in_sizes[0];
  const int E  = in_sizes[1]/2;
  const int EH = in_sizes[2]/2;
  const int EHpad = (EH + 63) & ~63;   // 64-aligned: last tile's pad rows are writable

  char* wp = (char*)d_ws;
  auto alloc = [&](size_t bytes)->char*{
    char* p = wp; wp += (bytes + 255) & ~(size_t)255; return p;
  };
  int* flag    = (int*)alloc(256);
  int* cnt_r   = (int*)alloc((size_t)N*4);
  int* off_r   = (int*)alloc((size_t)(N+1)*4);
  int* cur_r   = (int*)alloc((size_t)N*4);
  int* cnt_h   = (int*)alloc((size_t)N*4);
  int* off_h   = (int*)alloc((size_t)(N+1)*4);
  int* cur_h   = (int*)alloc((size_t)N*4);
  int2* spk_r  = (int2*)alloc((size_t)E*8);
  int2* spk_h  = (int2*)alloc((size_t)EH*8);
  float* uacc  = (float*)alloc(64*4);

  SegTable tbl; tbl.count = 27; tbl.total = 0;
  float* cvt[27];
  for (int i=0;i<27;i++){
    int n = in_sizes[4+i];
    cvt[i] = (float*)alloc((size_t)n*4);
    tbl.s[i].src = d_in[4+i];
    tbl.s[i].dst = cvt[i];
    tbl.s[i].n   = n;
    tbl.total   += n;
  }
  const float* distc   = cvt[0];
  const float* feac    = cvt[1];
  const float* embc    = cvt[2];
  const float* mlp_w1  = cvt[4];
  const float* mlp_b1  = cvt[5];
  const float* mlp_w2  = cvt[6];
  const float* mlp_b2  = cvt[7];
  const float* mlph_w1 = cvt[9];
  const float* mlph_b1 = cvt[10];
  const float* mlph_b2 = cvt[12];
  const float* v1_b  = cvt[14];
  const float* v2_b  = cvt[16];
  const float* vh1_b = cvt[18];
  const float* vh2_b = cvt[20];
  const float* cat_b = cvt[22];
  const float* u1_b  = cvt[24];
  const float* u2_w  = cvt[25];
  const float* u2_b  = cvt[26];

  ushort* lin_wb   = (ushort*)alloc((size_t)4*16384*2);
  ushort* linh_wb  = (ushort*)alloc((size_t)4*16384*2);
  ushort* v1_wb    = (ushort*)alloc((size_t)4*16384*2);
  ushort* vh1_wb   = (ushort*)alloc((size_t)4*16384*2);
  ushort* cat_wb   = (ushort*)alloc((size_t)4*16384*2);
  ushort* mlph_w2b = (ushort*)alloc((size_t)4*16384*2);
  ushort* v2_wb    = (ushort*)alloc((size_t)4*8192*2);
  ushort* vh2_wb   = (ushort*)alloc((size_t)4*8192*2);
  ushort* u1_wb    = (ushort*)alloc((size_t)8192*2);
  WTable wt; wt.count = 9;
  wt.s[0] = { cvt[3],  lin_wb,   4*16384 };
  wt.s[1] = { cvt[8],  linh_wb,  4*16384 };
  wt.s[2] = { cvt[13], v1_wb,    4*16384 };
  wt.s[3] = { cvt[17], vh1_wb,   4*16384 };
  wt.s[4] = { cvt[21], cat_wb,   4*16384 };
  wt.s[5] = { cvt[11], mlph_w2b, 4*16384 };
  wt.s[6] = { cvt[15], v2_wb,    4*8192  };
  wt.s[7] = { cvt[19], vh2_wb,   4*8192  };
  wt.s[8] = { cvt[23], u1_wb,    8192    };
  wt.total = 6*4*16384 + 2*4*8192 + 8192;

  ushort*   Wtab = (ushort*)alloc((size_t)4*TBL_ROWS*128*2);
  unsigned* Wpk  = (unsigned*)alloc((size_t)4*TBL_K*128*4);
  float* v     = (float*)alloc((size_t)N*128*4);
  ushort* vlin  = (ushort*)alloc((size_t)N*128*2);
  ushort* vlinh = (ushort*)alloc((size_t)N*128*2);
  float* accR  = (float*)alloc((size_t)N*128*4);
  float* accH  = (float*)alloc((size_t)N*128*4);

  size_t used = (size_t)(wp - (char*)d_ws);
  size_t whs1 = (size_t)EHpad*128*2;
  bool pre = (ws_size >= used + 4*whs1 + 256);
  ushort* WhS = (ushort*)alloc(pre ? 4*whs1 : whs1);

  detect_mode<<<1,256,0,stream>>>((const unsigned*)d_in[6], flag);
  {
    int cb = (int)((tbl.total + 255)/256);
    if (cb > 4096) cb = 4096;
    convert_all<<<cb,256,0,stream>>>(tbl, flag);
  }
  convert_wb<<<(wt.total+255)/256,256,0,stream>>>(wt);

  int nb;
  nb = (E+255)/256;     init_all<<<nb,256,0,stream>>>(cnt_r,cnt_h,uacc,spk_r,spk_h,N,E,EH);
  nb = (E+255)/256;     count_edges<<<nb,256,0,stream>>>(ei,eih,E,EH,N,cnt_r,cnt_h);
  scan_pair<<<1,1024,0,stream>>>(cnt_r,off_r,cur_r,cnt_h,off_h,cur_h,N);
  nb = (E+255)/256;     scatter_edges<<<nb,256,0,stream>>>(ei,distc,eih,E,EH,N,cur_r,cur_h,spk_r,spk_h);
  build_wtab<<<4*TBL_TILES,256,0,stream>>>(mlp_w1,mlp_b1,mlp_w2,mlp_b2,Wtab);
  pack_wtab<<<(int)((4L*TBL_K*128+255)/256),256,0,stream>>>(Wtab,Wpk);

  const int nt = (N+15)/16;
  const int ht64 = (EH+63)/64;
  if (pre)
    hull_all<<<4*ht64,256,0,stream>>>(spk_h, feac, mlph_w1, mlph_b1, mlph_w2b, mlph_b2,
                                      WhS, whs1/2, EH, ht64, 0);

  f_first<<<nt,256,0,stream>>>(z, embc, v, lin_wb, linh_wb, vlin, vlinh, N);
  for (int l=0;l<4;l++){
    if (!pre)
      hull_all<<<ht64,256,0,stream>>>(spk_h, feac, mlph_w1, mlph_b1, mlph_w2b, mlph_b2,
                                      WhS, 0, EH, ht64, l);
    const ushort* WhSl = pre ? (WhS + (size_t)l*(whs1/2)) : WhS;
    acc_both<<<2*N,128,0,stream>>>(off_r, spk_r, vlin, Wpk + (size_t)l*TBL_K*128, accR,
                                   off_h, spk_h, vlinh, WhSl, accH, E, EH, N);
    if (l<3){
      f_mid<<<nt,256,0,stream>>>(accR, accH, v,
          v1_wb + (size_t)l*16384, v1_b + l*128, v2_wb + (size_t)l*8192, v2_b + l*64,
          vh1_wb + (size_t)l*16384, vh1_b + l*128, vh2_wb + (size_t)l*8192, vh2_b + l*64,
          cat_wb + (size_t)l*16384, cat_b + l*128,
          lin_wb + (size_t)(l+1)*16384, linh_wb + (size_t)(l+1)*16384, vlin, vlinh, N);
    } else {
      f_last<<<nt,256,0,stream>>>(accR, accH, v,
          v1_wb + (size_t)l*16384, v1_b + l*128, v2_wb + (size_t)l*8192, v2_b + l*64,
          vh1_wb + (size_t)l*16384, vh1_b + l*128, vh2_wb + (size_t)l*8192, vh2_b + l*64,
          cat_wb + (size_t)l*16384, cat_b + l*128,
          u1_wb, u1_b, u2_w, u2_b, batch, uacc, N);
    }
  }
  write_out<<<1,64,0,stream>>>(uacc, d_out, flag);
}